// Round 9
// baseline (343.025 us; speedup 1.0000x reference)
//
#include <hip/hip_runtime.h>
#include <math.h>

#define NB 4096
#define NN 64

typedef _Float16 h8 __attribute__((ext_vector_type(8)));
typedef float f4 __attribute__((ext_vector_type(4)));
typedef unsigned long long u64;

typedef const __attribute__((address_space(1))) void* gas_t;
typedef __attribute__((address_space(3))) void* las_t;

__device__ __forceinline__ void gload16(const void* g, void* l) {
  __builtin_amdgcn_global_load_lds((gas_t)g, (las_t)l, 16, 0, 0);
}
__device__ __forceinline__ void rbar() {
  asm volatile("" ::: "memory");
  __builtin_amdgcn_s_barrier();
  asm volatile("" ::: "memory");
}
__device__ __forceinline__ void lgkm0() {
  asm volatile("s_waitcnt lgkmcnt(0)" ::: "memory");
}
template<int N> __device__ __forceinline__ void waitv() {
  if constexpr (N == 0) asm volatile("s_waitcnt vmcnt(0)" ::: "memory");
  else                  asm volatile("s_waitcnt vmcnt(1)" ::: "memory");
  __builtin_amdgcn_sched_barrier(0);
}

// activation buffers: 64 rows x 128 f16, 256 B row stride, byte ^= (row&7)<<4
__device__ __forceinline__ int aoff(int row, int colb) {
  return row * 256 + (colb ^ ((row & 7) << 4));
}
__device__ __forceinline__ h8 ald8(const char* a, int row, int colb) {
  return *(const h8*)(a + aoff(row, colb));
}
__device__ __forceinline__ _Float16 ald(const char* a, int row, int colb) {
  return *(const _Float16*)(a + aoff(row, colb));
}
__device__ __forceinline__ void ast(char* a, int row, int colb, _Float16 v) {
  *(_Float16*)(a + aoff(row, colb)) = v;
}

// ---------------- weight prep ----------------
// f16 ws: 0 Wl1p[128][32] | 4096 Wl2p[32][128] | 8192 W11p[128][32] |
// 12288 W12 | 28672 W21 | 45056 W22 | 61440 Wat 2x[128][128] (Wo.Wv fused) |
// 94208 Wf1 2x | 126976 Wf2 2x | 159744 params [32][128]
// params idx: 0 b_l1 1 b_l2 2 b11 3 b12 4 b21 5 b22 6 bat0 7 bat1
//             8 bf1_0 9 bf2_0 10 bf1_1 11 bf2_1 12 ln1g0 13 ln1b0 14 ln2g0
//             15 ln2b0 16 ln1g1 17 ln1b1 18 ln2g1 19 ln2b1 20..31 zero
__global__ void prepA(
    const float* __restrict__ W_l1, const float* __restrict__ W_l2,
    const float* __restrict__ W11, const float* __restrict__ W12,
    const float* __restrict__ W21, const float* __restrict__ W22,
    const float* __restrict__ Wf1, const float* __restrict__ Wf2,
    const float* __restrict__ b_l1, const float* __restrict__ b_l2,
    const float* __restrict__ b11, const float* __restrict__ b12,
    const float* __restrict__ b21, const float* __restrict__ b22,
    const float* __restrict__ bf1, const float* __restrict__ bf2,
    const float* __restrict__ ln1_g, const float* __restrict__ ln1_b,
    const float* __restrict__ ln2_g, const float* __restrict__ ln2_b,
    _Float16* __restrict__ ws)
{
  const int e = blockIdx.x * 256 + threadIdx.x;
  float v;
  if (e < 4096) { const int o = e >> 5, k = e & 31; v = (k < 20) ? W_l1[o * 20 + k] : 0.f; }
  else if (e < 8192) { const int i = e - 4096; const int o = i >> 7, k = i & 127; v = (o < 20) ? W_l2[o * 128 + k] : 0.f; }
  else if (e < 12288) { const int i = e - 8192; const int o = i >> 5, k = i & 31; v = (k < 27) ? W11[o * 27 + k] : 0.f; }
  else if (e < 28672) v = W12[e - 12288];
  else if (e < 45056) v = W21[e - 28672];
  else if (e < 61440) v = W22[e - 45056];
  else if (e < 94208) return;                      // Wat by prepB
  else if (e < 126976) v = Wf1[e - 94208];
  else if (e < 159744) v = Wf2[e - 126976];
  else {
    const int p = e - 159744, idx = p >> 7, col = p & 127;
    switch (idx) {
      case 0: v = b_l1[col]; break;
      case 1: v = (col < 20) ? b_l2[col] : 0.f; break;
      case 2: v = b11[col]; break;
      case 3: v = b12[col]; break;
      case 4: v = b21[col]; break;
      case 5: v = b22[col]; break;
      case 8: v = bf1[col]; break;
      case 9: v = bf2[col]; break;
      case 10: v = bf1[128 + col]; break;
      case 11: v = bf2[128 + col]; break;
      case 12: v = ln1_g[col]; break;
      case 13: v = ln1_b[col]; break;
      case 14: v = ln2_g[col]; break;
      case 15: v = ln2_b[col]; break;
      case 16: v = ln1_g[128 + col]; break;
      case 17: v = ln1_b[128 + col]; break;
      case 18: v = ln2_g[128 + col]; break;
      case 19: v = ln2_b[128 + col]; break;
      default: v = 0.f; break;                      // 6,7 by prepB; 20+ zero
    }
  }
  ws[e] = (_Float16)v;
}

__global__ void prepB(
    const float* __restrict__ Wqkv, const float* __restrict__ bqkv,
    const float* __restrict__ Wo, const float* __restrict__ bo,
    _Float16* __restrict__ ws)
{
  if (blockIdx.x < 128) {
    const int e = blockIdx.x * 256 + threadIdx.x;       // 0..32767
    const int l = e >> 14, r = e & 16383, o = r >> 7, k = r & 127;
    const float* wo = Wo + (l * 128 + o) * 128;
    const float* wv = Wqkv + l * 49152 + 32768 + k;
    float acc = 0.f;
#pragma unroll 4
    for (int m = 0; m < 128; ++m) acc += wo[m] * wv[m * 128];
    ws[61440 + e] = (_Float16)acc;
  } else {
    const int t = threadIdx.x;                          // 256 threads: bat[2][128]
    const int l = t >> 7, o = t & 127;
    const float* wo = Wo + (l * 128 + o) * 128;
    const float* bv = bqkv + l * 384 + 256;
    float acc = bo[l * 128 + o];
    for (int m = 0; m < 128; ++m) acc += bv[m] * wo[m];
    ws[159744 + (6 + l) * 128 + o] = (_Float16)acc;
  }
}

// ---------------- chunk staging (4 KB, pre-swizzled source) ----------------
__device__ __forceinline__ void stage64(const _Float16* __restrict__ Wp, int KT,
                                        int kc, int oc, char* buf, int tid) {
  const int o = tid >> 2, kq = tid & 3;
  const int kreal = kq ^ ((o >> 1) & 3);
  gload16(Wp + (oc * 64 + o) * KT + kc * 32 + kreal * 8, buf + tid * 16);
}
__device__ __forceinline__ void stage32(const _Float16* __restrict__ Wp,
                                        int kc, char* buf, int tid) {
  const int o = tid >> 3, u = tid & 7;
  const int ureal = u ^ (o & 7);
  gload16(Wp + o * 128 + kc * 64 + ureal * 8, buf + tid * 16);
}

struct Resid2 { h8 a[8]; };   // a[0..3]=g0 rows r, a[4..7]=g1 rows r (by value only)

// ---------------- generic 8-chunk matmul stage, both graphs, in-place ----------------
// EPI: 0 bias(+RELU) | 1 raw (Z) | 3 bias+residG+LN (returns resid) | 4 bias+residReg+LN
template<int EPI, bool RELU, bool LAST, typename PF>
__device__ __forceinline__ Resid2 mm128_stage(
    const _Float16* __restrict__ Wp, char* g0, char* g1,
    const _Float16* pb, int bidx, int lnidx, Resid2 rin,
    char* wbase, int q0, int tid, PF&& pf)
{
  const int lane = tid & 63, wv = tid >> 6, lc = lane & 15, kg = lane >> 4;
  const int row0 = wv * 16 + lc, rb = wv * 16 + kg * 4;

  h8 af0[4], af1[4];
#pragma unroll
  for (int i = 0; i < 4; ++i) {
    af0[i] = ald8(g0, row0, i * 64 + kg * 16);
    af1[i] = ald8(g1, row0, i * 64 + kg * 16);
  }
  f4 acc0[8], acc1[8];
#pragma unroll
  for (int t = 0; t < 8; ++t) { acc0[t] = (f4){0.f,0.f,0.f,0.f}; acc1[t] = (f4){0.f,0.f,0.f,0.f}; }

#pragma unroll
  for (int oc = 0; oc < 2; ++oc) {
#pragma unroll
    for (int kc = 0; kc < 4; ++kc) {
      const int ql = oc * 4 + kc;
      if (LAST && ql == 7) waitv<0>(); else waitv<1>();
      rbar();
      char* nbuf = wbase + ((q0 + ql + 2) % 3) * 4096;
      if (ql + 2 < 8) stage64(Wp, 128, (ql + 2) & 3, (ql + 2) >> 2, nbuf, tid);
      else pf(ql - 6, nbuf);
      const char* wb = wbase + ((q0 + ql) % 3) * 4096;
#pragma unroll
      for (int t = 0; t < 4; ++t) {
        const int o = t * 16 + lc;
        const int kq = kg ^ ((o >> 1) & 3);
        const h8 bf = *(const h8*)(wb + (o * 4 + kq) * 16);
        acc0[oc * 4 + t] = __builtin_amdgcn_mfma_f32_16x16x32_f16(af0[kc], bf, acc0[oc * 4 + t], 0, 0, 0);
        acc1[oc * 4 + t] = __builtin_amdgcn_mfma_f32_16x16x32_f16(af1[kc], bf, acc1[oc * 4 + t], 0, 0, 0);
      }
    }
    if constexpr (EPI <= 1) {
#pragma unroll
      for (int t = 0; t < 4; ++t) {
        const int col = oc * 64 + t * 16 + lc;
        float bv = 0.f;
        if constexpr (EPI == 0) bv = (float)pb[bidx * 128 + col];
#pragma unroll
        for (int r = 0; r < 4; ++r) {
          float v0 = acc0[oc * 4 + t][r] + bv, v1 = acc1[oc * 4 + t][r] + bv;
          if constexpr (RELU) { v0 = fmaxf(v0, 0.f); v1 = fmaxf(v1, 0.f); }
          ast(g0, rb + r, col * 2, (_Float16)v0);
          ast(g1, rb + r, col * 2, (_Float16)v1);
        }
      }
    }
  }

  Resid2 rout{};
  if constexpr (EPI >= 3) {
    // add bias + residual
#pragma unroll
    for (int gt = 0; gt < 8; ++gt) {
      const int col = (gt >> 2) * 64 + (gt & 3) * 16 + lc;
      const float bv = (float)pb[bidx * 128 + col];
#pragma unroll
      for (int r = 0; r < 4; ++r) {
        float r0, r1;
        if constexpr (EPI == 3) { r0 = (float)ald(g0, rb + r, col * 2); r1 = (float)ald(g1, rb + r, col * 2); }
        else { r0 = (float)rin.a[r][gt]; r1 = (float)rin.a[4 + r][gt]; }
        acc0[gt][r] += bv + r0;
        acc1[gt][r] += bv + r1;
      }
    }
    // fused LN: per-row mean/var via 16-lane shfl reduce (two-pass)
    float m0a[4], m1a[4], rs0a[4], rs1a[4];
#pragma unroll
    for (int r = 0; r < 4; ++r) {
      float s0 = 0.f, s1 = 0.f;
#pragma unroll
      for (int gt = 0; gt < 8; ++gt) { s0 += acc0[gt][r]; s1 += acc1[gt][r]; }
      s0 += __shfl_xor(s0, 1, 64); s0 += __shfl_xor(s0, 2, 64);
      s0 += __shfl_xor(s0, 4, 64); s0 += __shfl_xor(s0, 8, 64);
      s1 += __shfl_xor(s1, 1, 64); s1 += __shfl_xor(s1, 2, 64);
      s1 += __shfl_xor(s1, 4, 64); s1 += __shfl_xor(s1, 8, 64);
      const float m0 = s0 * 0.0078125f, m1 = s1 * 0.0078125f;
      float q0s = 0.f, q1s = 0.f;
#pragma unroll
      for (int gt = 0; gt < 8; ++gt) {
        const float d0 = acc0[gt][r] - m0; q0s = fmaf(d0, d0, q0s);
        const float d1 = acc1[gt][r] - m1; q1s = fmaf(d1, d1, q1s);
      }
      q0s += __shfl_xor(q0s, 1, 64); q0s += __shfl_xor(q0s, 2, 64);
      q0s += __shfl_xor(q0s, 4, 64); q0s += __shfl_xor(q0s, 8, 64);
      q1s += __shfl_xor(q1s, 1, 64); q1s += __shfl_xor(q1s, 2, 64);
      q1s += __shfl_xor(q1s, 4, 64); q1s += __shfl_xor(q1s, 8, 64);
      m0a[r] = m0; m1a[r] = m1;
      rs0a[r] = 1.0f / sqrtf(q0s * 0.0078125f + 1e-5f);
      rs1a[r] = 1.0f / sqrtf(q1s * 0.0078125f + 1e-5f);
    }
#pragma unroll
    for (int gt = 0; gt < 8; ++gt) {
      const int col = (gt >> 2) * 64 + (gt & 3) * 16 + lc;
      const float gg = (float)pb[lnidx * 128 + col];
      const float bb = (float)pb[(lnidx + 1) * 128 + col];
#pragma unroll
      for (int r = 0; r < 4; ++r) {
        const _Float16 o0 = (_Float16)((acc0[gt][r] - m0a[r]) * rs0a[r] * gg + bb);
        const _Float16 o1 = (_Float16)((acc1[gt][r] - m1a[r]) * rs1a[r] * gg + bb);
        ast(g0, rb + r, col * 2, o0);
        ast(g1, rb + r, col * 2, o1);
        if constexpr (EPI == 3) { rout.a[r][gt] = o0; rout.a[4 + r][gt] = o1; }
      }
    }
  }
  return rout;
}

// W11 Z-stage: K=32 (A = cols 32..63), 2 chunks, raw epilogue, in-place
template<typename PF>
__device__ __forceinline__ void mm32_stage(
    const _Float16* __restrict__ Wp, char* g0, char* g1,
    char* wbase, int q0, int tid, PF&& pf)
{
  const int lane = tid & 63, wv = tid >> 6, lc = lane & 15, kg = lane >> 4;
  const int row0 = wv * 16 + lc, rb = wv * 16 + kg * 4;
  const h8 af0 = ald8(g0, row0, 64 + kg * 16);
  const h8 af1 = ald8(g1, row0, 64 + kg * 16);
#pragma unroll
  for (int oc = 0; oc < 2; ++oc) {
    waitv<1>(); rbar();
    pf(oc, wbase + ((q0 + oc + 2) % 3) * 4096);
    const char* wb = wbase + ((q0 + oc) % 3) * 4096;
    f4 a0[4], a1[4];
#pragma unroll
    for (int t = 0; t < 4; ++t) { a0[t] = (f4){0.f,0.f,0.f,0.f}; a1[t] = (f4){0.f,0.f,0.f,0.f}; }
#pragma unroll
    for (int t = 0; t < 4; ++t) {
      const int o = t * 16 + lc;
      const int kq = kg ^ ((o >> 1) & 3);
      const h8 bf = *(const h8*)(wb + (o * 4 + kq) * 16);
      a0[t] = __builtin_amdgcn_mfma_f32_16x16x32_f16(af0, bf, a0[t], 0, 0, 0);
      a1[t] = __builtin_amdgcn_mfma_f32_16x16x32_f16(af1, bf, a1[t], 0, 0, 0);
    }
#pragma unroll
    for (int t = 0; t < 4; ++t) {
      const int col = oc * 64 + t * 16 + lc;
#pragma unroll
      for (int r = 0; r < 4; ++r) {
        ast(g0, rb + r, col * 2, (_Float16)a0[t][r]);
        ast(g1, rb + r, col * 2, (_Float16)a1[t][r]);
      }
    }
  }
}

// in-place MFMA aggregation with bias+relu: G <- relu(M'^T G + b)
__device__ __forceinline__ void agg_ip(const u64* mc, char* G, const _Float16* pb,
                                       int bidx, int tid)
{
  const int lane = tid & 63, wv = tid >> 6, lc = lane & 15, kg = lane >> 4;
  const int c0 = wv * 32 + lc;
  u64 mrow[4];
#pragma unroll
  for (int rt = 0; rt < 4; ++rt) mrow[rt] = mc[rt * 16 + lc];
  h8 bf[2][2];
#pragma unroll
  for (int ks = 0; ks < 2; ++ks)
#pragma unroll
    for (int ct = 0; ct < 2; ++ct)
#pragma unroll
      for (int e = 0; e < 8; ++e)
        bf[ks][ct][e] = ald(G, ks * 32 + kg * 8 + e, (c0 + ct * 16) * 2);
  f4 acc[4][2];
#pragma unroll
  for (int rt = 0; rt < 4; ++rt) { acc[rt][0] = (f4){0.f,0.f,0.f,0.f}; acc[rt][1] = (f4){0.f,0.f,0.f,0.f}; }
#pragma unroll
  for (int ks = 0; ks < 2; ++ks)
#pragma unroll
    for (int rt = 0; rt < 4; ++rt) {
      const unsigned int byte = (unsigned int)(mrow[rt] >> (ks * 32 + kg * 8)) & 0xffu;
      h8 af;
#pragma unroll
      for (int e = 0; e < 8; ++e) af[e] = (_Float16)((byte >> e) & 1u);
#pragma unroll
      for (int ct = 0; ct < 2; ++ct)
        acc[rt][ct] = __builtin_amdgcn_mfma_f32_16x16x32_f16(af, bf[ks][ct], acc[rt][ct], 0, 0, 0);
    }
#pragma unroll
  for (int ct = 0; ct < 2; ++ct) {
    const int col = c0 + ct * 16;
    const float bv = (float)pb[bidx * 128 + col];
#pragma unroll
    for (int rt = 0; rt < 4; ++rt)
#pragma unroll
      for (int qq = 0; qq < 4; ++qq)
        ast(G, rt * 16 + kg * 4 + qq, col * 2, (_Float16)fmaxf(acc[rt][ct][qq] + bv, 0.f));
  }
}

struct SM {
  alignas(16) char G0[16384];
  alignas(16) char G1[16384];
  alignas(16) char WB[12288];
  alignas(16) char PB[8192];       // params [32][128] f16
  u64 mcol[2][64];
};   // 53248 B -> 3 blocks/CU

__global__ __launch_bounds__(256, 3)
void gin_critic_kernel(
    const float* __restrict__ data,
    const float* __restrict__ Wfc, const float* __restrict__ bfc,
    const _Float16* __restrict__ ws,
    float* __restrict__ out)
{
  __shared__ SM sm;
  const int tid = threadIdx.x;
  const int lane = tid & 63, wv = tid >> 6, lc = lane & 15, kg = lane >> 4;
  const int row0 = wv * 16 + lc, rb = wv * 16 + kg * 4;
  const int b = blockIdx.x;
  const long base = (long)b * 2 * NN * 27;
  char* G0 = sm.G0; char* G1 = sm.G1; char* wbase = sm.WB;
  const _Float16* pb = (const _Float16*)sm.PB;

  const _Float16* Wl1p = ws + 0;
  const _Float16* Wl2p = ws + 4096;
  const _Float16* W11p = ws + 8192;
  const _Float16* W12p = ws + 12288;
  const _Float16* W21p = ws + 28672;
  const _Float16* W22p = ws + 45056;
  const _Float16* Wat0 = ws + 61440;
  const _Float16* Wat1 = ws + 61440 + 16384;
  const _Float16* Wf1_0 = ws + 94208;
  const _Float16* Wf1_1 = ws + 94208 + 16384;
  const _Float16* Wf2_0 = ws + 126976;
  const _Float16* Wf2_1 = ws + 126976 + 16384;

  // ---- input staging: lidar -> cols 0..19, orig7 -> cols 32..38 ----
#pragma unroll
  for (int i = 0; i < 14; ++i) {
    const int idx = tid + i * 256;
    const int cidx = idx < 3456 ? idx : 3455;
    float v = data[base + cidx];
    asm volatile("" : "+v"(v));
    if (idx < 3456) {
      const int gi = idx / 1728;
      const int r = idx - gi * 1728;
      const int n = r / 27, f = r - n * 27;
      char* Gg = gi ? G1 : G0;
      if (f < 7) ast(Gg, n, 64 + f * 2, (_Float16)v);
      else       ast(Gg, n, (f - 7) * 2, (_Float16)v);
    }
  }
  if (tid < 128) {
    const int gi = tid >> 6, n = tid & 63;
    char* Gg = gi ? G1 : G0;
#pragma unroll
    for (int c = 20; c < 32; ++c) ast(Gg, n, c * 2, (_Float16)0.f);
#pragma unroll
    for (int c = 59; c < 64; ++c) ast(Gg, n, c * 2, (_Float16)0.f);
  }
  // pos (plain loads, auto-waited at mask)
  const float* pp = data + base + (long)(wv >> 1) * 1728 + lane * 27;
  const float px = pp[0], py = pp[1];
  lgkm0(); rbar();   // staged inputs visible to all waves

  // ---- adjacency mask (exact double cone + guard-band atan2 fallback) ----
  {
    const int g = wv >> 1;
    const float FOVF = (float)(0.35 * 3.14159265358979323846);
    const double TT = tan(0.35 * 3.14159265358979323846);
    const double T2 = TT * TT;
    for (int jj = 0; jj < 32; ++jj) {
      const int j = (wv & 1) * 32 + jj;
      const float x0j = __shfl(px, j, 64);
      const float x1j = __shfl(py, j, 64);
      const float dxf = px - x0j;
      const float dyf = py - x1j;
      const float dist = sqrtf(dxf * dxf + dyf * dyf);
      bool pred;
      if (lane == j || dist > 10.0f) {
        pred = false;
      } else if (dxf <= 0.0f) {
        pred = (dxf == 0.0f && dyf == 0.0f);
      } else {
        const double qa = (double)dyf * (double)dyf;
        const double qb = (double)dxf * (double)dxf * T2;
        if (qa <= qb * 0.99999) pred = true;
        else if (qa >= qb * 1.00001) pred = false;
        else pred = (fabsf((float)atan2((double)dyf, (double)dxf)) <= FOVF);
      }
      const u64 bal = __ballot(pred);
      if (lane == 0) sm.mcol[g][j] = bal | (1ull << j);
    }
  }

  // ---- issue params (2) + chunks q0,q1 -> FIFO [p0,p1,q0,q1] ----
  gload16(ws + 159744 + (size_t)tid * 8, sm.PB + (size_t)tid * 16);
  gload16(ws + 159744 + (size_t)(tid + 256) * 8, sm.PB + (size_t)(tid + 256) * 16);
  stage64(Wl1p, 32, 0, 0, wbase + 0 * 4096, tid);   // q0: L1a
  stage32(Wl2p, 0, wbase + 1 * 4096, tid);          // q1: L2a

  // ---- lidar MLP (hand-rolled, chunks q0..q3) ----
  h8 axl0, axl1;
  f4 l20[2], l21[2];
  l20[0] = l20[1] = l21[0] = l21[1] = (f4){0.f,0.f,0.f,0.f};
  // q0: L1a -> hidden half a at cols 64..127
  waitv<1>(); rbar();
  stage64(Wl1p, 32, 0, 1, wbase + 2 * 4096, tid);   // q2: L1b
  axl0 = ald8(G0, row0, kg * 16);
  axl1 = ald8(G1, row0, kg * 16);
  {
    const char* wb = wbase + 0 * 4096;
    f4 a0[4], a1[4];
#pragma unroll
    for (int t = 0; t < 4; ++t) { a0[t] = (f4){0.f,0.f,0.f,0.f}; a1[t] = (f4){0.f,0.f,0.f,0.f}; }
#pragma unroll
    for (int t = 0; t < 4; ++t) {
      const int o = t * 16 + lc;
      const int kq = kg ^ ((o >> 1) & 3);
      const h8 bf = *(const h8*)(wb + (o * 4 + kq) * 16);
      a0[t] = __builtin_amdgcn_mfma_f32_16x16x32_f16(axl0, bf, a0[t], 0, 0, 0);
      a1[t] = __builtin_amdgcn_mfma_f32_16x16x32_f16(axl1, bf, a1[t], 0, 0, 0);
    }
#pragma unroll
    for (int t = 0; t < 4; ++t) {
      const int col = t * 16 + lc;
      const float bv = (float)pb[0 * 128 + col];
#pragma unroll
      for (int r = 0; r < 4; ++r) {
        ast(G0, rb + r, 128 + col * 2, (_Float16)fmaxf(a0[t][r] + bv, 0.f));
        ast(G1, rb + r, 128 + col * 2, (_Float16)fmaxf(a1[t][r] + bv, 0.f));
      }
    }
  }
  // q1: L2a (K-half 0 from hidden half a)
  waitv<1>(); rbar();
  stage32(Wl2p, 1, wbase + 0 * 4096, tid);          // q3: L2b
  {
    const char* wb = wbase + 1 * 4096;
    h8 ah0[2], ah1[2];
#pragma unroll
    for (int i = 0; i < 2; ++i) {
      ah0[i] = ald8(G0, row0, 128 + i * 64 + kg * 16);
      ah1[i] = ald8(G1, row0, 128 + i * 64 + kg * 16);
    }
#pragma unroll
    for (int ks = 0; ks < 2; ++ks)
#pragma unroll
      for (int ct = 0; ct < 2; ++ct) {
        const int o = ct * 16 + lc;
        const int u = (ks * 4 + kg) ^ (o & 7);
        const h8 bf = *(const h8*)(wb + (o * 8 + u) * 16);
        l20[ct] = __builtin_amdgcn_mfma_f32_16x16x32_f16(ah0[ks], bf, l20[ct], 0, 0, 0);
        l21[ct] = __builtin_amdgcn_mfma_f32_16x16x32_f16(ah1[ks], bf, l21[ct], 0, 0, 0);
      }
  }
  // q2: L1b -> hidden half b overwrites cols 64..127
  waitv<1>(); rbar();
  stage64(W11p, 32, 0, 0, wbase + 1 * 4096, tid);   // q4: W11 oc0
  {
    const char* wb = wbase + 2 * 4096;
    f4 a0[4], a1[4];
#pragma unroll
    for (int t = 0; t < 4; ++t) { a0[t] = (f4){0.f,0.f,0.f,0.f}; a1[t] = (f4){0.f,0.f,0.f,0.f}; }
#pragma unroll
    for (int t = 0; t < 4; ++t) {
      const int o = t * 16 + lc;
      const int kq = kg ^ ((o >> 1) & 3);
      const h8 bf = *(const h8*)(wb + (o * 4 + kq) * 16);
      a0[t] = __builtin_amdgcn_mfma_f32_16x16x32_f16(axl0, bf, a0[t], 0, 0, 0);
      a1[t] = __builtin_amdgcn_mfma_f32_16x16x32_f16(axl1, bf, a1[t], 0, 0, 0);
    }
#pragma unroll
    for (int t = 0; t < 4; ++t) {
      const int col = t * 16 + lc;
      const float bv = (float)pb[0 * 128 + 64 + col];
#pragma unroll
      for (int r = 0; r < 4; ++r) {
        ast(G0, rb + r, 128 + col * 2, (_Float16)fmaxf(a0[t][r] + bv, 0.f));
        ast(G1, rb + r, 128 + col * 2, (_Float16)fmaxf(a1[t][r] + bv, 0.f));
      }
    }
  }
  // q3: L2b (K-half 1) -> lf20 into cols 39..58
  waitv<1>(); rbar();
  stage64(W11p, 32, 0, 1, wbase + 2 * 4096, tid);   // q5: W11 oc1
  {
    const char* wb = wbase + 0 * 4096;
    h8 ah0[2], ah1[2];
#pragma unroll
    for (int i = 0; i < 2; ++i) {
      ah0[i] = ald8(G0, row0, 128 + i * 64 + kg * 16);
      ah1[i] = ald8(G1, row0, 128 + i * 64 + kg * 16);
    }
#pragma unroll
    for (int ks = 0; ks < 2; ++ks)
#pragma unroll
      for (int ct = 0; ct < 2; ++ct) {
        const int o = ct * 16 + lc;
        const int u = (ks * 4 + kg) ^ (o & 7);
        const h8 bf = *(const h8*)(wb + (o * 8 + u) * 16);
        l20[ct] = __builtin_amdgcn_mfma_f32_16x16x32_f16(ah0[ks], bf, l20[ct], 0, 0, 0);
        l21[ct] = __builtin_amdgcn_mfma_f32_16x16x32_f16(ah1[ks], bf, l21[ct], 0, 0, 0);
      }
#pragma unroll
    for (int ct = 0; ct < 2; ++ct) {
      const int col = ct * 16 + lc;
      if (col < 20) {
        const float bv = (float)pb[1 * 128 + col];
#pragma unroll
        for (int r = 0; r < 4; ++r) {
          ast(G0, rb + r, 78 + col * 2, (_Float16)fmaxf(l20[ct][r] + bv, 0.f));
          ast(G1, rb + r, 78 + col * 2, (_Float16)fmaxf(l21[ct][r] + bv, 0.f));
        }
      }
    }
  }

  Resid2 rz{};
  // W11 Z-stage (q4,q5): Z1 = x . W11^T, in-place all 128 cols
  mm32_stage(W11p, G0, G1, wbase, 4, tid,
      [&](int s, char* buf) { stage64(W12p, 128, s, 0, buf, tid); });
  lgkm0(); rbar();
  // GIN1 agg: h1 = relu(M'^T Z1 + b11)
  agg_ip(sm.mcol[0], G0, pb, 2, tid);
  agg_ip(sm.mcol[1], G1, pb, 2, tid);
  lgkm0(); rbar();
  // W12: h = relu(h1 . W12^T + b12)
  mm128_stage<0, true, false>(W12p, G0, G1, pb, 3, -1, rz, wbase, 6, tid,
      [&](int s, char* buf) { stage64(W21p, 128, s, 0, buf, tid); });
  // Z2 = h . W21^T (raw)
  mm128_stage<1, false, false>(W21p, G0, G1, pb, 0, -1, rz, wbase, 14, tid,
      [&](int s, char* buf) { stage64(W22p, 128, s, 0, buf, tid); });
  lgkm0(); rbar();
  // GIN2 agg: h2a = relu(M'^T Z2 + b21)
  agg_ip(sm.mcol[0], G0, pb, 4, tid);
  agg_ip(sm.mcol[1], G1, pb, 4, tid);
  lgkm0(); rbar();
  // W22: t = relu(h2a . W22^T + b22)
  mm128_stage<0, true, false>(W22p, G0, G1, pb, 5, -1, rz, wbase, 22, tid,
      [&](int s, char* buf) { stage64(Wat0, 128, s, 0, buf, tid); });
  // transformer layer 0
  Resid2 r0 = mm128_stage<3, false, false>(Wat0, G0, G1, pb, 6, 12, rz, wbase, 30, tid,
      [&](int s, char* buf) { stage64(Wf1_0, 128, s, 0, buf, tid); });
  mm128_stage<0, true, false>(Wf1_0, G0, G1, pb, 8, -1, rz, wbase, 38, tid,
      [&](int s, char* buf) { stage64(Wf2_0, 128, s, 0, buf, tid); });
  mm128_stage<4, false, false>(Wf2_0, G0, G1, pb, 9, 14, r0, wbase, 46, tid,
      [&](int s, char* buf) { stage64(Wat1, 128, s, 0, buf, tid); });
  // transformer layer 1
  Resid2 r1 = mm128_stage<3, false, false>(Wat1, G0, G1, pb, 7, 16, rz, wbase, 54, tid,
      [&](int s, char* buf) { stage64(Wf1_1, 128, s, 0, buf, tid); });
  mm128_stage<0, true, false>(Wf1_1, G0, G1, pb, 10, -1, rz, wbase, 62, tid,
      [&](int s, char* buf) { stage64(Wf2_1, 128, s, 0, buf, tid); });
  mm128_stage<4, false, true>(Wf2_1, G0, G1, pb, 11, 18, r1, wbase, 70, tid,
      [&](int, char*) {});

  // ---- head (wave-local rows) ----
#pragma unroll
  for (int g = 0; g < 2; ++g) {
    const char* Pg = g ? G1 : G0;
    const int n = tid >> 2, q = tid & 3;
    float s = 0.f;
#pragma unroll
    for (int u = 0; u < 4; ++u) {
      const h8 v = ald8(Pg, n, q * 64 + u * 16);
      const float4 w0 = *(const float4*)(Wfc + q * 32 + u * 8);
      const float4 w1 = *(const float4*)(Wfc + q * 32 + u * 8 + 4);
      s = fmaf((float)v[0], w0.x, s); s = fmaf((float)v[1], w0.y, s);
      s = fmaf((float)v[2], w0.z, s); s = fmaf((float)v[3], w0.w, s);
      s = fmaf((float)v[4], w1.x, s); s = fmaf((float)v[5], w1.y, s);
      s = fmaf((float)v[6], w1.z, s); s = fmaf((float)v[7], w1.w, s);
    }
    s += __shfl_xor(s, 1, 64);
    s += __shfl_xor(s, 2, 64);
    if (q == 0) out[((long)b * 2 + g) * NN + n] = s + bfc[0];
  }
}

extern "C" void kernel_launch(void* const* d_in, const int* in_sizes, int n_in,
                              void* d_out, int out_size, void* d_ws, size_t ws_size,
                              hipStream_t stream) {
  const float* data  = (const float*)d_in[0];
  const float* W_l1  = (const float*)d_in[1];
  const float* b_l1  = (const float*)d_in[2];
  const float* W_l2  = (const float*)d_in[3];
  const float* b_l2  = (const float*)d_in[4];
  const float* W11   = (const float*)d_in[5];
  const float* b11   = (const float*)d_in[6];
  const float* W12   = (const float*)d_in[7];
  const float* b12   = (const float*)d_in[8];
  const float* W21   = (const float*)d_in[9];
  const float* b21   = (const float*)d_in[10];
  const float* W22   = (const float*)d_in[11];
  const float* b22   = (const float*)d_in[12];
  const float* Wqkv  = (const float*)d_in[13];
  const float* bqkv  = (const float*)d_in[14];
  const float* Wo    = (const float*)d_in[15];
  const float* bo    = (const float*)d_in[16];
  const float* ln1_g = (const float*)d_in[17];
  const float* ln1_b = (const float*)d_in[18];
  const float* Wf1   = (const float*)d_in[19];
  const float* bf1   = (const float*)d_in[20];
  const float* Wf2   = (const float*)d_in[21];
  const float* bf2   = (const float*)d_in[22];
  const float* ln2_g = (const float*)d_in[23];
  const float* ln2_b = (const float*)d_in[24];
  const float* Wfc   = (const float*)d_in[25];
  const float* bfc   = (const float*)d_in[26];

  _Float16* ws = (_Float16*)d_ws;

  prepA<<<dim3(640), dim3(256), 0, stream>>>(
      W_l1, W_l2, W11, W12, W21, W22, Wf1, Wf2,
      b_l1, b_l2, b11, b12, b21, b22, bf1, bf2,
      ln1_g, ln1_b, ln2_g, ln2_b, ws);
  prepB<<<dim3(129), dim3(256), 0, stream>>>(Wqkv, bqkv, Wo, bo, ws);

  gin_critic_kernel<<<dim3(NB / 2), dim3(256), 0, stream>>>(
      data, Wfc, bfc, ws, (float*)d_out);
}

// Round 10
// 298.018 us; speedup vs baseline: 1.1510x; 1.1510x over previous
//
#include <hip/hip_runtime.h>
#include <math.h>

#define NB 4096
#define NN 64

typedef _Float16 h8 __attribute__((ext_vector_type(8)));
typedef float f4 __attribute__((ext_vector_type(4)));
typedef unsigned long long u64;

typedef const __attribute__((address_space(1))) void* gas_t;
typedef __attribute__((address_space(3))) void* las_t;

__device__ __forceinline__ void gload16(const void* g, void* l) {
  __builtin_amdgcn_global_load_lds((gas_t)g, (las_t)l, 16, 0, 0);
}
__device__ __forceinline__ void rbar() {
  asm volatile("" ::: "memory");
  __builtin_amdgcn_s_barrier();
  asm volatile("" ::: "memory");
}
__device__ __forceinline__ void lgkm0() {
  asm volatile("s_waitcnt lgkmcnt(0)" ::: "memory");
}
template<int N> __device__ __forceinline__ void waitv() {
  if constexpr (N == 0) asm volatile("s_waitcnt vmcnt(0)" ::: "memory");
  else                  asm volatile("s_waitcnt vmcnt(1)" ::: "memory");
  __builtin_amdgcn_sched_barrier(0);
}

// activation buffers: 64 rows x 128 f16, 256 B row stride, byte ^= (row&7)<<4
__device__ __forceinline__ int aoff(int row, int colb) {
  return row * 256 + (colb ^ ((row & 7) << 4));
}
__device__ __forceinline__ h8 ald8(const char* a, int row, int colb) {
  return *(const h8*)(a + aoff(row, colb));
}
__device__ __forceinline__ void ast8(char* a, int row, int colb, h8 v) {
  *(h8*)(a + aoff(row, colb)) = v;
}
__device__ __forceinline__ _Float16 ald(const char* a, int row, int colb) {
  return *(const _Float16*)(a + aoff(row, colb));
}
__device__ __forceinline__ void ast(char* a, int row, int colb, _Float16 v) {
  *(_Float16*)(a + aoff(row, colb)) = v;
}

// ---------------- weight prep ----------------
// f16 ws: 0 Wl1p[128][32] | 4096 Wl2p[32][128] | 8192 W11p[128][32] |
// 12288 W12 | 28672 W21 | 45056 W22 | 61440 Wat 2x[128][128] (Wo.Wv fused) |
// 94208 Wf1 2x | 126976 Wf2 2x | 159744 params [32][128] f16
// params idx: 0 b_l1 1 b_l2 2 b11 3 b12 4 b21 5 b22 6 bat0 7 bat1
//             8 bf1_0 9 bf2_0 10 bf1_1 11 bf2_1 12 ln1g0 13 ln1b0 14 ln2g0
//             15 ln2b0 16 ln1g1 17 ln1b1 18 ln2g1 19 ln2b1 20..31 zero
__global__ void prepA(
    const float* __restrict__ W_l1, const float* __restrict__ W_l2,
    const float* __restrict__ W11, const float* __restrict__ W12,
    const float* __restrict__ W21, const float* __restrict__ W22,
    const float* __restrict__ Wf1, const float* __restrict__ Wf2,
    const float* __restrict__ b_l1, const float* __restrict__ b_l2,
    const float* __restrict__ b11, const float* __restrict__ b12,
    const float* __restrict__ b21, const float* __restrict__ b22,
    const float* __restrict__ bf1, const float* __restrict__ bf2,
    const float* __restrict__ ln1_g, const float* __restrict__ ln1_b,
    const float* __restrict__ ln2_g, const float* __restrict__ ln2_b,
    _Float16* __restrict__ ws)
{
  const int e = blockIdx.x * 256 + threadIdx.x;
  float v;
  if (e < 4096) { const int o = e >> 5, k = e & 31; v = (k < 20) ? W_l1[o * 20 + k] : 0.f; }
  else if (e < 8192) { const int i = e - 4096; const int o = i >> 7, k = i & 127; v = (o < 20) ? W_l2[o * 128 + k] : 0.f; }
  else if (e < 12288) { const int i = e - 8192; const int o = i >> 5, k = i & 31; v = (k < 27) ? W11[o * 27 + k] : 0.f; }
  else if (e < 28672) v = W12[e - 12288];
  else if (e < 45056) v = W21[e - 28672];
  else if (e < 61440) v = W22[e - 45056];
  else if (e < 94208) return;                      // Wat by prepB
  else if (e < 126976) v = Wf1[e - 94208];
  else if (e < 159744) v = Wf2[e - 126976];
  else {
    const int p = e - 159744, idx = p >> 7, col = p & 127;
    switch (idx) {
      case 0: v = b_l1[col]; break;
      case 1: v = (col < 20) ? b_l2[col] : 0.f; break;
      case 2: v = b11[col]; break;
      case 3: v = b12[col]; break;
      case 4: v = b21[col]; break;
      case 5: v = b22[col]; break;
      case 8: v = bf1[col]; break;
      case 9: v = bf2[col]; break;
      case 10: v = bf1[128 + col]; break;
      case 11: v = bf2[128 + col]; break;
      case 12: v = ln1_g[col]; break;
      case 13: v = ln1_b[col]; break;
      case 14: v = ln2_g[col]; break;
      case 15: v = ln2_b[col]; break;
      case 16: v = ln1_g[128 + col]; break;
      case 17: v = ln1_b[128 + col]; break;
      case 18: v = ln2_g[128 + col]; break;
      case 19: v = ln2_b[128 + col]; break;
      default: v = 0.f; break;                      // 6,7 by prepB; 20+ zero
    }
  }
  ws[e] = (_Float16)v;
}

__global__ void prepB(
    const float* __restrict__ Wqkv, const float* __restrict__ bqkv,
    const float* __restrict__ Wo, const float* __restrict__ bo,
    _Float16* __restrict__ ws)
{
  if (blockIdx.x < 128) {
    const int e = blockIdx.x * 256 + threadIdx.x;       // 0..32767
    const int l = e >> 14, r = e & 16383, o = r >> 7, k = r & 127;
    const float* wo = Wo + (l * 128 + o) * 128;
    const float* wv = Wqkv + l * 49152 + 32768 + k;
    float acc = 0.f;
#pragma unroll 4
    for (int m = 0; m < 128; ++m) acc += wo[m] * wv[m * 128];
    ws[61440 + e] = (_Float16)acc;
  } else {
    const int t = threadIdx.x;                          // bat[2][128]
    const int l = t >> 7, o = t & 127;
    const float* wo = Wo + (l * 128 + o) * 128;
    const float* bv = bqkv + l * 384 + 256;
    float acc = bo[l * 128 + o];
    for (int m = 0; m < 128; ++m) acc += bv[m] * wo[m];
    ws[159744 + (6 + l) * 128 + o] = (_Float16)acc;
  }
}

// ---------------- chunk staging (4 KB, pre-swizzled source) ----------------
__device__ __forceinline__ void stage64(const _Float16* __restrict__ Wp, int KT,
                                        int kc, int oc, char* buf, int tid) {
  const int o = tid >> 2, kq = tid & 3;
  const int kreal = kq ^ ((o >> 1) & 3);
  gload16(Wp + (oc * 64 + o) * KT + kc * 32 + kreal * 8, buf + tid * 16);
}
__device__ __forceinline__ void stage32(const _Float16* __restrict__ Wp,
                                        int kc, char* buf, int tid) {
  const int o = tid >> 3, u = tid & 7;
  const int ureal = u ^ (o & 7);
  gload16(Wp + o * 128 + kc * 64 + ureal * 8, buf + tid * 16);
}

// residual capture: c0/c1 = per-graph, [r] = row, elem oc*4+t = col slot
struct Cap { h8 c0[4]; h8 c1[4]; };

// ---------------- 8-chunk matmul stage, both graphs, in-place ----------------
// oc-major chunks; acc released per 64-col half (32 VGPRs, not 128).
// EPI: 0 bias+relu | 1 raw | 2 bias+resid(in-place G) | 3 bias+resid(from rin)
// CAP: capture pre-overwrite G values (the FF2 residual) in FF1.
template<int EPI, bool CAP, bool LAST, typename PF>
__device__ __forceinline__ Cap mm128_stage(
    const _Float16* __restrict__ Wp, char* g0, char* g1,
    const _Float16* pb, int bidx, Cap rin,
    char* wbase, int q0, int tid, PF&& pf)
{
  const int lane = tid & 63, wv = tid >> 6, lc = lane & 15, kg = lane >> 4;
  const int row0 = wv * 16 + lc, rb = wv * 16 + kg * 4;

  h8 af0[4], af1[4];     // hoisted before any in-place write
#pragma unroll
  for (int i = 0; i < 4; ++i) {
    af0[i] = ald8(g0, row0, i * 64 + kg * 16);
    af1[i] = ald8(g1, row0, i * 64 + kg * 16);
  }
  Cap rout{};
#pragma unroll
  for (int oc = 0; oc < 2; ++oc) {
    f4 a0[4], a1[4];
#pragma unroll
    for (int t = 0; t < 4; ++t) { a0[t] = (f4){0.f,0.f,0.f,0.f}; a1[t] = (f4){0.f,0.f,0.f,0.f}; }
#pragma unroll
    for (int kc = 0; kc < 4; ++kc) {
      const int ql = oc * 4 + kc;
      if (LAST && ql == 7) waitv<0>(); else waitv<1>();
      rbar();
      const int s = ql + 2;
      char* nbuf = wbase + ((q0 + s) % 3) * 4096;
      if (s < 8) stage64(Wp, 128, s & 3, s >> 2, nbuf, tid);
      else pf(s - 8, nbuf);
      const char* wb = wbase + ((q0 + ql) % 3) * 4096;
#pragma unroll
      for (int t = 0; t < 4; ++t) {
        const int o = t * 16 + lc;
        const int kq = kg ^ ((o >> 1) & 3);
        const h8 bf = *(const h8*)(wb + (o * 4 + kq) * 16);
        a0[t] = __builtin_amdgcn_mfma_f32_16x16x32_f16(af0[kc], bf, a0[t], 0, 0, 0);
        a1[t] = __builtin_amdgcn_mfma_f32_16x16x32_f16(af1[kc], bf, a1[t], 0, 0, 0);
      }
    }
    // epilogue for this 64-col half
#pragma unroll
    for (int t = 0; t < 4; ++t) {
      const int col = oc * 64 + t * 16 + lc;
      const float bv = (EPI == 1) ? 0.f : (float)pb[bidx * 128 + col];
#pragma unroll
      for (int r = 0; r < 4; ++r) {
        float v0 = a0[t][r] + bv, v1 = a1[t][r] + bv;
        if constexpr (EPI == 2) {
          v0 += (float)ald(g0, rb + r, col * 2);
          v1 += (float)ald(g1, rb + r, col * 2);
        }
        if constexpr (EPI == 3) {
          v0 += (float)rin.c0[r][oc * 4 + t];
          v1 += (float)rin.c1[r][oc * 4 + t];
        }
        if constexpr (EPI == 0) { v0 = fmaxf(v0, 0.f); v1 = fmaxf(v1, 0.f); }
        if constexpr (CAP) {
          rout.c0[r][oc * 4 + t] = ald(g0, rb + r, col * 2);   // capture t' before overwrite
          rout.c1[r][oc * 4 + t] = ald(g1, rb + r, col * 2);
        }
        ast(g0, rb + r, col * 2, (_Float16)v0);
        ast(g1, rb + r, col * 2, (_Float16)v1);
      }
    }
  }
  return rout;
}

// W11 raw Z-stage: K=32 (A = cols 32..63), 2 chunks (oc halves), in-place
template<typename PF>
__device__ __forceinline__ void mm32z_stage(
    const _Float16* __restrict__ Wp, char* g0, char* g1,
    char* wbase, int q0, int tid, PF&& pf)
{
  const int lane = tid & 63, wv = tid >> 6, lc = lane & 15, kg = lane >> 4;
  const int row0 = wv * 16 + lc, rb = wv * 16 + kg * 4;
  const h8 af0 = ald8(g0, row0, 64 + kg * 16);
  const h8 af1 = ald8(g1, row0, 64 + kg * 16);
#pragma unroll
  for (int oc = 0; oc < 2; ++oc) {
    waitv<1>(); rbar();
    pf(oc, wbase + ((q0 + oc + 2) % 3) * 4096);
    const char* wb = wbase + ((q0 + oc) % 3) * 4096;
    f4 a0[4], a1[4];
#pragma unroll
    for (int t = 0; t < 4; ++t) { a0[t] = (f4){0.f,0.f,0.f,0.f}; a1[t] = (f4){0.f,0.f,0.f,0.f}; }
#pragma unroll
    for (int t = 0; t < 4; ++t) {
      const int o = t * 16 + lc;
      const int kq = kg ^ ((o >> 1) & 3);
      const h8 bf = *(const h8*)(wb + (o * 4 + kq) * 16);
      a0[t] = __builtin_amdgcn_mfma_f32_16x16x32_f16(af0, bf, a0[t], 0, 0, 0);
      a1[t] = __builtin_amdgcn_mfma_f32_16x16x32_f16(af1, bf, a1[t], 0, 0, 0);
    }
#pragma unroll
    for (int t = 0; t < 4; ++t) {
      const int col = oc * 64 + t * 16 + lc;
#pragma unroll
      for (int r = 0; r < 4; ++r) {
        ast(g0, rb + r, col * 2, (_Float16)a0[t][r]);
        ast(g1, rb + r, col * 2, (_Float16)a1[t][r]);
      }
    }
  }
}

// in-place MFMA aggregation + bias + relu: G <- relu(M'^T G + b)
// internal read->barrier->write fence (cross-wave row reads)
__device__ __forceinline__ void agg_ip(const u64* mc, char* G, const _Float16* pb,
                                       int bidx, int tid)
{
  const int lane = tid & 63, wv = tid >> 6, lc = lane & 15, kg = lane >> 4;
  const int c0 = wv * 32 + lc;
  u64 mrow[4];
#pragma unroll
  for (int rt = 0; rt < 4; ++rt) mrow[rt] = mc[rt * 16 + lc];
  h8 bf[2][2];
#pragma unroll
  for (int ks = 0; ks < 2; ++ks)
#pragma unroll
    for (int ct = 0; ct < 2; ++ct)
#pragma unroll
      for (int e = 0; e < 8; ++e)
        bf[ks][ct][e] = ald(G, ks * 32 + kg * 8 + e, (c0 + ct * 16) * 2);
  lgkm0(); rbar();                    // all waves' reads in regs before any write
  f4 acc[4][2];
#pragma unroll
  for (int rt = 0; rt < 4; ++rt) { acc[rt][0] = (f4){0.f,0.f,0.f,0.f}; acc[rt][1] = (f4){0.f,0.f,0.f,0.f}; }
#pragma unroll
  for (int ks = 0; ks < 2; ++ks)
#pragma unroll
    for (int rt = 0; rt < 4; ++rt) {
      const unsigned int byte = (unsigned int)(mrow[rt] >> (ks * 32 + kg * 8)) & 0xffu;
      h8 af;
#pragma unroll
      for (int e = 0; e < 8; ++e) af[e] = (_Float16)((byte >> e) & 1u);
#pragma unroll
      for (int ct = 0; ct < 2; ++ct)
        acc[rt][ct] = __builtin_amdgcn_mfma_f32_16x16x32_f16(af, bf[ks][ct], acc[rt][ct], 0, 0, 0);
    }
#pragma unroll
  for (int ct = 0; ct < 2; ++ct) {
    const int col = c0 + ct * 16;
    const float bv = (float)pb[bidx * 128 + col];
#pragma unroll
    for (int rt = 0; rt < 4; ++rt)
#pragma unroll
      for (int qq = 0; qq < 4; ++qq)
        ast(G, rt * 16 + kg * 4 + qq, col * 2, (_Float16)fmaxf(acc[rt][ct][qq] + bv, 0.f));
  }
}

// standalone in-place LN, wave-local rows (n = tid>>2), f16 params from PB
__device__ __forceinline__ void layer_norm(char* buf, const _Float16* pb, int lnidx, int tid)
{
  const int n = tid >> 2, q = tid & 3;
  float vals[32];
#pragma unroll
  for (int u = 0; u < 4; ++u) {
    const h8 v = ald8(buf, n, q * 64 + u * 16);
#pragma unroll
    for (int e = 0; e < 8; ++e) vals[u * 8 + e] = (float)v[e];
  }
  float s = 0.f;
#pragma unroll
  for (int u = 0; u < 32; ++u) s += vals[u];
  s += __shfl_xor(s, 1, 64);
  s += __shfl_xor(s, 2, 64);
  const float mean = s * 0.0078125f;
  float vv = 0.f;
#pragma unroll
  for (int u = 0; u < 32; ++u) { const float d = vals[u] - mean; vv = fmaf(d, d, vv); }
  vv += __shfl_xor(vv, 1, 64);
  vv += __shfl_xor(vv, 2, 64);
  const float rstd = 1.0f / sqrtf(vv * 0.0078125f + 1e-5f);
#pragma unroll
  for (int u = 0; u < 4; ++u) {
    h8 o;
#pragma unroll
    for (int e = 0; e < 8; ++e) {
      const int col = q * 32 + u * 8 + e;
      const float gg = (float)pb[lnidx * 128 + col];
      const float bb = (float)pb[(lnidx + 1) * 128 + col];
      o[e] = (_Float16)((vals[u * 8 + e] - mean) * rstd * gg + bb);
    }
    ast8(buf, n, q * 64 + u * 16, o);
  }
}

struct SM {
  alignas(16) char G0[16384];
  alignas(16) char G1[16384];
  alignas(16) char WB[12288];
  alignas(16) char PB[8192];       // params [32][128] f16
  u64 mcol[2][64];
};   // 54272 B -> 3 blocks/CU

__global__ __launch_bounds__(256, 3)
void gin_critic_kernel(
    const float* __restrict__ data,
    const float* __restrict__ Wfc, const float* __restrict__ bfc,
    const _Float16* __restrict__ ws,
    float* __restrict__ out)
{
  __shared__ SM sm;
  const int tid = threadIdx.x;
  const int lane = tid & 63, wv = tid >> 6, lc = lane & 15, kg = lane >> 4;
  const int row0 = wv * 16 + lc, rb = wv * 16 + kg * 4;
  const int b = blockIdx.x;
  const long base = (long)b * 2 * NN * 27;
  char* G0 = sm.G0; char* G1 = sm.G1; char* wbase = sm.WB;
  const _Float16* pb = (const _Float16*)sm.PB;

  const _Float16* Wl1p = ws + 0;
  const _Float16* Wl2p = ws + 4096;
  const _Float16* W11p = ws + 8192;
  const _Float16* W12p = ws + 12288;
  const _Float16* W21p = ws + 28672;
  const _Float16* W22p = ws + 45056;
  const _Float16* Wat0 = ws + 61440;
  const _Float16* Wat1 = ws + 61440 + 16384;
  const _Float16* Wf1_0 = ws + 94208;
  const _Float16* Wf1_1 = ws + 94208 + 16384;
  const _Float16* Wf2_0 = ws + 126976;
  const _Float16* Wf2_1 = ws + 126976 + 16384;

  // ---- input staging: lidar -> cols 0..19, orig7 -> cols 32..38 ----
#pragma unroll
  for (int i = 0; i < 14; ++i) {
    const int idx = tid + i * 256;
    const int cidx = idx < 3456 ? idx : 3455;
    float v = data[base + cidx];
    asm volatile("" : "+v"(v));
    if (idx < 3456) {
      const int gi = idx / 1728;
      const int r = idx - gi * 1728;
      const int n = r / 27, f = r - n * 27;
      char* Gg = gi ? G1 : G0;
      if (f < 7) ast(Gg, n, 64 + f * 2, (_Float16)v);
      else       ast(Gg, n, (f - 7) * 2, (_Float16)v);
    }
  }
  if (tid < 128) {
    const int gi = tid >> 6, n = tid & 63;
    char* Gg = gi ? G1 : G0;
#pragma unroll
    for (int c = 20; c < 32; ++c) ast(Gg, n, c * 2, (_Float16)0.f);
#pragma unroll
    for (int c = 59; c < 64; ++c) ast(Gg, n, c * 2, (_Float16)0.f);
  }
  const float* pp = data + base + (long)(wv >> 1) * 1728 + lane * 27;
  const float px = pp[0], py = pp[1];
  lgkm0(); rbar();   // staged inputs visible

  // ---- adjacency mask (exact double cone + guard-band atan2 fallback) ----
  {
    const int g = wv >> 1;
    const float FOVF = (float)(0.35 * 3.14159265358979323846);
    const double TT = tan(0.35 * 3.14159265358979323846);
    const double T2 = TT * TT;
    for (int jj = 0; jj < 32; ++jj) {
      const int j = (wv & 1) * 32 + jj;
      const float x0j = __shfl(px, j, 64);
      const float x1j = __shfl(py, j, 64);
      const float dxf = px - x0j;
      const float dyf = py - x1j;
      const float dist = sqrtf(dxf * dxf + dyf * dyf);
      bool pred;
      if (lane == j || dist > 10.0f) {
        pred = false;
      } else if (dxf <= 0.0f) {
        pred = (dxf == 0.0f && dyf == 0.0f);
      } else {
        const double qa = (double)dyf * (double)dyf;
        const double qb = (double)dxf * (double)dxf * T2;
        if (qa <= qb * 0.99999) pred = true;
        else if (qa >= qb * 1.00001) pred = false;
        else pred = (fabsf((float)atan2((double)dyf, (double)dxf)) <= FOVF);
      }
      const u64 bal = __ballot(pred);
      if (lane == 0) sm.mcol[g][j] = bal | (1ull << j);
    }
  }

  // ---- FIFO start: params (2) + chunks q0,q1 ----
  gload16(ws + 159744 + (size_t)tid * 8, sm.PB + (size_t)tid * 16);
  gload16(ws + 159744 + (size_t)(tid + 256) * 8, sm.PB + (size_t)(tid + 256) * 16);
  stage64(Wl1p, 32, 0, 0, wbase + 0 * 4096, tid);   // q0: L1a
  stage32(Wl2p, 0, wbase + 1 * 4096, tid);          // q1: L2a

  // ---- lidar MLP (hand-rolled, chunks q0..q3, hidden time-shared in cols 64..127) ----
  h8 axl0, axl1;
  f4 l20[2], l21[2];
  l20[0] = l20[1] = l21[0] = l21[1] = (f4){0.f,0.f,0.f,0.f};
  // q0: L1a -> hidden[0..63] at cols 64..127
  waitv<1>(); rbar();
  stage64(Wl1p, 32, 0, 1, wbase + 2 * 4096, tid);   // q2: L1b
  axl0 = ald8(G0, row0, kg * 16);
  axl1 = ald8(G1, row0, kg * 16);
  {
    const char* wb = wbase + 0 * 4096;
    f4 a0[4], a1[4];
#pragma unroll
    for (int t = 0; t < 4; ++t) { a0[t] = (f4){0.f,0.f,0.f,0.f}; a1[t] = (f4){0.f,0.f,0.f,0.f}; }
#pragma unroll
    for (int t = 0; t < 4; ++t) {
      const int o = t * 16 + lc;
      const int kq = kg ^ ((o >> 1) & 3);
      const h8 bf = *(const h8*)(wb + (o * 4 + kq) * 16);
      a0[t] = __builtin_amdgcn_mfma_f32_16x16x32_f16(axl0, bf, a0[t], 0, 0, 0);
      a1[t] = __builtin_amdgcn_mfma_f32_16x16x32_f16(axl1, bf, a1[t], 0, 0, 0);
    }
#pragma unroll
    for (int t = 0; t < 4; ++t) {
      const int col = t * 16 + lc;
      const float bv = (float)pb[0 * 128 + col];
#pragma unroll
      for (int r = 0; r < 4; ++r) {
        ast(G0, rb + r, 128 + col * 2, (_Float16)fmaxf(a0[t][r] + bv, 0.f));
        ast(G1, rb + r, 128 + col * 2, (_Float16)fmaxf(a1[t][r] + bv, 0.f));
      }
    }
  }
  // q1: L2a (K-half 0)
  waitv<1>(); rbar();
  stage32(Wl2p, 1, wbase + 0 * 4096, tid);          // q3: L2b
  {
    const char* wb = wbase + 1 * 4096;
    h8 ah0[2], ah1[2];
#pragma unroll
    for (int i = 0; i < 2; ++i) {
      ah0[i] = ald8(G0, row0, 128 + i * 64 + kg * 16);
      ah1[i] = ald8(G1, row0, 128 + i * 64 + kg * 16);
    }
#pragma unroll
    for (int ks = 0; ks < 2; ++ks)
#pragma unroll
      for (int ct = 0; ct < 2; ++ct) {
        const int o = ct * 16 + lc;
        const int u = (ks * 4 + kg) ^ (o & 7);
        const h8 bf = *(const h8*)(wb + (o * 8 + u) * 16);
        l20[ct] = __builtin_amdgcn_mfma_f32_16x16x32_f16(ah0[ks], bf, l20[ct], 0, 0, 0);
        l21[ct] = __builtin_amdgcn_mfma_f32_16x16x32_f16(ah1[ks], bf, l21[ct], 0, 0, 0);
      }
  }
  // q2: L1b -> hidden[64..127] overwrites cols 64..127
  waitv<1>(); rbar();
  stage64(W11p, 32, 0, 0, wbase + 1 * 4096, tid);   // q4: W11 oc0
  {
    const char* wb = wbase + 2 * 4096;
    f4 a0[4], a1[4];
#pragma unroll
    for (int t = 0; t < 4; ++t) { a0[t] = (f4){0.f,0.f,0.f,0.f}; a1[t] = (f4){0.f,0.f,0.f,0.f}; }
#pragma unroll
    for (int t = 0; t < 4; ++t) {
      const int o = t * 16 + lc;
      const int kq = kg ^ ((o >> 1) & 3);
      const h8 bf = *(const h8*)(wb + (o * 4 + kq) * 16);
      a0[t] = __builtin_amdgcn_mfma_f32_16x16x32_f16(axl0, bf, a0[t], 0, 0, 0);
      a1[t] = __builtin_amdgcn_mfma_f32_16x16x32_f16(axl1, bf, a1[t], 0, 0, 0);
    }
#pragma unroll
    for (int t = 0; t < 4; ++t) {
      const int col = t * 16 + lc;
      const float bv = (float)pb[0 * 128 + 64 + col];
#pragma unroll
      for (int r = 0; r < 4; ++r) {
        ast(G0, rb + r, 128 + col * 2, (_Float16)fmaxf(a0[t][r] + bv, 0.f));
        ast(G1, rb + r, 128 + col * 2, (_Float16)fmaxf(a1[t][r] + bv, 0.f));
      }
    }
  }
  // q3: L2b (K-half 1) -> lf20 into cols 39..58
  waitv<1>(); rbar();
  stage64(W11p, 32, 0, 1, wbase + 2 * 4096, tid);   // q5: W11 oc1
  {
    const char* wb = wbase + 0 * 4096;
    h8 ah0[2], ah1[2];
#pragma unroll
    for (int i = 0; i < 2; ++i) {
      ah0[i] = ald8(G0, row0, 128 + i * 64 + kg * 16);
      ah1[i] = ald8(G1, row0, 128 + i * 64 + kg * 16);
    }
#pragma unroll
    for (int ks = 0; ks < 2; ++ks)
#pragma unroll
      for (int ct = 0; ct < 2; ++ct) {
        const int o = ct * 16 + lc;
        const int u = (ks * 4 + kg) ^ (o & 7);
        const h8 bf = *(const h8*)(wb + (o * 8 + u) * 16);
        l20[ct] = __builtin_amdgcn_mfma_f32_16x16x32_f16(ah0[ks], bf, l20[ct], 0, 0, 0);
        l21[ct] = __builtin_amdgcn_mfma_f32_16x16x32_f16(ah1[ks], bf, l21[ct], 0, 0, 0);
      }
#pragma unroll
    for (int ct = 0; ct < 2; ++ct) {
      const int col = ct * 16 + lc;
      if (col < 20) {
        const float bv = (float)pb[1 * 128 + col];
#pragma unroll
        for (int r = 0; r < 4; ++r) {
          ast(G0, rb + r, 78 + col * 2, (_Float16)fmaxf(l20[ct][r] + bv, 0.f));
          ast(G1, rb + r, 78 + col * 2, (_Float16)fmaxf(l21[ct][r] + bv, 0.f));
        }
      }
    }
  }

  Cap rz{};
  // W11 Z-stage (q4,q5): Z1 = x.W11^T
  mm32z_stage(W11p, G0, G1, wbase, 4, tid,
      [&](int s, char* buf) { stage64(W12p, 128, s, 0, buf, tid); });
  lgkm0(); rbar();
  agg_ip(sm.mcol[0], G0, pb, 2, tid);    // h1 = relu(M'^T Z1 + b11)
  agg_ip(sm.mcol[1], G1, pb, 2, tid);
  lgkm0(); rbar();
  // W12
  mm128_stage<0, false, false>(W12p, G0, G1, pb, 3, rz, wbase, 6, tid,
      [&](int s, char* buf) { stage64(W21p, 128, s, 0, buf, tid); });
  // Z2 = h.W21^T (raw)
  mm128_stage<1, false, false>(W21p, G0, G1, pb, 0, rz, wbase, 14, tid,
      [&](int s, char* buf) { stage64(W22p, 128, s, 0, buf, tid); });
  lgkm0(); rbar();
  agg_ip(sm.mcol[0], G0, pb, 4, tid);    // h2 = relu(M'^T Z2 + b21)
  agg_ip(sm.mcol[1], G1, pb, 4, tid);
  lgkm0(); rbar();
  // W22: t
  mm128_stage<0, false, false>(W22p, G0, G1, pb, 5, rz, wbase, 22, tid,
      [&](int s, char* buf) { stage64(Wat0, 128, s, 0, buf, tid); });
  // ---- transformer layer 0 ----
  mm128_stage<2, false, false>(Wat0, G0, G1, pb, 6, rz, wbase, 30, tid,
      [&](int s, char* buf) { stage64(Wf1_0, 128, s, 0, buf, tid); });
  layer_norm(G0, pb, 12, tid);
  layer_norm(G1, pb, 12, tid);
  Cap c0 = mm128_stage<0, true, false>(Wf1_0, G0, G1, pb, 8, rz, wbase, 38, tid,
      [&](int s, char* buf) { stage64(Wf2_0, 128, s, 0, buf, tid); });
  mm128_stage<3, false, false>(Wf2_0, G0, G1, pb, 9, c0, wbase, 46, tid,
      [&](int s, char* buf) { stage64(Wat1, 128, s, 0, buf, tid); });
  layer_norm(G0, pb, 14, tid);
  layer_norm(G1, pb, 14, tid);
  // ---- transformer layer 1 ----
  mm128_stage<2, false, false>(Wat1, G0, G1, pb, 7, rz, wbase, 54, tid,
      [&](int s, char* buf) { stage64(Wf1_1, 128, s, 0, buf, tid); });
  layer_norm(G0, pb, 16, tid);
  layer_norm(G1, pb, 16, tid);
  Cap c1 = mm128_stage<0, true, false>(Wf1_1, G0, G1, pb, 10, rz, wbase, 62, tid,
      [&](int s, char* buf) { stage64(Wf2_1, 128, s, 0, buf, tid); });
  mm128_stage<3, false, true>(Wf2_1, G0, G1, pb, 11, c1, wbase, 70, tid,
      [&](int, char*) {});
  layer_norm(G0, pb, 18, tid);
  layer_norm(G1, pb, 18, tid);

  // ---- head (wave-local rows) ----
#pragma unroll
  for (int g = 0; g < 2; ++g) {
    const char* Pg = g ? G1 : G0;
    const int n = tid >> 2, q = tid & 3;
    float s = 0.f;
#pragma unroll
    for (int u = 0; u < 4; ++u) {
      const h8 v = ald8(Pg, n, q * 64 + u * 16);
      const float4 w0 = *(const float4*)(Wfc + q * 32 + u * 8);
      const float4 w1 = *(const float4*)(Wfc + q * 32 + u * 8 + 4);
      s = fmaf((float)v[0], w0.x, s); s = fmaf((float)v[1], w0.y, s);
      s = fmaf((float)v[2], w0.z, s); s = fmaf((float)v[3], w0.w, s);
      s = fmaf((float)v[4], w1.x, s); s = fmaf((float)v[5], w1.y, s);
      s = fmaf((float)v[6], w1.z, s); s = fmaf((float)v[7], w1.w, s);
    }
    s += __shfl_xor(s, 1, 64);
    s += __shfl_xor(s, 2, 64);
    if (q == 0) out[((long)b * 2 + g) * NN + n] = s + bfc[0];
  }
}

extern "C" void kernel_launch(void* const* d_in, const int* in_sizes, int n_in,
                              void* d_out, int out_size, void* d_ws, size_t ws_size,
                              hipStream_t stream) {
  const float* data  = (const float*)d_in[0];
  const float* W_l1  = (const float*)d_in[1];
  const float* b_l1  = (const float*)d_in[2];
  const float* W_l2  = (const float*)d_in[3];
  const float* b_l2  = (const float*)d_in[4];
  const float* W11   = (const float*)d_in[5];
  const float* b11   = (const float*)d_in[6];
  const float* W12   = (const float*)d_in[7];
  const float* b12   = (const float*)d_in[8];
  const float* W21   = (const float*)d_in[9];
  const float* b21   = (const float*)d_in[10];
  const float* W22   = (const float*)d_in[11];
  const float* b22   = (const float*)d_in[12];
  const float* Wqkv  = (const float*)d_in[13];
  const float* bqkv  = (const float*)d_in[14];
  const float* Wo    = (const float*)d_in[15];
  const float* bo    = (const float*)d_in[16];
  const float* ln1_g = (const float*)d_in[17];
  const float* ln1_b = (const float*)d_in[18];
  const float* Wf1   = (const float*)d_in[19];
  const float* bf1   = (const float*)d_in[20];
  const float* Wf2   = (const float*)d_in[21];
  const float* bf2   = (const float*)d_in[22];
  const float* ln2_g = (const float*)d_in[23];
  const float* ln2_b = (const float*)d_in[24];
  const float* Wfc   = (const float*)d_in[25];
  const float* bfc   = (const float*)d_in[26];

  _Float16* ws = (_Float16*)d_ws;

  prepA<<<dim3(640), dim3(256), 0, stream>>>(
      W_l1, W_l2, W11, W12, W21, W22, Wf1, Wf2,
      b_l1, b_l2, b11, b12, b21, b22, bf1, bf2,
      ln1_g, ln1_b, ln2_g, ln2_b, ws);
  prepB<<<dim3(129), dim3(256), 0, stream>>>(Wqkv, bqkv, Wo, bo, ws);

  gin_critic_kernel<<<dim3(NB / 2), dim3(256), 0, stream>>>(
      data, Wfc, bfc, ws, (float*)d_out);
}

// Round 11
// 255.720 us; speedup vs baseline: 1.3414x; 1.1654x over previous
//
#include <hip/hip_runtime.h>
#include <math.h>

#define NB 4096
#define NN 64

typedef _Float16 h8 __attribute__((ext_vector_type(8)));
typedef float f4 __attribute__((ext_vector_type(4)));
typedef unsigned long long u64;

typedef const __attribute__((address_space(1))) void* gas_t;
typedef __attribute__((address_space(3))) void* las_t;

__device__ __forceinline__ void gload16(const void* g, void* l) {
  __builtin_amdgcn_global_load_lds((gas_t)g, (las_t)l, 16, 0, 0);
}
__device__ __forceinline__ void rbar() {
  asm volatile("" ::: "memory");
  __builtin_amdgcn_s_barrier();
  asm volatile("" ::: "memory");
}
__device__ __forceinline__ void lgkm0() {
  asm volatile("s_waitcnt lgkmcnt(0)" ::: "memory");
}
template<int N> __device__ __forceinline__ void waitv() {
  if constexpr (N == 0) asm volatile("s_waitcnt vmcnt(0)" ::: "memory");
  else                  asm volatile("s_waitcnt vmcnt(1)" ::: "memory");
  __builtin_amdgcn_sched_barrier(0);
}

// activation buffers: 64 rows x 128 f16, 256 B row stride, byte ^= (row&7)<<4
__device__ __forceinline__ int aoff(int row, int colb) {
  return row * 256 + (colb ^ ((row & 7) << 4));
}
__device__ __forceinline__ h8 ald8(const char* a, int row, int colb) {
  return *(const h8*)(a + aoff(row, colb));
}
__device__ __forceinline__ void ast8(char* a, int row, int colb, h8 v) {
  *(h8*)(a + aoff(row, colb)) = v;
}
__device__ __forceinline__ _Float16 ald(const char* a, int row, int colb) {
  return *(const _Float16*)(a + aoff(row, colb));
}
__device__ __forceinline__ void ast(char* a, int row, int colb, _Float16 v) {
  *(_Float16*)(a + aoff(row, colb)) = v;
}

// ---------------- weight prep ----------------
// f16 ws: 0 Wl1p[128][32] | 4096 Wl2p[32][128] | 8192 W11p[128][32] |
// 12288 W12 | 28672 W21 | 45056 W22 | 61440 Wat 2x[128][128] (Wo.Wv fused) |
// 94208 Wf1 2x | 126976 Wf2 2x | 159744 params [32][128] f16
// params idx: 0 b_l1 1 b_l2 2 b11 3 b12 4 b21 5 b22 6 bat0 7 bat1
//             8 bf1_0 9 bf2_0 10 bf1_1 11 bf2_1 12 ln1g0 13 ln1b0 14 ln2g0
//             15 ln2b0 16 ln1g1 17 ln1b1 18 ln2g1 19 ln2b1 20..31 zero
__global__ void prepA(
    const float* __restrict__ W_l1, const float* __restrict__ W_l2,
    const float* __restrict__ W11, const float* __restrict__ W12,
    const float* __restrict__ W21, const float* __restrict__ W22,
    const float* __restrict__ Wf1, const float* __restrict__ Wf2,
    const float* __restrict__ b_l1, const float* __restrict__ b_l2,
    const float* __restrict__ b11, const float* __restrict__ b12,
    const float* __restrict__ b21, const float* __restrict__ b22,
    const float* __restrict__ bf1, const float* __restrict__ bf2,
    const float* __restrict__ ln1_g, const float* __restrict__ ln1_b,
    const float* __restrict__ ln2_g, const float* __restrict__ ln2_b,
    _Float16* __restrict__ ws)
{
  const int e = blockIdx.x * 256 + threadIdx.x;
  float v;
  if (e < 4096) { const int o = e >> 5, k = e & 31; v = (k < 20) ? W_l1[o * 20 + k] : 0.f; }
  else if (e < 8192) { const int i = e - 4096; const int o = i >> 7, k = i & 127; v = (o < 20) ? W_l2[o * 128 + k] : 0.f; }
  else if (e < 12288) { const int i = e - 8192; const int o = i >> 5, k = i & 31; v = (k < 27) ? W11[o * 27 + k] : 0.f; }
  else if (e < 28672) v = W12[e - 12288];
  else if (e < 45056) v = W21[e - 28672];
  else if (e < 61440) v = W22[e - 45056];
  else if (e < 94208) return;                      // Wat by prepB
  else if (e < 126976) v = Wf1[e - 94208];
  else if (e < 159744) v = Wf2[e - 126976];
  else {
    const int p = e - 159744, idx = p >> 7, col = p & 127;
    switch (idx) {
      case 0: v = b_l1[col]; break;
      case 1: v = (col < 20) ? b_l2[col] : 0.f; break;
      case 2: v = b11[col]; break;
      case 3: v = b12[col]; break;
      case 4: v = b21[col]; break;
      case 5: v = b22[col]; break;
      case 8: v = bf1[col]; break;
      case 9: v = bf2[col]; break;
      case 10: v = bf1[128 + col]; break;
      case 11: v = bf2[128 + col]; break;
      case 12: v = ln1_g[col]; break;
      case 13: v = ln1_b[col]; break;
      case 14: v = ln2_g[col]; break;
      case 15: v = ln2_b[col]; break;
      case 16: v = ln1_g[128 + col]; break;
      case 17: v = ln1_b[128 + col]; break;
      case 18: v = ln2_g[128 + col]; break;
      case 19: v = ln2_b[128 + col]; break;
      default: v = 0.f; break;                      // 6,7 by prepB; 20+ zero
    }
  }
  ws[e] = (_Float16)v;
}

__global__ void prepB(
    const float* __restrict__ Wqkv, const float* __restrict__ bqkv,
    const float* __restrict__ Wo, const float* __restrict__ bo,
    _Float16* __restrict__ ws)
{
  if (blockIdx.x < 128) {
    const int e = blockIdx.x * 256 + threadIdx.x;       // 0..32767
    const int l = e >> 14, r = e & 16383, o = r >> 7, k = r & 127;
    const float* wo = Wo + (l * 128 + o) * 128;
    const float* wv = Wqkv + l * 49152 + 32768 + k;
    float acc = 0.f;
#pragma unroll 4
    for (int m = 0; m < 128; ++m) acc += wo[m] * wv[m * 128];
    ws[61440 + e] = (_Float16)acc;
  } else {
    const int t = threadIdx.x;                          // bat[2][128]
    const int l = t >> 7, o = t & 127;
    const float* wo = Wo + (l * 128 + o) * 128;
    const float* bv = bqkv + l * 384 + 256;
    float acc = bo[l * 128 + o];
    for (int m = 0; m < 128; ++m) acc += bv[m] * wo[m];
    ws[159744 + (6 + l) * 128 + o] = (_Float16)acc;
  }
}

// ---------------- chunk staging (4 KB, pre-swizzled source) ----------------
__device__ __forceinline__ void stage64(const _Float16* __restrict__ Wp, int KT,
                                        int kc, int oc, char* buf, int tid) {
  const int o = tid >> 2, kq = tid & 3;
  const int kreal = kq ^ ((o >> 1) & 3);
  gload16(Wp + (oc * 64 + o) * KT + kc * 32 + kreal * 8, buf + tid * 16);
}
__device__ __forceinline__ void stage32(const _Float16* __restrict__ Wp,
                                        int kc, char* buf, int tid) {
  const int o = tid >> 3, u = tid & 7;
  const int ureal = u ^ (o & 7);
  gload16(Wp + o * 128 + kc * 64 + ureal * 8, buf + tid * 16);
}

// residual capture: c0/c1 = per-graph, [r] = row, elem oc*4+t = col slot
struct Cap { h8 c0[4]; h8 c1[4]; };

// ---------------- 8-chunk matmul stage, both graphs, in-place ----------------
// oc-major chunks; acc released per 64-col half (32 VGPRs, not 128).
// EPI: 0 bias+relu | 1 raw | 2 bias+resid(in-place G) | 3 bias+resid(from rin)
// CAP: capture pre-overwrite G values (the FF2 residual) in FF1.
template<int EPI, bool CAP, bool LAST, typename PF>
__device__ __forceinline__ Cap mm128_stage(
    const _Float16* __restrict__ Wp, char* g0, char* g1,
    const _Float16* pb, int bidx, Cap rin,
    char* wbase, int q0, int tid, PF&& pf)
{
  const int lane = tid & 63, wv = tid >> 6, lc = lane & 15, kg = lane >> 4;
  const int row0 = wv * 16 + lc, rb = wv * 16 + kg * 4;

  h8 af0[4], af1[4];     // hoisted before any in-place write
#pragma unroll
  for (int i = 0; i < 4; ++i) {
    af0[i] = ald8(g0, row0, i * 64 + kg * 16);
    af1[i] = ald8(g1, row0, i * 64 + kg * 16);
  }
  Cap rout{};
#pragma unroll
  for (int oc = 0; oc < 2; ++oc) {
    f4 a0[4], a1[4];
#pragma unroll
    for (int t = 0; t < 4; ++t) { a0[t] = (f4){0.f,0.f,0.f,0.f}; a1[t] = (f4){0.f,0.f,0.f,0.f}; }
#pragma unroll
    for (int kc = 0; kc < 4; ++kc) {
      const int ql = oc * 4 + kc;
      if (LAST && ql == 7) waitv<0>(); else waitv<1>();
      rbar();
      const int s = ql + 2;
      char* nbuf = wbase + ((q0 + s) % 3) * 4096;
      if (s < 8) stage64(Wp, 128, s & 3, s >> 2, nbuf, tid);
      else pf(s - 8, nbuf);
      const char* wb = wbase + ((q0 + ql) % 3) * 4096;
#pragma unroll
      for (int t = 0; t < 4; ++t) {
        const int o = t * 16 + lc;
        const int kq = kg ^ ((o >> 1) & 3);
        const h8 bf = *(const h8*)(wb + (o * 4 + kq) * 16);
        a0[t] = __builtin_amdgcn_mfma_f32_16x16x32_f16(af0[kc], bf, a0[t], 0, 0, 0);
        a1[t] = __builtin_amdgcn_mfma_f32_16x16x32_f16(af1[kc], bf, a1[t], 0, 0, 0);
      }
    }
    // epilogue for this 64-col half
#pragma unroll
    for (int t = 0; t < 4; ++t) {
      const int col = oc * 64 + t * 16 + lc;
      const float bv = (EPI == 1) ? 0.f : (float)pb[bidx * 128 + col];
#pragma unroll
      for (int r = 0; r < 4; ++r) {
        float v0 = a0[t][r] + bv, v1 = a1[t][r] + bv;
        if constexpr (EPI == 2) {
          v0 += (float)ald(g0, rb + r, col * 2);
          v1 += (float)ald(g1, rb + r, col * 2);
        }
        if constexpr (EPI == 3) {
          v0 += (float)rin.c0[r][oc * 4 + t];
          v1 += (float)rin.c1[r][oc * 4 + t];
        }
        if constexpr (EPI == 0) { v0 = fmaxf(v0, 0.f); v1 = fmaxf(v1, 0.f); }
        if constexpr (CAP) {
          rout.c0[r][oc * 4 + t] = ald(g0, rb + r, col * 2);   // capture t' before overwrite
          rout.c1[r][oc * 4 + t] = ald(g1, rb + r, col * 2);
        }
        ast(g0, rb + r, col * 2, (_Float16)v0);
        ast(g1, rb + r, col * 2, (_Float16)v1);
      }
    }
  }
  return rout;
}

// W11 raw Z-stage: K=32 (A = cols 32..63), 2 chunks (oc halves), in-place
template<typename PF>
__device__ __forceinline__ void mm32z_stage(
    const _Float16* __restrict__ Wp, char* g0, char* g1,
    char* wbase, int q0, int tid, PF&& pf)
{
  const int lane = tid & 63, wv = tid >> 6, lc = lane & 15, kg = lane >> 4;
  const int row0 = wv * 16 + lc, rb = wv * 16 + kg * 4;
  const h8 af0 = ald8(g0, row0, 64 + kg * 16);
  const h8 af1 = ald8(g1, row0, 64 + kg * 16);
#pragma unroll
  for (int oc = 0; oc < 2; ++oc) {
    waitv<1>(); rbar();
    pf(oc, wbase + ((q0 + oc + 2) % 3) * 4096);
    const char* wb = wbase + ((q0 + oc) % 3) * 4096;
    f4 a0[4], a1[4];
#pragma unroll
    for (int t = 0; t < 4; ++t) { a0[t] = (f4){0.f,0.f,0.f,0.f}; a1[t] = (f4){0.f,0.f,0.f,0.f}; }
#pragma unroll
    for (int t = 0; t < 4; ++t) {
      const int o = t * 16 + lc;
      const int kq = kg ^ ((o >> 1) & 3);
      const h8 bf = *(const h8*)(wb + (o * 4 + kq) * 16);
      a0[t] = __builtin_amdgcn_mfma_f32_16x16x32_f16(af0, bf, a0[t], 0, 0, 0);
      a1[t] = __builtin_amdgcn_mfma_f32_16x16x32_f16(af1, bf, a1[t], 0, 0, 0);
    }
#pragma unroll
    for (int t = 0; t < 4; ++t) {
      const int col = oc * 64 + t * 16 + lc;
#pragma unroll
      for (int r = 0; r < 4; ++r) {
        ast(g0, rb + r, col * 2, (_Float16)a0[t][r]);
        ast(g1, rb + r, col * 2, (_Float16)a1[t][r]);
      }
    }
  }
}

// in-place MFMA aggregation + bias + relu: G <- relu(M'^T G + b)
// internal read->barrier->write fence (cross-wave row reads)
__device__ __forceinline__ void agg_ip(const u64* mc, char* G, const _Float16* pb,
                                       int bidx, int tid)
{
  const int lane = tid & 63, wv = tid >> 6, lc = lane & 15, kg = lane >> 4;
  const int c0 = wv * 32 + lc;
  u64 mrow[4];
#pragma unroll
  for (int rt = 0; rt < 4; ++rt) mrow[rt] = mc[rt * 16 + lc];
  h8 bf[2][2];
#pragma unroll
  for (int ks = 0; ks < 2; ++ks)
#pragma unroll
    for (int ct = 0; ct < 2; ++ct)
#pragma unroll
      for (int e = 0; e < 8; ++e)
        bf[ks][ct][e] = ald(G, ks * 32 + kg * 8 + e, (c0 + ct * 16) * 2);
  lgkm0(); rbar();                    // all waves' reads in regs before any write
  f4 acc[4][2];
#pragma unroll
  for (int rt = 0; rt < 4; ++rt) { acc[rt][0] = (f4){0.f,0.f,0.f,0.f}; acc[rt][1] = (f4){0.f,0.f,0.f,0.f}; }
#pragma unroll
  for (int ks = 0; ks < 2; ++ks)
#pragma unroll
    for (int rt = 0; rt < 4; ++rt) {
      const unsigned int byte = (unsigned int)(mrow[rt] >> (ks * 32 + kg * 8)) & 0xffu;
      h8 af;
#pragma unroll
      for (int e = 0; e < 8; ++e) af[e] = (_Float16)((byte >> e) & 1u);
#pragma unroll
      for (int ct = 0; ct < 2; ++ct)
        acc[rt][ct] = __builtin_amdgcn_mfma_f32_16x16x32_f16(af, bf[ks][ct], acc[rt][ct], 0, 0, 0);
    }
#pragma unroll
  for (int ct = 0; ct < 2; ++ct) {
    const int col = c0 + ct * 16;
    const float bv = (float)pb[bidx * 128 + col];
#pragma unroll
    for (int rt = 0; rt < 4; ++rt)
#pragma unroll
      for (int qq = 0; qq < 4; ++qq)
        ast(G, rt * 16 + kg * 4 + qq, col * 2, (_Float16)fmaxf(acc[rt][ct][qq] + bv, 0.f));
  }
}

// standalone in-place LN, wave-local rows (n = tid>>2), f16 params from PB
__device__ __forceinline__ void layer_norm(char* buf, const _Float16* pb, int lnidx, int tid)
{
  const int n = tid >> 2, q = tid & 3;
  float vals[32];
#pragma unroll
  for (int u = 0; u < 4; ++u) {
    const h8 v = ald8(buf, n, q * 64 + u * 16);
#pragma unroll
    for (int e = 0; e < 8; ++e) vals[u * 8 + e] = (float)v[e];
  }
  float s = 0.f;
#pragma unroll
  for (int u = 0; u < 32; ++u) s += vals[u];
  s += __shfl_xor(s, 1, 64);
  s += __shfl_xor(s, 2, 64);
  const float mean = s * 0.0078125f;
  float vv = 0.f;
#pragma unroll
  for (int u = 0; u < 32; ++u) { const float d = vals[u] - mean; vv = fmaf(d, d, vv); }
  vv += __shfl_xor(vv, 1, 64);
  vv += __shfl_xor(vv, 2, 64);
  const float rstd = 1.0f / sqrtf(vv * 0.0078125f + 1e-5f);
#pragma unroll
  for (int u = 0; u < 4; ++u) {
    h8 o;
#pragma unroll
    for (int e = 0; e < 8; ++e) {
      const int col = q * 32 + u * 8 + e;
      const float gg = (float)pb[lnidx * 128 + col];
      const float bb = (float)pb[(lnidx + 1) * 128 + col];
      o[e] = (_Float16)((vals[u * 8 + e] - mean) * rstd * gg + bb);
    }
    ast8(buf, n, q * 64 + u * 16, o);
  }
}

struct SM {
  alignas(16) char G0[16384];
  alignas(16) char G1[16384];
  alignas(16) char WB[12288];
  alignas(16) char PB[8192];       // params [32][128] f16
  u64 mcol[2][64];
};   // 54272 B

// (256,2): VGPR cap 256 — the (256,3) cap of ~170 forced mass spill-to-scratch
// in rounds 8-10 (WRITE_SIZE 123-240 MB). Never force occupancy over spill.
__global__ __launch_bounds__(256, 2)
void gin_critic_kernel(
    const float* __restrict__ data,
    const float* __restrict__ Wfc, const float* __restrict__ bfc,
    const _Float16* __restrict__ ws,
    float* __restrict__ out)
{
  __shared__ SM sm;
  const int tid = threadIdx.x;
  const int lane = tid & 63, wv = tid >> 6, lc = lane & 15, kg = lane >> 4;
  const int row0 = wv * 16 + lc, rb = wv * 16 + kg * 4;
  const int b = blockIdx.x;
  const long base = (long)b * 2 * NN * 27;
  char* G0 = sm.G0; char* G1 = sm.G1; char* wbase = sm.WB;
  const _Float16* pb = (const _Float16*)sm.PB;

  const _Float16* Wl1p = ws + 0;
  const _Float16* Wl2p = ws + 4096;
  const _Float16* W11p = ws + 8192;
  const _Float16* W12p = ws + 12288;
  const _Float16* W21p = ws + 28672;
  const _Float16* W22p = ws + 45056;
  const _Float16* Wat0 = ws + 61440;
  const _Float16* Wat1 = ws + 61440 + 16384;
  const _Float16* Wf1_0 = ws + 94208;
  const _Float16* Wf1_1 = ws + 94208 + 16384;
  const _Float16* Wf2_0 = ws + 126976;
  const _Float16* Wf2_1 = ws + 126976 + 16384;

  // ---- input staging: lidar -> cols 0..19, orig7 -> cols 32..38 ----
#pragma unroll
  for (int i = 0; i < 14; ++i) {
    const int idx = tid + i * 256;
    const int cidx = idx < 3456 ? idx : 3455;
    float v = data[base + cidx];
    asm volatile("" : "+v"(v));
    if (idx < 3456) {
      const int gi = idx / 1728;
      const int r = idx - gi * 1728;
      const int n = r / 27, f = r - n * 27;
      char* Gg = gi ? G1 : G0;
      if (f < 7) ast(Gg, n, 64 + f * 2, (_Float16)v);
      else       ast(Gg, n, (f - 7) * 2, (_Float16)v);
    }
  }
  if (tid < 128) {
    const int gi = tid >> 6, n = tid & 63;
    char* Gg = gi ? G1 : G0;
#pragma unroll
    for (int c = 20; c < 32; ++c) ast(Gg, n, c * 2, (_Float16)0.f);
#pragma unroll
    for (int c = 59; c < 64; ++c) ast(Gg, n, c * 2, (_Float16)0.f);
  }
  const float* pp = data + base + (long)(wv >> 1) * 1728 + lane * 27;
  const float px = pp[0], py = pp[1];
  lgkm0(); rbar();   // staged inputs visible

  // ---- adjacency mask (exact double cone + guard-band atan2 fallback) ----
  {
    const int g = wv >> 1;
    const float FOVF = (float)(0.35 * 3.14159265358979323846);
    const double TT = tan(0.35 * 3.14159265358979323846);
    const double T2 = TT * TT;
    for (int jj = 0; jj < 32; ++jj) {
      const int j = (wv & 1) * 32 + jj;
      const float x0j = __shfl(px, j, 64);
      const float x1j = __shfl(py, j, 64);
      const float dxf = px - x0j;
      const float dyf = py - x1j;
      const float dist = sqrtf(dxf * dxf + dyf * dyf);
      bool pred;
      if (lane == j || dist > 10.0f) {
        pred = false;
      } else if (dxf <= 0.0f) {
        pred = (dxf == 0.0f && dyf == 0.0f);
      } else {
        const double qa = (double)dyf * (double)dyf;
        const double qb = (double)dxf * (double)dxf * T2;
        if (qa <= qb * 0.99999) pred = true;
        else if (qa >= qb * 1.00001) pred = false;
        else pred = (fabsf((float)atan2((double)dyf, (double)dxf)) <= FOVF);
      }
      const u64 bal = __ballot(pred);
      if (lane == 0) sm.mcol[g][j] = bal | (1ull << j);
    }
  }

  // ---- FIFO start: params (2) + chunks q0,q1 ----
  gload16(ws + 159744 + (size_t)tid * 8, sm.PB + (size_t)tid * 16);
  gload16(ws + 159744 + (size_t)(tid + 256) * 8, sm.PB + (size_t)(tid + 256) * 16);
  stage64(Wl1p, 32, 0, 0, wbase + 0 * 4096, tid);   // q0: L1a
  stage32(Wl2p, 0, wbase + 1 * 4096, tid);          // q1: L2a

  // ---- lidar MLP (hand-rolled, chunks q0..q3, hidden time-shared in cols 64..127) ----
  h8 axl0, axl1;
  f4 l20[2], l21[2];
  l20[0] = l20[1] = l21[0] = l21[1] = (f4){0.f,0.f,0.f,0.f};
  // q0: L1a -> hidden[0..63] at cols 64..127
  waitv<1>(); rbar();
  stage64(Wl1p, 32, 0, 1, wbase + 2 * 4096, tid);   // q2: L1b
  axl0 = ald8(G0, row0, kg * 16);
  axl1 = ald8(G1, row0, kg * 16);
  {
    const char* wb = wbase + 0 * 4096;
    f4 a0[4], a1[4];
#pragma unroll
    for (int t = 0; t < 4; ++t) { a0[t] = (f4){0.f,0.f,0.f,0.f}; a1[t] = (f4){0.f,0.f,0.f,0.f}; }
#pragma unroll
    for (int t = 0; t < 4; ++t) {
      const int o = t * 16 + lc;
      const int kq = kg ^ ((o >> 1) & 3);
      const h8 bf = *(const h8*)(wb + (o * 4 + kq) * 16);
      a0[t] = __builtin_amdgcn_mfma_f32_16x16x32_f16(axl0, bf, a0[t], 0, 0, 0);
      a1[t] = __builtin_amdgcn_mfma_f32_16x16x32_f16(axl1, bf, a1[t], 0, 0, 0);
    }
#pragma unroll
    for (int t = 0; t < 4; ++t) {
      const int col = t * 16 + lc;
      const float bv = (float)pb[0 * 128 + col];
#pragma unroll
      for (int r = 0; r < 4; ++r) {
        ast(G0, rb + r, 128 + col * 2, (_Float16)fmaxf(a0[t][r] + bv, 0.f));
        ast(G1, rb + r, 128 + col * 2, (_Float16)fmaxf(a1[t][r] + bv, 0.f));
      }
    }
  }
  // q1: L2a (K-half 0)
  waitv<1>(); rbar();
  stage32(Wl2p, 1, wbase + 0 * 4096, tid);          // q3: L2b
  {
    const char* wb = wbase + 1 * 4096;
    h8 ah0[2], ah1[2];
#pragma unroll
    for (int i = 0; i < 2; ++i) {
      ah0[i] = ald8(G0, row0, 128 + i * 64 + kg * 16);
      ah1[i] = ald8(G1, row0, 128 + i * 64 + kg * 16);
    }
#pragma unroll
    for (int ks = 0; ks < 2; ++ks)
#pragma unroll
      for (int ct = 0; ct < 2; ++ct) {
        const int o = ct * 16 + lc;
        const int u = (ks * 4 + kg) ^ (o & 7);
        const h8 bf = *(const h8*)(wb + (o * 8 + u) * 16);
        l20[ct] = __builtin_amdgcn_mfma_f32_16x16x32_f16(ah0[ks], bf, l20[ct], 0, 0, 0);
        l21[ct] = __builtin_amdgcn_mfma_f32_16x16x32_f16(ah1[ks], bf, l21[ct], 0, 0, 0);
      }
  }
  // q2: L1b -> hidden[64..127] overwrites cols 64..127
  waitv<1>(); rbar();
  stage64(W11p, 32, 0, 0, wbase + 1 * 4096, tid);   // q4: W11 oc0
  {
    const char* wb = wbase + 2 * 4096;
    f4 a0[4], a1[4];
#pragma unroll
    for (int t = 0; t < 4; ++t) { a0[t] = (f4){0.f,0.f,0.f,0.f}; a1[t] = (f4){0.f,0.f,0.f,0.f}; }
#pragma unroll
    for (int t = 0; t < 4; ++t) {
      const int o = t * 16 + lc;
      const int kq = kg ^ ((o >> 1) & 3);
      const h8 bf = *(const h8*)(wb + (o * 4 + kq) * 16);
      a0[t] = __builtin_amdgcn_mfma_f32_16x16x32_f16(axl0, bf, a0[t], 0, 0, 0);
      a1[t] = __builtin_amdgcn_mfma_f32_16x16x32_f16(axl1, bf, a1[t], 0, 0, 0);
    }
#pragma unroll
    for (int t = 0; t < 4; ++t) {
      const int col = t * 16 + lc;
      const float bv = (float)pb[0 * 128 + 64 + col];
#pragma unroll
      for (int r = 0; r < 4; ++r) {
        ast(G0, rb + r, 128 + col * 2, (_Float16)fmaxf(a0[t][r] + bv, 0.f));
        ast(G1, rb + r, 128 + col * 2, (_Float16)fmaxf(a1[t][r] + bv, 0.f));
      }
    }
  }
  // q3: L2b (K-half 1) -> lf20 into cols 39..58
  waitv<1>(); rbar();
  stage64(W11p, 32, 0, 1, wbase + 2 * 4096, tid);   // q5: W11 oc1
  {
    const char* wb = wbase + 0 * 4096;
    h8 ah0[2], ah1[2];
#pragma unroll
    for (int i = 0; i < 2; ++i) {
      ah0[i] = ald8(G0, row0, 128 + i * 64 + kg * 16);
      ah1[i] = ald8(G1, row0, 128 + i * 64 + kg * 16);
    }
#pragma unroll
    for (int ks = 0; ks < 2; ++ks)
#pragma unroll
      for (int ct = 0; ct < 2; ++ct) {
        const int o = ct * 16 + lc;
        const int u = (ks * 4 + kg) ^ (o & 7);
        const h8 bf = *(const h8*)(wb + (o * 8 + u) * 16);
        l20[ct] = __builtin_amdgcn_mfma_f32_16x16x32_f16(ah0[ks], bf, l20[ct], 0, 0, 0);
        l21[ct] = __builtin_amdgcn_mfma_f32_16x16x32_f16(ah1[ks], bf, l21[ct], 0, 0, 0);
      }
#pragma unroll
    for (int ct = 0; ct < 2; ++ct) {
      const int col = ct * 16 + lc;
      if (col < 20) {
        const float bv = (float)pb[1 * 128 + col];
#pragma unroll
        for (int r = 0; r < 4; ++r) {
          ast(G0, rb + r, 78 + col * 2, (_Float16)fmaxf(l20[ct][r] + bv, 0.f));
          ast(G1, rb + r, 78 + col * 2, (_Float16)fmaxf(l21[ct][r] + bv, 0.f));
        }
      }
    }
  }

  Cap rz{};
  // W11 Z-stage (q4,q5): Z1 = x.W11^T
  mm32z_stage(W11p, G0, G1, wbase, 4, tid,
      [&](int s, char* buf) { stage64(W12p, 128, s, 0, buf, tid); });
  lgkm0(); rbar();
  agg_ip(sm.mcol[0], G0, pb, 2, tid);    // h1 = relu(M'^T Z1 + b11)
  agg_ip(sm.mcol[1], G1, pb, 2, tid);
  lgkm0(); rbar();
  // W12
  mm128_stage<0, false, false>(W12p, G0, G1, pb, 3, rz, wbase, 6, tid,
      [&](int s, char* buf) { stage64(W21p, 128, s, 0, buf, tid); });
  // Z2 = h.W21^T (raw)
  mm128_stage<1, false, false>(W21p, G0, G1, pb, 0, rz, wbase, 14, tid,
      [&](int s, char* buf) { stage64(W22p, 128, s, 0, buf, tid); });
  lgkm0(); rbar();
  agg_ip(sm.mcol[0], G0, pb, 4, tid);    // h2 = relu(M'^T Z2 + b21)
  agg_ip(sm.mcol[1], G1, pb, 4, tid);
  lgkm0(); rbar();
  // W22: t
  mm128_stage<0, false, false>(W22p, G0, G1, pb, 5, rz, wbase, 22, tid,
      [&](int s, char* buf) { stage64(Wat0, 128, s, 0, buf, tid); });
  // ---- transformer layer 0 ----
  mm128_stage<2, false, false>(Wat0, G0, G1, pb, 6, rz, wbase, 30, tid,
      [&](int s, char* buf) { stage64(Wf1_0, 128, s, 0, buf, tid); });
  layer_norm(G0, pb, 12, tid);
  layer_norm(G1, pb, 12, tid);
  Cap c0 = mm128_stage<0, true, false>(Wf1_0, G0, G1, pb, 8, rz, wbase, 38, tid,
      [&](int s, char* buf) { stage64(Wf2_0, 128, s, 0, buf, tid); });
  mm128_stage<3, false, false>(Wf2_0, G0, G1, pb, 9, c0, wbase, 46, tid,
      [&](int s, char* buf) { stage64(Wat1, 128, s, 0, buf, tid); });
  layer_norm(G0, pb, 14, tid);
  layer_norm(G1, pb, 14, tid);
  // ---- transformer layer 1 ----
  mm128_stage<2, false, false>(Wat1, G0, G1, pb, 7, rz, wbase, 54, tid,
      [&](int s, char* buf) { stage64(Wf1_1, 128, s, 0, buf, tid); });
  layer_norm(G0, pb, 16, tid);
  layer_norm(G1, pb, 16, tid);
  Cap c1 = mm128_stage<0, true, false>(Wf1_1, G0, G1, pb, 10, rz, wbase, 62, tid,
      [&](int s, char* buf) { stage64(Wf2_1, 128, s, 0, buf, tid); });
  mm128_stage<3, false, true>(Wf2_1, G0, G1, pb, 11, c1, wbase, 70, tid,
      [&](int, char*) {});
  layer_norm(G0, pb, 18, tid);
  layer_norm(G1, pb, 18, tid);

  // ---- head (wave-local rows) ----
#pragma unroll
  for (int g = 0; g < 2; ++g) {
    const char* Pg = g ? G1 : G0;
    const int n = tid >> 2, q = tid & 3;
    float s = 0.f;
#pragma unroll
    for (int u = 0; u < 4; ++u) {
      const h8 v = ald8(Pg, n, q * 64 + u * 16);
      const float4 w0 = *(const float4*)(Wfc + q * 32 + u * 8);
      const float4 w1 = *(const float4*)(Wfc + q * 32 + u * 8 + 4);
      s = fmaf((float)v[0], w0.x, s); s = fmaf((float)v[1], w0.y, s);
      s = fmaf((float)v[2], w0.z, s); s = fmaf((float)v[3], w0.w, s);
      s = fmaf((float)v[4], w1.x, s); s = fmaf((float)v[5], w1.y, s);
      s = fmaf((float)v[6], w1.z, s); s = fmaf((float)v[7], w1.w, s);
    }
    s += __shfl_xor(s, 1, 64);
    s += __shfl_xor(s, 2, 64);
    if (q == 0) out[((long)b * 2 + g) * NN + n] = s + bfc[0];
  }
}

extern "C" void kernel_launch(void* const* d_in, const int* in_sizes, int n_in,
                              void* d_out, int out_size, void* d_ws, size_t ws_size,
                              hipStream_t stream) {
  const float* data  = (const float*)d_in[0];
  const float* W_l1  = (const float*)d_in[1];
  const float* b_l1  = (const float*)d_in[2];
  const float* W_l2  = (const float*)d_in[3];
  const float* b_l2  = (const float*)d_in[4];
  const float* W11   = (const float*)d_in[5];
  const float* b11   = (const float*)d_in[6];
  const float* W12   = (const float*)d_in[7];
  const float* b12   = (const float*)d_in[8];
  const float* W21   = (const float*)d_in[9];
  const float* b21   = (const float*)d_in[10];
  const float* W22   = (const float*)d_in[11];
  const float* b22   = (const float*)d_in[12];
  const float* Wqkv  = (const float*)d_in[13];
  const float* bqkv  = (const float*)d_in[14];
  const float* Wo    = (const float*)d_in[15];
  const float* bo    = (const float*)d_in[16];
  const float* ln1_g = (const float*)d_in[17];
  const float* ln1_b = (const float*)d_in[18];
  const float* Wf1   = (const float*)d_in[19];
  const float* bf1   = (const float*)d_in[20];
  const float* Wf2   = (const float*)d_in[21];
  const float* bf2   = (const float*)d_in[22];
  const float* ln2_g = (const float*)d_in[23];
  const float* ln2_b = (const float*)d_in[24];
  const float* Wfc   = (const float*)d_in[25];
  const float* bfc   = (const float*)d_in[26];

  _Float16* ws = (_Float16*)d_ws;

  prepA<<<dim3(640), dim3(256), 0, stream>>>(
      W_l1, W_l2, W11, W12, W21, W22, Wf1, Wf2,
      b_l1, b_l2, b11, b12, b21, b22, bf1, bf2,
      ln1_g, ln1_b, ln2_g, ln2_b, ws);
  prepB<<<dim3(129), dim3(256), 0, stream>>>(Wqkv, bqkv, Wo, bo, ws);

  gin_critic_kernel<<<dim3(NB / 2), dim3(256), 0, stream>>>(
      data, Wfc, bfc, ws, (float*)d_out);
}

// Round 12
// 198.767 us; speedup vs baseline: 1.7258x; 1.2865x over previous
//
#include <hip/hip_runtime.h>
#include <math.h>

#define NB 4096
#define NN 64

typedef _Float16 h8 __attribute__((ext_vector_type(8)));
typedef _Float16 h4 __attribute__((ext_vector_type(4)));
typedef float f4 __attribute__((ext_vector_type(4)));
typedef unsigned long long u64;

typedef const __attribute__((address_space(1))) void* gas_t;
typedef __attribute__((address_space(3))) void* las_t;

__device__ __forceinline__ void gload16(const void* g, void* l) {
  __builtin_amdgcn_global_load_lds((gas_t)g, (las_t)l, 16, 0, 0);
}
__device__ __forceinline__ void rbar() {
  asm volatile("" ::: "memory");
  __builtin_amdgcn_s_barrier();
  asm volatile("" ::: "memory");
}
__device__ __forceinline__ void lgkm0() {
  asm volatile("s_waitcnt lgkmcnt(0)" ::: "memory");
}
template<int N> __device__ __forceinline__ void waitv() {
  if constexpr (N == 0) asm volatile("s_waitcnt vmcnt(0)" ::: "memory");
  else                  asm volatile("s_waitcnt vmcnt(1)" ::: "memory");
  __builtin_amdgcn_sched_barrier(0);
}

// activation buffers: 64 rows x 128 f16, 256 B row stride, byte ^= (row&7)<<4
__device__ __forceinline__ int aoff(int row, int colb) {
  return row * 256 + (colb ^ ((row & 7) << 4));
}
__device__ __forceinline__ h8 ald8(const char* a, int row, int colb) {
  return *(const h8*)(a + aoff(row, colb));
}
__device__ __forceinline__ void ast8(char* a, int row, int colb, h8 v) {
  *(h8*)(a + aoff(row, colb)) = v;
}
__device__ __forceinline__ _Float16 ald(const char* a, int row, int colb) {
  return *(const _Float16*)(a + aoff(row, colb));
}
__device__ __forceinline__ void ast(char* a, int row, int colb, _Float16 v) {
  *(_Float16*)(a + aoff(row, colb)) = v;
}

// ---------------- weight prep ----------------
// f16 ws: 0 Wl1p[128][32] | 4096 Wl2p[32][128] | 8192 W11p[128][32] |
// 12288 W12 | 28672 W21 | 45056 W22 | 61440 Wat 2x[128][128] (Wo.Wv fused) |
// 94208 Wf1 2x | 126976 Wf2 2x | 159744 params [20][128] f16
// params idx: 0 b_l1 1 b_l2 2 b11 3 b12 4 b21 5 b22 6 bat0 7 bat1
//             8 bf1_0 9 bf2_0 10 bf1_1 11 bf2_1 12 ln1g0 13 ln1b0 14 ln2g0
//             15 ln2b0 16 ln1g1 17 ln1b1 18 ln2g1 19 ln2b1
__global__ void prepA(
    const float* __restrict__ W_l1, const float* __restrict__ W_l2,
    const float* __restrict__ W11, const float* __restrict__ W12,
    const float* __restrict__ W21, const float* __restrict__ W22,
    const float* __restrict__ Wf1, const float* __restrict__ Wf2,
    const float* __restrict__ b_l1, const float* __restrict__ b_l2,
    const float* __restrict__ b11, const float* __restrict__ b12,
    const float* __restrict__ b21, const float* __restrict__ b22,
    const float* __restrict__ bf1, const float* __restrict__ bf2,
    const float* __restrict__ ln1_g, const float* __restrict__ ln1_b,
    const float* __restrict__ ln2_g, const float* __restrict__ ln2_b,
    _Float16* __restrict__ ws)
{
  const int e = blockIdx.x * 256 + threadIdx.x;
  float v;
  if (e < 4096) { const int o = e >> 5, k = e & 31; v = (k < 20) ? W_l1[o * 20 + k] : 0.f; }
  else if (e < 8192) { const int i = e - 4096; const int o = i >> 7, k = i & 127; v = (o < 20) ? W_l2[o * 128 + k] : 0.f; }
  else if (e < 12288) { const int i = e - 8192; const int o = i >> 5, k = i & 31; v = (k < 27) ? W11[o * 27 + k] : 0.f; }
  else if (e < 28672) v = W12[e - 12288];
  else if (e < 45056) v = W21[e - 28672];
  else if (e < 61440) v = W22[e - 45056];
  else if (e < 94208) return;                      // Wat by prepB
  else if (e < 126976) v = Wf1[e - 94208];
  else if (e < 159744) v = Wf2[e - 126976];
  else {
    const int p = e - 159744;
    if (p >= 2560) return;
    const int idx = p >> 7, col = p & 127;
    switch (idx) {
      case 0: v = b_l1[col]; break;
      case 1: v = (col < 20) ? b_l2[col] : 0.f; break;
      case 2: v = b11[col]; break;
      case 3: v = b12[col]; break;
      case 4: v = b21[col]; break;
      case 5: v = b22[col]; break;
      case 8: v = bf1[col]; break;
      case 9: v = bf2[col]; break;
      case 10: v = bf1[128 + col]; break;
      case 11: v = bf2[128 + col]; break;
      case 12: v = ln1_g[col]; break;
      case 13: v = ln1_b[col]; break;
      case 14: v = ln2_g[col]; break;
      case 15: v = ln2_b[col]; break;
      case 16: v = ln1_g[128 + col]; break;
      case 17: v = ln1_b[128 + col]; break;
      case 18: v = ln2_g[128 + col]; break;
      case 19: v = ln2_b[128 + col]; break;
      default: v = 0.f; break;                      // 6,7 by prepB
    }
  }
  ws[e] = (_Float16)v;
}

__global__ void prepB(
    const float* __restrict__ Wqkv, const float* __restrict__ bqkv,
    const float* __restrict__ Wo, const float* __restrict__ bo,
    _Float16* __restrict__ ws)
{
  if (blockIdx.x < 128) {
    const int e = blockIdx.x * 256 + threadIdx.x;       // 0..32767
    const int l = e >> 14, r = e & 16383, o = r >> 7, k = r & 127;
    const float* wo = Wo + (l * 128 + o) * 128;
    const float* wv = Wqkv + l * 49152 + 32768 + k;
    float acc = 0.f;
#pragma unroll 4
    for (int m = 0; m < 128; ++m) acc += wo[m] * wv[m * 128];
    ws[61440 + e] = (_Float16)acc;
  } else {
    const int t = threadIdx.x;                          // bat[2][128]
    const int l = t >> 7, o = t & 127;
    const float* wo = Wo + (l * 128 + o) * 128;
    const float* bv = bqkv + l * 384 + 256;
    float acc = bo[l * 128 + o];
    for (int m = 0; m < 128; ++m) acc += bv[m] * wo[m];
    ws[159744 + (6 + l) * 128 + o] = (_Float16)acc;
  }
}

// ---------------- chunk staging (4 KB, pre-swizzled source) ----------------
__device__ __forceinline__ void stage64(const _Float16* __restrict__ Wp, int KT,
                                        int kc, int oc, char* buf, int tid) {
  const int o = tid >> 2, kq = tid & 3;
  const int kreal = kq ^ ((o >> 1) & 3);
  gload16(Wp + (oc * 64 + o) * KT + kc * 32 + kreal * 8, buf + tid * 16);
}
__device__ __forceinline__ void stage32(const _Float16* __restrict__ Wp,
                                        int kc, char* buf, int tid) {
  const int o = tid >> 3, u = tid & 7;
  const int ureal = u ^ (o & 7);
  gload16(Wp + o * 128 + kc * 64 + ureal * 8, buf + tid * 16);
}

// residual capture: per t-slot (oc*4+t) one 4-feature quad per graph
struct Cap { h4 q0[8]; h4 q1[8]; };

// ---------------- 8-chunk matmul stage, SWAPPED roles (A=W, B=act) ----------------
// C = [feature row][node col] -> lane's 4 acc values are 4 CONSECUTIVE features of
// one node => packed ds_write_b64 epilogue into G[node][feature].
// EPI: 0 bias+relu | 1 raw | 2 bias+resid(in-place G) | 3 bias+resid(from rin)
template<int EPI, bool CAP, bool LAST, typename PF>
__device__ __forceinline__ Cap mm128_stage(
    const _Float16* __restrict__ Wp, char* g0, char* g1,
    const _Float16* pb, int bidx, Cap rin,
    char* wbase, int q0, int tid, PF&& pf)
{
  const int lane = tid & 63, wv = tid >> 6, lc = lane & 15, kg = lane >> 4;
  const int nrow = wv * 16 + lc;         // this lane's node (C col)

  // B-frags (activations) hoisted before any in-place write
  h8 bf0[4], bf1[4];
#pragma unroll
  for (int i = 0; i < 4; ++i) {
    bf0[i] = ald8(g0, nrow, i * 64 + kg * 16);
    bf1[i] = ald8(g1, nrow, i * 64 + kg * 16);
  }
  Cap rout{};
#pragma unroll
  for (int oc = 0; oc < 2; ++oc) {
    f4 a0[4], a1[4];
#pragma unroll
    for (int t = 0; t < 4; ++t) { a0[t] = (f4){0.f,0.f,0.f,0.f}; a1[t] = (f4){0.f,0.f,0.f,0.f}; }
#pragma unroll
    for (int kc = 0; kc < 4; ++kc) {
      const int ql = oc * 4 + kc;
      if (LAST && ql == 7) waitv<0>(); else waitv<1>();
      rbar();
      const int s = ql + 2;
      char* nbuf = wbase + ((q0 + s) % 3) * 4096;
      if (s < 8) stage64(Wp, 128, s & 3, s >> 2, nbuf, tid);
      else pf(s - 8, nbuf);
      const char* wb = wbase + ((q0 + ql) % 3) * 4096;
#pragma unroll
      for (int t = 0; t < 4; ++t) {
        const int o = t * 16 + lc;
        const int kq = kg ^ ((o >> 1) & 3);
        const h8 af = *(const h8*)(wb + (o * 4 + kq) * 16);
        a0[t] = __builtin_amdgcn_mfma_f32_16x16x32_f16(af, bf0[kc], a0[t], 0, 0, 0);
        a1[t] = __builtin_amdgcn_mfma_f32_16x16x32_f16(af, bf1[kc], a1[t], 0, 0, 0);
      }
    }
    // packed epilogue for this 64-feature half
#pragma unroll
    for (int t = 0; t < 4; ++t) {
      const int slot = oc * 4 + t;
      const int fb = slot * 16 + kg * 4;   // 4 consecutive features
      const int cb = fb * 2;
      h4 bq{};
      if constexpr (EPI != 1) bq = *(const h4*)(pb + bidx * 128 + fb);
      h4 r0q{}, r1q{};
      if constexpr (EPI == 2) {
        r0q = *(const h4*)(g0 + aoff(nrow, cb));
        r1q = *(const h4*)(g1 + aoff(nrow, cb));
      }
      if constexpr (CAP) {
        rout.q0[slot] = *(const h4*)(g0 + aoff(nrow, cb));
        rout.q1[slot] = *(const h4*)(g1 + aoff(nrow, cb));
      }
      h4 o0, o1;
#pragma unroll
      for (int r = 0; r < 4; ++r) {
        float v0 = a0[t][r], v1 = a1[t][r];
        if constexpr (EPI != 1) { v0 += (float)bq[r]; v1 += (float)bq[r]; }
        if constexpr (EPI == 2) { v0 += (float)r0q[r]; v1 += (float)r1q[r]; }
        if constexpr (EPI == 3) { v0 += (float)rin.q0[slot][r]; v1 += (float)rin.q1[slot][r]; }
        if constexpr (EPI == 0) { v0 = fmaxf(v0, 0.f); v1 = fmaxf(v1, 0.f); }
        o0[r] = (_Float16)v0; o1[r] = (_Float16)v1;
      }
      *(h4*)(g0 + aoff(nrow, cb)) = o0;
      *(h4*)(g1 + aoff(nrow, cb)) = o1;
    }
  }
  return rout;
}

// W11 raw Z-stage, swapped: B = act cols 32..63 (K=32), packed raw writes
template<typename PF>
__device__ __forceinline__ void mm32z_stage(
    const _Float16* __restrict__ Wp, char* g0, char* g1,
    char* wbase, int q0, int tid, PF&& pf)
{
  const int lane = tid & 63, wv = tid >> 6, lc = lane & 15, kg = lane >> 4;
  const int nrow = wv * 16 + lc;
  const h8 bf0 = ald8(g0, nrow, 64 + kg * 16);
  const h8 bf1 = ald8(g1, nrow, 64 + kg * 16);
#pragma unroll
  for (int oc = 0; oc < 2; ++oc) {
    waitv<1>(); rbar();
    pf(oc, wbase + ((q0 + oc + 2) % 3) * 4096);
    const char* wb = wbase + ((q0 + oc) % 3) * 4096;
    f4 a0[4], a1[4];
#pragma unroll
    for (int t = 0; t < 4; ++t) { a0[t] = (f4){0.f,0.f,0.f,0.f}; a1[t] = (f4){0.f,0.f,0.f,0.f}; }
#pragma unroll
    for (int t = 0; t < 4; ++t) {
      const int o = t * 16 + lc;
      const int kq = kg ^ ((o >> 1) & 3);
      const h8 af = *(const h8*)(wb + (o * 4 + kq) * 16);
      a0[t] = __builtin_amdgcn_mfma_f32_16x16x32_f16(af, bf0, a0[t], 0, 0, 0);
      a1[t] = __builtin_amdgcn_mfma_f32_16x16x32_f16(af, bf1, a1[t], 0, 0, 0);
    }
#pragma unroll
    for (int t = 0; t < 4; ++t) {
      const int fb = (oc * 4 + t) * 16 + kg * 4;
      const int cb = fb * 2;
      h4 o0, o1;
#pragma unroll
      for (int r = 0; r < 4; ++r) { o0[r] = (_Float16)a0[t][r]; o1[r] = (_Float16)a1[t][r]; }
      *(h4*)(g0 + aoff(nrow, cb)) = o0;
      *(h4*)(g1 + aoff(nrow, cb)) = o1;
    }
  }
}

// in-place MFMA aggregation + bias + relu: G <- relu(M'^T G + b)  (unchanged)
__device__ __forceinline__ void agg_ip(const u64* mc, char* G, const _Float16* pb,
                                       int bidx, int tid)
{
  const int lane = tid & 63, wv = tid >> 6, lc = lane & 15, kg = lane >> 4;
  const int c0 = wv * 32 + lc;
  u64 mrow[4];
#pragma unroll
  for (int rt = 0; rt < 4; ++rt) mrow[rt] = mc[rt * 16 + lc];
  h8 bf[2][2];
#pragma unroll
  for (int ks = 0; ks < 2; ++ks)
#pragma unroll
    for (int ct = 0; ct < 2; ++ct)
#pragma unroll
      for (int e = 0; e < 8; ++e)
        bf[ks][ct][e] = ald(G, ks * 32 + kg * 8 + e, (c0 + ct * 16) * 2);
  lgkm0(); rbar();                    // all waves' reads in regs before any write
  f4 acc[4][2];
#pragma unroll
  for (int rt = 0; rt < 4; ++rt) { acc[rt][0] = (f4){0.f,0.f,0.f,0.f}; acc[rt][1] = (f4){0.f,0.f,0.f,0.f}; }
#pragma unroll
  for (int ks = 0; ks < 2; ++ks)
#pragma unroll
    for (int rt = 0; rt < 4; ++rt) {
      const unsigned int byte = (unsigned int)(mrow[rt] >> (ks * 32 + kg * 8)) & 0xffu;
      h8 af;
#pragma unroll
      for (int e = 0; e < 8; ++e) af[e] = (_Float16)((byte >> e) & 1u);
#pragma unroll
      for (int ct = 0; ct < 2; ++ct)
        acc[rt][ct] = __builtin_amdgcn_mfma_f32_16x16x32_f16(af, bf[ks][ct], acc[rt][ct], 0, 0, 0);
    }
#pragma unroll
  for (int ct = 0; ct < 2; ++ct) {
    const int col = c0 + ct * 16;
    const float bv = (float)pb[bidx * 128 + col];
#pragma unroll
    for (int rt = 0; rt < 4; ++rt)
#pragma unroll
      for (int qq = 0; qq < 4; ++qq)
        ast(G, rt * 16 + kg * 4 + qq, col * 2, (_Float16)fmaxf(acc[rt][ct][qq] + bv, 0.f));
  }
}

// standalone in-place LN, wave-local rows (n = tid>>2), f16 params from PB
__device__ __forceinline__ void layer_norm(char* buf, const _Float16* pb, int lnidx, int tid)
{
  const int n = tid >> 2, q = tid & 3;
  float vals[32];
#pragma unroll
  for (int u = 0; u < 4; ++u) {
    const h8 v = ald8(buf, n, q * 64 + u * 16);
#pragma unroll
    for (int e = 0; e < 8; ++e) vals[u * 8 + e] = (float)v[e];
  }
  float s = 0.f;
#pragma unroll
  for (int u = 0; u < 32; ++u) s += vals[u];
  s += __shfl_xor(s, 1, 64);
  s += __shfl_xor(s, 2, 64);
  const float mean = s * 0.0078125f;
  float vv = 0.f;
#pragma unroll
  for (int u = 0; u < 32; ++u) { const float d = vals[u] - mean; vv = fmaf(d, d, vv); }
  vv += __shfl_xor(vv, 1, 64);
  vv += __shfl_xor(vv, 2, 64);
  const float rstd = 1.0f / sqrtf(vv * 0.0078125f + 1e-5f);
#pragma unroll
  for (int u = 0; u < 4; ++u) {
    h8 o;
#pragma unroll
    for (int e = 0; e < 8; ++e) {
      const int col = q * 32 + u * 8 + e;
      const float gg = (float)pb[lnidx * 128 + col];
      const float bb = (float)pb[(lnidx + 1) * 128 + col];
      o[e] = (_Float16)((vals[u * 8 + e] - mean) * rstd * gg + bb);
    }
    ast8(buf, n, q * 64 + u * 16, o);
  }
}

struct SM {
  alignas(16) char G0[16384];
  alignas(16) char G1[16384];
  alignas(16) char WB[12288];
  alignas(16) char PB[5120];       // params [20][128] f16
  u64 mcol[2][64];
};   // 51200 B

// (256,2): VGPR cap 256 — a (256,3) cap forced mass spill in rounds 8-10.
__global__ __launch_bounds__(256, 2)
void gin_critic_kernel(
    const float* __restrict__ data,
    const float* __restrict__ Wfc, const float* __restrict__ bfc,
    const _Float16* __restrict__ ws,
    float* __restrict__ out)
{
  __shared__ SM sm;
  const int tid = threadIdx.x;
  const int lane = tid & 63, wv = tid >> 6, lc = lane & 15, kg = lane >> 4;
  const int row0 = wv * 16 + lc, rb = wv * 16 + kg * 4;
  const int b = blockIdx.x;
  const long base = (long)b * 2 * NN * 27;
  char* G0 = sm.G0; char* G1 = sm.G1; char* wbase = sm.WB;
  const _Float16* pb = (const _Float16*)sm.PB;

  const _Float16* Wl1p = ws + 0;
  const _Float16* Wl2p = ws + 4096;
  const _Float16* W11p = ws + 8192;
  const _Float16* W12p = ws + 12288;
  const _Float16* W21p = ws + 28672;
  const _Float16* W22p = ws + 45056;
  const _Float16* Wat0 = ws + 61440;
  const _Float16* Wat1 = ws + 61440 + 16384;
  const _Float16* Wf1_0 = ws + 94208;
  const _Float16* Wf1_1 = ws + 94208 + 16384;
  const _Float16* Wf2_0 = ws + 126976;
  const _Float16* Wf2_1 = ws + 126976 + 16384;

  // ---- input staging: lidar -> cols 0..19, orig7 -> cols 32..38 ----
#pragma unroll
  for (int i = 0; i < 14; ++i) {
    const int idx = tid + i * 256;
    const int cidx = idx < 3456 ? idx : 3455;
    float v = data[base + cidx];
    asm volatile("" : "+v"(v));
    if (idx < 3456) {
      const int gi = idx / 1728;
      const int r = idx - gi * 1728;
      const int n = r / 27, f = r - n * 27;
      char* Gg = gi ? G1 : G0;
      if (f < 7) ast(Gg, n, 64 + f * 2, (_Float16)v);
      else       ast(Gg, n, (f - 7) * 2, (_Float16)v);
    }
  }
  if (tid < 128) {
    const int gi = tid >> 6, n = tid & 63;
    char* Gg = gi ? G1 : G0;
#pragma unroll
    for (int c = 20; c < 32; ++c) ast(Gg, n, c * 2, (_Float16)0.f);
#pragma unroll
    for (int c = 59; c < 64; ++c) ast(Gg, n, c * 2, (_Float16)0.f);
  }
  const float* pp = data + base + (long)(wv >> 1) * 1728 + lane * 27;
  const float px = pp[0], py = pp[1];
  lgkm0(); rbar();   // staged inputs visible

  // ---- adjacency mask (exact double cone + guard-band atan2 fallback) ----
  {
    const int g = wv >> 1;
    const float FOVF = (float)(0.35 * 3.14159265358979323846);
    const double TT = tan(0.35 * 3.14159265358979323846);
    const double T2 = TT * TT;
    for (int jj = 0; jj < 32; ++jj) {
      const int j = (wv & 1) * 32 + jj;
      const float x0j = __shfl(px, j, 64);
      const float x1j = __shfl(py, j, 64);
      const float dxf = px - x0j;
      const float dyf = py - x1j;
      const float dist = sqrtf(dxf * dxf + dyf * dyf);
      bool pred;
      if (lane == j || dist > 10.0f) {
        pred = false;
      } else if (dxf <= 0.0f) {
        pred = (dxf == 0.0f && dyf == 0.0f);
      } else {
        const double qa = (double)dyf * (double)dyf;
        const double qb = (double)dxf * (double)dxf * T2;
        if (qa <= qb * 0.99999) pred = true;
        else if (qa >= qb * 1.00001) pred = false;
        else pred = (fabsf((float)atan2((double)dyf, (double)dxf)) <= FOVF);
      }
      const u64 bal = __ballot(pred);
      if (lane == 0) sm.mcol[g][j] = bal | (1ull << j);
    }
  }

  // ---- FIFO start: params (2 uniform loads) + chunks q0,q1 ----
  gload16(ws + 159744 + (size_t)tid * 8, sm.PB + (size_t)tid * 16);
  gload16(ws + 159744 + 2048 + (size_t)(tid & 63) * 8, sm.PB + 4096 + (size_t)(tid & 63) * 16);
  stage64(Wl1p, 32, 0, 0, wbase + 0 * 4096, tid);   // q0: L1a
  stage32(Wl2p, 0, wbase + 1 * 4096, tid);          // q1: L2a

  // ---- lidar MLP (hand-rolled, old orientation; chunks q0..q3) ----
  h8 axl0, axl1;
  f4 l20[2], l21[2];
  l20[0] = l20[1] = l21[0] = l21[1] = (f4){0.f,0.f,0.f,0.f};
  // q0: L1a -> hidden[0..63] at cols 64..127
  waitv<1>(); rbar();
  stage64(Wl1p, 32, 0, 1, wbase + 2 * 4096, tid);   // q2: L1b
  axl0 = ald8(G0, row0, kg * 16);
  axl1 = ald8(G1, row0, kg * 16);
  {
    const char* wb = wbase + 0 * 4096;
    f4 a0[4], a1[4];
#pragma unroll
    for (int t = 0; t < 4; ++t) { a0[t] = (f4){0.f,0.f,0.f,0.f}; a1[t] = (f4){0.f,0.f,0.f,0.f}; }
#pragma unroll
    for (int t = 0; t < 4; ++t) {
      const int o = t * 16 + lc;
      const int kq = kg ^ ((o >> 1) & 3);
      const h8 bf = *(const h8*)(wb + (o * 4 + kq) * 16);
      a0[t] = __builtin_amdgcn_mfma_f32_16x16x32_f16(axl0, bf, a0[t], 0, 0, 0);
      a1[t] = __builtin_amdgcn_mfma_f32_16x16x32_f16(axl1, bf, a1[t], 0, 0, 0);
    }
#pragma unroll
    for (int t = 0; t < 4; ++t) {
      const int col = t * 16 + lc;
      const float bv = (float)pb[0 * 128 + col];
#pragma unroll
      for (int r = 0; r < 4; ++r) {
        ast(G0, rb + r, 128 + col * 2, (_Float16)fmaxf(a0[t][r] + bv, 0.f));
        ast(G1, rb + r, 128 + col * 2, (_Float16)fmaxf(a1[t][r] + bv, 0.f));
      }
    }
  }
  // q1: L2a (K-half 0)
  waitv<1>(); rbar();
  stage32(Wl2p, 1, wbase + 0 * 4096, tid);          // q3: L2b
  {
    const char* wb = wbase + 1 * 4096;
    h8 ah0[2], ah1[2];
#pragma unroll
    for (int i = 0; i < 2; ++i) {
      ah0[i] = ald8(G0, row0, 128 + i * 64 + kg * 16);
      ah1[i] = ald8(G1, row0, 128 + i * 64 + kg * 16);
    }
#pragma unroll
    for (int ks = 0; ks < 2; ++ks)
#pragma unroll
      for (int ct = 0; ct < 2; ++ct) {
        const int o = ct * 16 + lc;
        const int u = (ks * 4 + kg) ^ (o & 7);
        const h8 bf = *(const h8*)(wb + (o * 8 + u) * 16);
        l20[ct] = __builtin_amdgcn_mfma_f32_16x16x32_f16(ah0[ks], bf, l20[ct], 0, 0, 0);
        l21[ct] = __builtin_amdgcn_mfma_f32_16x16x32_f16(ah1[ks], bf, l21[ct], 0, 0, 0);
      }
  }
  // q2: L1b -> hidden[64..127] overwrites cols 64..127
  waitv<1>(); rbar();
  stage64(W11p, 32, 0, 0, wbase + 1 * 4096, tid);   // q4: W11 oc0
  {
    const char* wb = wbase + 2 * 4096;
    f4 a0[4], a1[4];
#pragma unroll
    for (int t = 0; t < 4; ++t) { a0[t] = (f4){0.f,0.f,0.f,0.f}; a1[t] = (f4){0.f,0.f,0.f,0.f}; }
#pragma unroll
    for (int t = 0; t < 4; ++t) {
      const int o = t * 16 + lc;
      const int kq = kg ^ ((o >> 1) & 3);
      const h8 bf = *(const h8*)(wb + (o * 4 + kq) * 16);
      a0[t] = __builtin_amdgcn_mfma_f32_16x16x32_f16(axl0, bf, a0[t], 0, 0, 0);
      a1[t] = __builtin_amdgcn_mfma_f32_16x16x32_f16(axl1, bf, a1[t], 0, 0, 0);
    }
#pragma unroll
    for (int t = 0; t < 4; ++t) {
      const int col = t * 16 + lc;
      const float bv = (float)pb[0 * 128 + 64 + col];
#pragma unroll
      for (int r = 0; r < 4; ++r) {
        ast(G0, rb + r, 128 + col * 2, (_Float16)fmaxf(a0[t][r] + bv, 0.f));
        ast(G1, rb + r, 128 + col * 2, (_Float16)fmaxf(a1[t][r] + bv, 0.f));
      }
    }
  }
  // q3: L2b (K-half 1) -> lf20 into cols 39..58
  waitv<1>(); rbar();
  stage64(W11p, 32, 0, 1, wbase + 2 * 4096, tid);   // q5: W11 oc1
  {
    const char* wb = wbase + 0 * 4096;
    h8 ah0[2], ah1[2];
#pragma unroll
    for (int i = 0; i < 2; ++i) {
      ah0[i] = ald8(G0, row0, 128 + i * 64 + kg * 16);
      ah1[i] = ald8(G1, row0, 128 + i * 64 + kg * 16);
    }
#pragma unroll
    for (int ks = 0; ks < 2; ++ks)
#pragma unroll
      for (int ct = 0; ct < 2; ++ct) {
        const int o = ct * 16 + lc;
        const int u = (ks * 4 + kg) ^ (o & 7);
        const h8 bf = *(const h8*)(wb + (o * 8 + u) * 16);
        l20[ct] = __builtin_amdgcn_mfma_f32_16x16x32_f16(ah0[ks], bf, l20[ct], 0, 0, 0);
        l21[ct] = __builtin_amdgcn_mfma_f32_16x16x32_f16(ah1[ks], bf, l21[ct], 0, 0, 0);
      }
#pragma unroll
    for (int ct = 0; ct < 2; ++ct) {
      const int col = ct * 16 + lc;
      if (col < 20) {
        const float bv = (float)pb[1 * 128 + col];
#pragma unroll
        for (int r = 0; r < 4; ++r) {
          ast(G0, rb + r, 78 + col * 2, (_Float16)fmaxf(l20[ct][r] + bv, 0.f));
          ast(G1, rb + r, 78 + col * 2, (_Float16)fmaxf(l21[ct][r] + bv, 0.f));
        }
      }
    }
  }

  Cap rz{};
  // W11 Z-stage (q4,q5): Z1 = x.W11^T
  mm32z_stage(W11p, G0, G1, wbase, 4, tid,
      [&](int s, char* buf) { stage64(W12p, 128, s, 0, buf, tid); });
  lgkm0(); rbar();
  agg_ip(sm.mcol[0], G0, pb, 2, tid);    // h1 = relu(M'^T Z1 + b11)
  agg_ip(sm.mcol[1], G1, pb, 2, tid);
  lgkm0(); rbar();
  // W12
  mm128_stage<0, false, false>(W12p, G0, G1, pb, 3, rz, wbase, 6, tid,
      [&](int s, char* buf) { stage64(W21p, 128, s, 0, buf, tid); });
  // Z2 = h.W21^T (raw)
  mm128_stage<1, false, false>(W21p, G0, G1, pb, 0, rz, wbase, 14, tid,
      [&](int s, char* buf) { stage64(W22p, 128, s, 0, buf, tid); });
  lgkm0(); rbar();
  agg_ip(sm.mcol[0], G0, pb, 4, tid);    // h2 = relu(M'^T Z2 + b21)
  agg_ip(sm.mcol[1], G1, pb, 4, tid);
  lgkm0(); rbar();
  // W22: t
  mm128_stage<0, false, false>(W22p, G0, G1, pb, 5, rz, wbase, 22, tid,
      [&](int s, char* buf) { stage64(Wat0, 128, s, 0, buf, tid); });
  // ---- transformer layer 0 ----
  mm128_stage<2, false, false>(Wat0, G0, G1, pb, 6, rz, wbase, 30, tid,
      [&](int s, char* buf) { stage64(Wf1_0, 128, s, 0, buf, tid); });
  layer_norm(G0, pb, 12, tid);
  layer_norm(G1, pb, 12, tid);
  Cap c0 = mm128_stage<0, true, false>(Wf1_0, G0, G1, pb, 8, rz, wbase, 38, tid,
      [&](int s, char* buf) { stage64(Wf2_0, 128, s, 0, buf, tid); });
  mm128_stage<3, false, false>(Wf2_0, G0, G1, pb, 9, c0, wbase, 46, tid,
      [&](int s, char* buf) { stage64(Wat1, 128, s, 0, buf, tid); });
  layer_norm(G0, pb, 14, tid);
  layer_norm(G1, pb, 14, tid);
  // ---- transformer layer 1 ----
  mm128_stage<2, false, false>(Wat1, G0, G1, pb, 7, rz, wbase, 54, tid,
      [&](int s, char* buf) { stage64(Wf1_1, 128, s, 0, buf, tid); });
  layer_norm(G0, pb, 16, tid);
  layer_norm(G1, pb, 16, tid);
  Cap c1 = mm128_stage<0, true, false>(Wf1_1, G0, G1, pb, 10, rz, wbase, 62, tid,
      [&](int s, char* buf) { stage64(Wf2_1, 128, s, 0, buf, tid); });
  mm128_stage<3, false, true>(Wf2_1, G0, G1, pb, 11, c1, wbase, 70, tid,
      [&](int, char*) {});
  layer_norm(G0, pb, 18, tid);
  layer_norm(G1, pb, 18, tid);

  // ---- head (wave-local rows) ----
#pragma unroll
  for (int g = 0; g < 2; ++g) {
    const char* Pg = g ? G1 : G0;
    const int n = tid >> 2, q = tid & 3;
    float s = 0.f;
#pragma unroll
    for (int u = 0; u < 4; ++u) {
      const h8 v = ald8(Pg, n, q * 64 + u * 16);
      const float4 w0 = *(const float4*)(Wfc + q * 32 + u * 8);
      const float4 w1 = *(const float4*)(Wfc + q * 32 + u * 8 + 4);
      s = fmaf((float)v[0], w0.x, s); s = fmaf((float)v[1], w0.y, s);
      s = fmaf((float)v[2], w0.z, s); s = fmaf((float)v[3], w0.w, s);
      s = fmaf((float)v[4], w1.x, s); s = fmaf((float)v[5], w1.y, s);
      s = fmaf((float)v[6], w1.z, s); s = fmaf((float)v[7], w1.w, s);
    }
    s += __shfl_xor(s, 1, 64);
    s += __shfl_xor(s, 2, 64);
    if (q == 0) out[((long)b * 2 + g) * NN + n] = s + bfc[0];
  }
}

extern "C" void kernel_launch(void* const* d_in, const int* in_sizes, int n_in,
                              void* d_out, int out_size, void* d_ws, size_t ws_size,
                              hipStream_t stream) {
  const float* data  = (const float*)d_in[0];
  const float* W_l1  = (const float*)d_in[1];
  const float* b_l1  = (const float*)d_in[2];
  const float* W_l2  = (const float*)d_in[3];
  const float* b_l2  = (const float*)d_in[4];
  const float* W11   = (const float*)d_in[5];
  const float* b11   = (const float*)d_in[6];
  const float* W12   = (const float*)d_in[7];
  const float* b12   = (const float*)d_in[8];
  const float* W21   = (const float*)d_in[9];
  const float* b21   = (const float*)d_in[10];
  const float* W22   = (const float*)d_in[11];
  const float* b22   = (const float*)d_in[12];
  const float* Wqkv  = (const float*)d_in[13];
  const float* bqkv  = (const float*)d_in[14];
  const float* Wo    = (const float*)d_in[15];
  const float* bo    = (const float*)d_in[16];
  const float* ln1_g = (const float*)d_in[17];
  const float* ln1_b = (const float*)d_in[18];
  const float* Wf1   = (const float*)d_in[19];
  const float* bf1   = (const float*)d_in[20];
  const float* Wf2   = (const float*)d_in[21];
  const float* bf2   = (const float*)d_in[22];
  const float* ln2_g = (const float*)d_in[23];
  const float* ln2_b = (const float*)d_in[24];
  const float* Wfc   = (const float*)d_in[25];
  const float* bfc   = (const float*)d_in[26];

  _Float16* ws = (_Float16*)d_ws;

  prepA<<<dim3(634), dim3(256), 0, stream>>>(
      W_l1, W_l2, W11, W12, W21, W22, Wf1, Wf2,
      b_l1, b_l2, b11, b12, b21, b22, bf1, bf2,
      ln1_g, ln1_b, ln2_g, ln2_b, ws);
  prepB<<<dim3(129), dim3(256), 0, stream>>>(Wqkv, bqkv, Wo, bo, ws);

  gin_critic_kernel<<<dim3(NB / 2), dim3(256), 0, stream>>>(
      data, Wfc, bfc, ws, (float*)d_out);
}

// Round 13
// 193.330 us; speedup vs baseline: 1.7743x; 1.0281x over previous
//
#include <hip/hip_runtime.h>
#include <math.h>

#define NB 4096
#define NN 64

typedef _Float16 h8 __attribute__((ext_vector_type(8)));
typedef _Float16 h4 __attribute__((ext_vector_type(4)));
typedef float f4 __attribute__((ext_vector_type(4)));
typedef unsigned long long u64;

typedef const __attribute__((address_space(1))) void* gas_t;
typedef __attribute__((address_space(3))) void* las_t;

__device__ __forceinline__ void gload16(const void* g, void* l) {
  __builtin_amdgcn_global_load_lds((gas_t)g, (las_t)l, 16, 0, 0);
}
__device__ __forceinline__ void rbar() {
  asm volatile("" ::: "memory");
  __builtin_amdgcn_s_barrier();
  asm volatile("" ::: "memory");
}
__device__ __forceinline__ void lgkm0() {
  asm volatile("s_waitcnt lgkmcnt(0)" ::: "memory");
}
template<int N> __device__ __forceinline__ void waitv() {
  if constexpr (N == 0) asm volatile("s_waitcnt vmcnt(0)" ::: "memory");
  else                  asm volatile("s_waitcnt vmcnt(1)" ::: "memory");
  __builtin_amdgcn_sched_barrier(0);
}

// activation buffers: 64 rows x 128 f16, 256 B row stride.
// 4-bit slot XOR: full 16-slot spread (r12's 3-bit left 4-8-way conflicts).
__device__ __forceinline__ int aoff(int row, int colb) {
  return row * 256 + (colb ^ ((row & 15) << 4));
}
__device__ __forceinline__ h8 ald8(const char* a, int row, int colb) {
  return *(const h8*)(a + aoff(row, colb));
}
__device__ __forceinline__ void ast8(char* a, int row, int colb, h8 v) {
  *(h8*)(a + aoff(row, colb)) = v;
}
__device__ __forceinline__ _Float16 ald(const char* a, int row, int colb) {
  return *(const _Float16*)(a + aoff(row, colb));
}
__device__ __forceinline__ void ast(char* a, int row, int colb, _Float16 v) {
  *(_Float16*)(a + aoff(row, colb)) = v;
}
// transposed Z layout in the SAME 16KB buffer: ZT[feature 0..127][node 0..63],
// 128 B row stride, 16B-slot XOR by (f&7)
__device__ __forceinline__ int zoff(int f, int nb) {   // nb = node*2 (bytes)
  return f * 128 + ((((nb >> 4) ^ (f & 7)) << 4) | (nb & 15));
}

// ---------------- weight prep ----------------
// f16 ws: 0 Wl1p[128][32] | 4096 Wl2p[32][128] | 8192 W11p[128][32] |
// 12288 W12 | 28672 W21 | 45056 W22 | 61440 Wat 2x[128][128] (Wo.Wv fused) |
// 94208 Wf1 2x | 126976 Wf2 2x | 159744 params [20][128] f16
// params idx: 0 b_l1 1 b_l2 2 b11 3 b12 4 b21 5 b22 6 bat0 7 bat1
//             8 bf1_0 9 bf2_0 10 bf1_1 11 bf2_1 12 ln1g0 13 ln1b0 14 ln2g0
//             15 ln2b0 16 ln1g1 17 ln1b1 18 ln2g1 19 ln2b1
__global__ void prepA(
    const float* __restrict__ W_l1, const float* __restrict__ W_l2,
    const float* __restrict__ W11, const float* __restrict__ W12,
    const float* __restrict__ W21, const float* __restrict__ W22,
    const float* __restrict__ Wf1, const float* __restrict__ Wf2,
    const float* __restrict__ b_l1, const float* __restrict__ b_l2,
    const float* __restrict__ b11, const float* __restrict__ b12,
    const float* __restrict__ b21, const float* __restrict__ b22,
    const float* __restrict__ bf1, const float* __restrict__ bf2,
    const float* __restrict__ ln1_g, const float* __restrict__ ln1_b,
    const float* __restrict__ ln2_g, const float* __restrict__ ln2_b,
    _Float16* __restrict__ ws)
{
  const int e = blockIdx.x * 256 + threadIdx.x;
  float v;
  if (e < 4096) { const int o = e >> 5, k = e & 31; v = (k < 20) ? W_l1[o * 20 + k] : 0.f; }
  else if (e < 8192) { const int i = e - 4096; const int o = i >> 7, k = i & 127; v = (o < 20) ? W_l2[o * 128 + k] : 0.f; }
  else if (e < 12288) { const int i = e - 8192; const int o = i >> 5, k = i & 31; v = (k < 27) ? W11[o * 27 + k] : 0.f; }
  else if (e < 28672) v = W12[e - 12288];
  else if (e < 45056) v = W21[e - 28672];
  else if (e < 61440) v = W22[e - 45056];
  else if (e < 94208) return;                      // Wat by prepB
  else if (e < 126976) v = Wf1[e - 94208];
  else if (e < 159744) v = Wf2[e - 126976];
  else {
    const int p = e - 159744;
    if (p >= 2560) return;
    const int idx = p >> 7, col = p & 127;
    switch (idx) {
      case 0: v = b_l1[col]; break;
      case 1: v = (col < 20) ? b_l2[col] : 0.f; break;
      case 2: v = b11[col]; break;
      case 3: v = b12[col]; break;
      case 4: v = b21[col]; break;
      case 5: v = b22[col]; break;
      case 8: v = bf1[col]; break;
      case 9: v = bf2[col]; break;
      case 10: v = bf1[128 + col]; break;
      case 11: v = bf2[128 + col]; break;
      case 12: v = ln1_g[col]; break;
      case 13: v = ln1_b[col]; break;
      case 14: v = ln2_g[col]; break;
      case 15: v = ln2_b[col]; break;
      case 16: v = ln1_g[128 + col]; break;
      case 17: v = ln1_b[128 + col]; break;
      case 18: v = ln2_g[128 + col]; break;
      case 19: v = ln2_b[128 + col]; break;
      default: v = 0.f; break;                      // 6,7 by prepB
    }
  }
  ws[e] = (_Float16)v;
}

__global__ void prepB(
    const float* __restrict__ Wqkv, const float* __restrict__ bqkv,
    const float* __restrict__ Wo, const float* __restrict__ bo,
    _Float16* __restrict__ ws)
{
  if (blockIdx.x < 128) {
    const int e = blockIdx.x * 256 + threadIdx.x;       // 0..32767
    const int l = e >> 14, r = e & 16383, o = r >> 7, k = r & 127;
    const float* wo = Wo + (l * 128 + o) * 128;
    const float* wv = Wqkv + l * 49152 + 32768 + k;
    float acc = 0.f;
#pragma unroll 4
    for (int m = 0; m < 128; ++m) acc += wo[m] * wv[m * 128];
    ws[61440 + e] = (_Float16)acc;
  } else {
    const int t = threadIdx.x;                          // bat[2][128]
    const int l = t >> 7, o = t & 127;
    const float* wo = Wo + (l * 128 + o) * 128;
    const float* bv = bqkv + l * 384 + 256;
    float acc = bo[l * 128 + o];
    for (int m = 0; m < 128; ++m) acc += bv[m] * wo[m];
    ws[159744 + (6 + l) * 128 + o] = (_Float16)acc;
  }
}

// ---------------- chunk staging (4 KB, pre-swizzled source) ----------------
__device__ __forceinline__ void stage64(const _Float16* __restrict__ Wp, int KT,
                                        int kc, int oc, char* buf, int tid) {
  const int o = tid >> 2, kq = tid & 3;
  const int kreal = kq ^ ((o >> 1) & 3);
  gload16(Wp + (oc * 64 + o) * KT + kc * 32 + kreal * 8, buf + tid * 16);
}
__device__ __forceinline__ void stage32(const _Float16* __restrict__ Wp,
                                        int kc, char* buf, int tid) {
  const int o = tid >> 3, u = tid & 7;
  const int ureal = u ^ (o & 7);
  gload16(Wp + o * 128 + kc * 64 + ureal * 8, buf + tid * 16);
}

// residual capture: per t-slot (oc*4+t) one 4-feature quad per graph
struct Cap { h4 q0[8]; h4 q1[8]; };

// ---------------- 8-chunk matmul stage, SWAPPED roles (A=W, B=act) ----------------
// C = [feature row][node col]; lane's 4 acc values = 4 consecutive features of one
// node => packed h4 epilogue into G[node][feature].
// EPI: 0 bias+relu | 2 bias+resid(in-place G) | 3 bias+resid(from rin)
template<int EPI, bool CAP, bool LAST, typename PF>
__device__ __forceinline__ Cap mm128_stage(
    const _Float16* __restrict__ Wp, char* g0, char* g1,
    const _Float16* pb, int bidx, Cap rin,
    char* wbase, int q0, int tid, PF&& pf)
{
  const int lane = tid & 63, wv = tid >> 6, lc = lane & 15, kg = lane >> 4;
  const int nrow = wv * 16 + lc;         // this lane's node (C col)

  h8 bf0[4], bf1[4];   // activations hoisted before any in-place write
#pragma unroll
  for (int i = 0; i < 4; ++i) {
    bf0[i] = ald8(g0, nrow, i * 64 + kg * 16);
    bf1[i] = ald8(g1, nrow, i * 64 + kg * 16);
  }
  Cap rout{};
#pragma unroll
  for (int oc = 0; oc < 2; ++oc) {
    f4 a0[4], a1[4];
#pragma unroll
    for (int t = 0; t < 4; ++t) { a0[t] = (f4){0.f,0.f,0.f,0.f}; a1[t] = (f4){0.f,0.f,0.f,0.f}; }
#pragma unroll
    for (int kc = 0; kc < 4; ++kc) {
      const int ql = oc * 4 + kc;
      if (LAST && ql == 7) waitv<0>(); else waitv<1>();
      rbar();
      const int s = ql + 2;
      char* nbuf = wbase + ((q0 + s) % 3) * 4096;
      if (s < 8) stage64(Wp, 128, s & 3, s >> 2, nbuf, tid);
      else pf(s - 8, nbuf);
      const char* wb = wbase + ((q0 + ql) % 3) * 4096;
#pragma unroll
      for (int t = 0; t < 4; ++t) {
        const int o = t * 16 + lc;
        const int kq = kg ^ ((o >> 1) & 3);
        const h8 af = *(const h8*)(wb + (o * 4 + kq) * 16);
        a0[t] = __builtin_amdgcn_mfma_f32_16x16x32_f16(af, bf0[kc], a0[t], 0, 0, 0);
        a1[t] = __builtin_amdgcn_mfma_f32_16x16x32_f16(af, bf1[kc], a1[t], 0, 0, 0);
      }
    }
#pragma unroll
    for (int t = 0; t < 4; ++t) {
      const int slot = oc * 4 + t;
      const int fb = slot * 16 + kg * 4;
      const int cb = fb * 2;
      h4 bq{};
      if constexpr (EPI != 1) bq = *(const h4*)(pb + bidx * 128 + fb);
      h4 r0q{}, r1q{};
      if constexpr (EPI == 2) {
        r0q = *(const h4*)(g0 + aoff(nrow, cb));
        r1q = *(const h4*)(g1 + aoff(nrow, cb));
      }
      if constexpr (CAP) {
        rout.q0[slot] = *(const h4*)(g0 + aoff(nrow, cb));
        rout.q1[slot] = *(const h4*)(g1 + aoff(nrow, cb));
      }
      h4 o0, o1;
#pragma unroll
      for (int r = 0; r < 4; ++r) {
        float v0 = a0[t][r], v1 = a1[t][r];
        v0 += (float)bq[r]; v1 += (float)bq[r];
        if constexpr (EPI == 2) { v0 += (float)r0q[r]; v1 += (float)r1q[r]; }
        if constexpr (EPI == 3) { v0 += (float)rin.q0[slot][r]; v1 += (float)rin.q1[slot][r]; }
        if constexpr (EPI == 0) { v0 = fmaxf(v0, 0.f); v1 = fmaxf(v1, 0.f); }
        o0[r] = (_Float16)v0; o1[r] = (_Float16)v1;
      }
      *(h4*)(g0 + aoff(nrow, cb)) = o0;
      *(h4*)(g1 + aoff(nrow, cb)) = o1;
    }
  }
  return rout;
}

// ---- W11 Z-stage, OLD orientation (A=act,B=W): C[m=node][n=feat] -> packed
// h4 quads into ZT[feature][node] (same G buffer, in-place; frags hoisted). ----
template<typename PF>
__device__ __forceinline__ void mm32z_old(
    const _Float16* __restrict__ Wp, char* g0, char* g1,
    char* wbase, int q0, int tid, PF&& pf)
{
  const int lane = tid & 63, wv = tid >> 6, lc = lane & 15, kg = lane >> 4;
  const int row0 = wv * 16 + lc, rb = wv * 16 + kg * 4;
  const h8 af0 = ald8(g0, row0, 64 + kg * 16);   // x at logical cols 32..63
  const h8 af1 = ald8(g1, row0, 64 + kg * 16);
#pragma unroll
  for (int oc = 0; oc < 2; ++oc) {
    waitv<1>(); rbar();
    pf(oc, wbase + ((q0 + oc + 2) % 3) * 4096);
    const char* wb = wbase + ((q0 + oc) % 3) * 4096;
    f4 a0[4], a1[4];
#pragma unroll
    for (int t = 0; t < 4; ++t) { a0[t] = (f4){0.f,0.f,0.f,0.f}; a1[t] = (f4){0.f,0.f,0.f,0.f}; }
#pragma unroll
    for (int t = 0; t < 4; ++t) {
      const int o = t * 16 + lc;
      const int kq = kg ^ ((o >> 1) & 3);
      const h8 wf = *(const h8*)(wb + (o * 4 + kq) * 16);
      a0[t] = __builtin_amdgcn_mfma_f32_16x16x32_f16(af0, wf, a0[t], 0, 0, 0);
      a1[t] = __builtin_amdgcn_mfma_f32_16x16x32_f16(af1, wf, a1[t], 0, 0, 0);
    }
#pragma unroll
    for (int t = 0; t < 4; ++t) {
      const int o = oc * 64 + t * 16 + lc;       // output feature (ZT row)
      h4 o0, o1;
#pragma unroll
      for (int r = 0; r < 4; ++r) { o0[r] = (_Float16)a0[t][r]; o1[r] = (_Float16)a1[t][r]; }
      *(h4*)(g0 + zoff(o, rb * 2)) = o0;         // nodes rb..rb+3
      *(h4*)(g1 + zoff(o, rb * 2)) = o1;
    }
  }
}

// ---- W21 Z-stage, OLD orientation, K=128, 8 chunks, raw -> ZT ----
template<typename PF>
__device__ __forceinline__ void mm128z_old(
    const _Float16* __restrict__ Wp, char* g0, char* g1,
    char* wbase, int q0, int tid, PF&& pf)
{
  const int lane = tid & 63, wv = tid >> 6, lc = lane & 15, kg = lane >> 4;
  const int row0 = wv * 16 + lc, rb = wv * 16 + kg * 4;
  h8 af0[4], af1[4];
#pragma unroll
  for (int i = 0; i < 4; ++i) {
    af0[i] = ald8(g0, row0, i * 64 + kg * 16);
    af1[i] = ald8(g1, row0, i * 64 + kg * 16);
  }
#pragma unroll
  for (int oc = 0; oc < 2; ++oc) {
    f4 a0[4], a1[4];
#pragma unroll
    for (int t = 0; t < 4; ++t) { a0[t] = (f4){0.f,0.f,0.f,0.f}; a1[t] = (f4){0.f,0.f,0.f,0.f}; }
#pragma unroll
    for (int kc = 0; kc < 4; ++kc) {
      const int ql = oc * 4 + kc;
      waitv<1>();
      rbar();
      const int s = ql + 2;
      char* nbuf = wbase + ((q0 + s) % 3) * 4096;
      if (s < 8) stage64(Wp, 128, s & 3, s >> 2, nbuf, tid);
      else pf(s - 8, nbuf);
      const char* wb = wbase + ((q0 + ql) % 3) * 4096;
#pragma unroll
      for (int t = 0; t < 4; ++t) {
        const int o = t * 16 + lc;
        const int kq = kg ^ ((o >> 1) & 3);
        const h8 wf = *(const h8*)(wb + (o * 4 + kq) * 16);
        a0[t] = __builtin_amdgcn_mfma_f32_16x16x32_f16(af0[kc], wf, a0[t], 0, 0, 0);
        a1[t] = __builtin_amdgcn_mfma_f32_16x16x32_f16(af1[kc], wf, a1[t], 0, 0, 0);
      }
    }
#pragma unroll
    for (int t = 0; t < 4; ++t) {
      const int o = oc * 64 + t * 16 + lc;
      h4 o0, o1;
#pragma unroll
      for (int r = 0; r < 4; ++r) { o0[r] = (_Float16)a0[t][r]; o1[r] = (_Float16)a1[t][r]; }
      *(h4*)(g0 + zoff(o, rb * 2)) = o0;
      *(h4*)(g1 + zoff(o, rb * 2)) = o1;
    }
  }
}

// ---- aggregation from ZT, both graphs: G <- relu(bias + Z M') where
// D[f][j] = sum_i ZT[f][i] M'[i][j]; A = ZT rows (vector reads), B = mask bits.
// Output lane = 4 consecutive features of one node -> packed h4 into G. ----
__device__ __forceinline__ void agg2_zt(
    const u64* mc0, const u64* mc1, char* g0, char* g1,
    const _Float16* pb, int bidx, int tid)
{
  const int lane = tid & 63, wv = tid >> 6, lc = lane & 15, kg = lane >> 4;
  const int fb = wv * 32;                       // this wave's 32 features
  h8 a0[2][2], a1[2][2];                        // [mt][ks]
#pragma unroll
  for (int mt = 0; mt < 2; ++mt)
#pragma unroll
    for (int ks = 0; ks < 2; ++ks) {
      a0[mt][ks] = *(const h8*)(g0 + zoff(fb + mt * 16 + lc, ks * 64 + kg * 16));
      a1[mt][ks] = *(const h8*)(g1 + zoff(fb + mt * 16 + lc, ks * 64 + kg * 16));
    }
  u64 mr0[4], mr1[4];
#pragma unroll
  for (int nt = 0; nt < 4; ++nt) { mr0[nt] = mc0[nt * 16 + lc]; mr1[nt] = mc1[nt * 16 + lc]; }
  lgkm0(); rbar();                              // all reads landed before any write
  f4 c0[2][4], c1[2][4];
#pragma unroll
  for (int mt = 0; mt < 2; ++mt)
#pragma unroll
    for (int nt = 0; nt < 4; ++nt) { c0[mt][nt] = (f4){0.f,0.f,0.f,0.f}; c1[mt][nt] = (f4){0.f,0.f,0.f,0.f}; }
#pragma unroll
  for (int ks = 0; ks < 2; ++ks)
#pragma unroll
    for (int nt = 0; nt < 4; ++nt) {
      h8 b0, b1;
#pragma unroll
      for (int e = 0; e < 8; ++e) {
        b0[e] = (_Float16)((mr0[nt] >> (ks * 32 + kg * 8 + e)) & 1ull);
        b1[e] = (_Float16)((mr1[nt] >> (ks * 32 + kg * 8 + e)) & 1ull);
      }
#pragma unroll
      for (int mt = 0; mt < 2; ++mt) {
        c0[mt][nt] = __builtin_amdgcn_mfma_f32_16x16x32_f16(a0[mt][ks], b0, c0[mt][nt], 0, 0, 0);
        c1[mt][nt] = __builtin_amdgcn_mfma_f32_16x16x32_f16(a1[mt][ks], b1, c1[mt][nt], 0, 0, 0);
      }
    }
#pragma unroll
  for (int mt = 0; mt < 2; ++mt) {
    const int f0 = fb + mt * 16 + kg * 4;       // 4 consecutive features
    const h4 bq = *(const h4*)(pb + bidx * 128 + f0);
#pragma unroll
    for (int nt = 0; nt < 4; ++nt) {
      const int j = nt * 16 + lc;
      h4 o0, o1;
#pragma unroll
      for (int r = 0; r < 4; ++r) {
        o0[r] = (_Float16)fmaxf(c0[mt][nt][r] + (float)bq[r], 0.f);
        o1[r] = (_Float16)fmaxf(c1[mt][nt][r] + (float)bq[r], 0.f);
      }
      *(h4*)(g0 + aoff(j, f0 * 2)) = o0;
      *(h4*)(g1 + aoff(j, f0 * 2)) = o1;
    }
  }
}

// standalone in-place LN, wave-local rows (n = tid>>2), f16 params from PB
__device__ __forceinline__ void layer_norm(char* buf, const _Float16* pb, int lnidx, int tid)
{
  const int n = tid >> 2, q = tid & 3;
  float vals[32];
#pragma unroll
  for (int u = 0; u < 4; ++u) {
    const h8 v = ald8(buf, n, q * 64 + u * 16);
#pragma unroll
    for (int e = 0; e < 8; ++e) vals[u * 8 + e] = (float)v[e];
  }
  float s = 0.f;
#pragma unroll
  for (int u = 0; u < 32; ++u) s += vals[u];
  s += __shfl_xor(s, 1, 64);
  s += __shfl_xor(s, 2, 64);
  const float mean = s * 0.0078125f;
  float vv = 0.f;
#pragma unroll
  for (int u = 0; u < 32; ++u) { const float d = vals[u] - mean; vv = fmaf(d, d, vv); }
  vv += __shfl_xor(vv, 1, 64);
  vv += __shfl_xor(vv, 2, 64);
  const float rstd = 1.0f / sqrtf(vv * 0.0078125f + 1e-5f);
#pragma unroll
  for (int u = 0; u < 4; ++u) {
    h8 o;
#pragma unroll
    for (int e = 0; e < 8; ++e) {
      const int col = q * 32 + u * 8 + e;
      const float gg = (float)pb[lnidx * 128 + col];
      const float bb = (float)pb[(lnidx + 1) * 128 + col];
      o[e] = (_Float16)((vals[u * 8 + e] - mean) * rstd * gg + bb);
    }
    ast8(buf, n, q * 64 + u * 16, o);
  }
}

struct SM {
  alignas(16) char G0[16384];
  alignas(16) char G1[16384];
  alignas(16) char WB[12288];
  alignas(16) char PB[5120];       // params [20][128] f16
  u64 mcol[2][64];
};   // 51200 B -> 3 blocks/CU

// (256,2): VGPR cap 256 — a (256,3) cap forced mass spill in rounds 8-10.
__global__ __launch_bounds__(256, 2)
void gin_critic_kernel(
    const float* __restrict__ data,
    const float* __restrict__ Wfc, const float* __restrict__ bfc,
    const _Float16* __restrict__ ws,
    float* __restrict__ out)
{
  __shared__ SM sm;
  const int tid = threadIdx.x;
  const int lane = tid & 63, wv = tid >> 6, lc = lane & 15, kg = lane >> 4;
  const int row0 = wv * 16 + lc, rb = wv * 16 + kg * 4;
  const int b = blockIdx.x;
  const long base = (long)b * 2 * NN * 27;
  char* G0 = sm.G0; char* G1 = sm.G1; char* wbase = sm.WB;
  const _Float16* pb = (const _Float16*)sm.PB;

  const _Float16* Wl1p = ws + 0;
  const _Float16* Wl2p = ws + 4096;
  const _Float16* W11p = ws + 8192;
  const _Float16* W12p = ws + 12288;
  const _Float16* W21p = ws + 28672;
  const _Float16* W22p = ws + 45056;
  const _Float16* Wat0 = ws + 61440;
  const _Float16* Wat1 = ws + 61440 + 16384;
  const _Float16* Wf1_0 = ws + 94208;
  const _Float16* Wf1_1 = ws + 94208 + 16384;
  const _Float16* Wf2_0 = ws + 126976;
  const _Float16* Wf2_1 = ws + 126976 + 16384;

  // ---- input staging: lidar -> cols 0..19, orig7 -> cols 32..38 ----
#pragma unroll
  for (int i = 0; i < 14; ++i) {
    const int idx = tid + i * 256;
    const int cidx = idx < 3456 ? idx : 3455;
    float v = data[base + cidx];
    asm volatile("" : "+v"(v));
    if (idx < 3456) {
      const int gi = idx / 1728;
      const int r = idx - gi * 1728;
      const int n = r / 27, f = r - n * 27;
      char* Gg = gi ? G1 : G0;
      if (f < 7) ast(Gg, n, 64 + f * 2, (_Float16)v);
      else       ast(Gg, n, (f - 7) * 2, (_Float16)v);
    }
  }
  if (tid < 128) {
    const int gi = tid >> 6, n = tid & 63;
    char* Gg = gi ? G1 : G0;
#pragma unroll
    for (int c = 20; c < 32; ++c) ast(Gg, n, c * 2, (_Float16)0.f);
#pragma unroll
    for (int c = 59; c < 64; ++c) ast(Gg, n, c * 2, (_Float16)0.f);
  }
  const float* pp = data + base + (long)(wv >> 1) * 1728 + lane * 27;
  const float px = pp[0], py = pp[1];
  lgkm0(); rbar();   // staged inputs visible

  // ---- adjacency mask (exact double cone + guard-band atan2 fallback) ----
  {
    const int g = wv >> 1;
    const float FOVF = (float)(0.35 * 3.14159265358979323846);
    const double TT = tan(0.35 * 3.14159265358979323846);
    const double T2 = TT * TT;
    for (int jj = 0; jj < 32; ++jj) {
      const int j = (wv & 1) * 32 + jj;
      const float x0j = __shfl(px, j, 64);
      const float x1j = __shfl(py, j, 64);
      const float dxf = px - x0j;
      const float dyf = py - x1j;
      const float dist = sqrtf(dxf * dxf + dyf * dyf);
      bool pred;
      if (lane == j || dist > 10.0f) {
        pred = false;
      } else if (dxf <= 0.0f) {
        pred = (dxf == 0.0f && dyf == 0.0f);
      } else {
        const double qa = (double)dyf * (double)dyf;
        const double qb = (double)dxf * (double)dxf * T2;
        if (qa <= qb * 0.99999) pred = true;
        else if (qa >= qb * 1.00001) pred = false;
        else pred = (fabsf((float)atan2((double)dyf, (double)dxf)) <= FOVF);
      }
      const u64 bal = __ballot(pred);
      if (lane == 0) sm.mcol[g][j] = bal | (1ull << j);
    }
  }

  // ---- FIFO start: params (2 uniform loads) + chunks q0,q1 ----
  gload16(ws + 159744 + (size_t)tid * 8, sm.PB + (size_t)tid * 16);
  gload16(ws + 159744 + 2048 + (size_t)(tid & 63) * 8, sm.PB + 4096 + (size_t)(tid & 63) * 16);
  stage64(Wl1p, 32, 0, 0, wbase + 0 * 4096, tid);   // q0: L1a
  stage32(Wl2p, 0, wbase + 1 * 4096, tid);          // q1: L2a

  // ---- lidar MLP (hand-rolled, chunks q0..q3, hidden time-shared cols 64..127) ----
  h8 axl0, axl1;
  f4 l20[2], l21[2];
  l20[0] = l20[1] = l21[0] = l21[1] = (f4){0.f,0.f,0.f,0.f};
  // q0: L1a -> hidden[0..63] at cols 64..127
  waitv<1>(); rbar();
  stage64(Wl1p, 32, 0, 1, wbase + 2 * 4096, tid);   // q2: L1b
  axl0 = ald8(G0, row0, kg * 16);
  axl1 = ald8(G1, row0, kg * 16);
  {
    const char* wb = wbase + 0 * 4096;
    f4 a0[4], a1[4];
#pragma unroll
    for (int t = 0; t < 4; ++t) { a0[t] = (f4){0.f,0.f,0.f,0.f}; a1[t] = (f4){0.f,0.f,0.f,0.f}; }
#pragma unroll
    for (int t = 0; t < 4; ++t) {
      const int o = t * 16 + lc;
      const int kq = kg ^ ((o >> 1) & 3);
      const h8 bf = *(const h8*)(wb + (o * 4 + kq) * 16);
      a0[t] = __builtin_amdgcn_mfma_f32_16x16x32_f16(axl0, bf, a0[t], 0, 0, 0);
      a1[t] = __builtin_amdgcn_mfma_f32_16x16x32_f16(axl1, bf, a1[t], 0, 0, 0);
    }
#pragma unroll
    for (int t = 0; t < 4; ++t) {
      const int col = t * 16 + lc;
      const float bv = (float)pb[0 * 128 + col];
#pragma unroll
      for (int r = 0; r < 4; ++r) {
        ast(G0, rb + r, 128 + col * 2, (_Float16)fmaxf(a0[t][r] + bv, 0.f));
        ast(G1, rb + r, 128 + col * 2, (_Float16)fmaxf(a1[t][r] + bv, 0.f));
      }
    }
  }
  // q1: L2a (K-half 0)
  waitv<1>(); rbar();
  stage32(Wl2p, 1, wbase + 0 * 4096, tid);          // q3: L2b
  {
    const char* wb = wbase + 1 * 4096;
    h8 ah0[2], ah1[2];
#pragma unroll
    for (int i = 0; i < 2; ++i) {
      ah0[i] = ald8(G0, row0, 128 + i * 64 + kg * 16);
      ah1[i] = ald8(G1, row0, 128 + i * 64 + kg * 16);
    }
#pragma unroll
    for (int ks = 0; ks < 2; ++ks)
#pragma unroll
      for (int ct = 0; ct < 2; ++ct) {
        const int o = ct * 16 + lc;
        const int u = (ks * 4 + kg) ^ (o & 7);
        const h8 bf = *(const h8*)(wb + (o * 8 + u) * 16);
        l20[ct] = __builtin_amdgcn_mfma_f32_16x16x32_f16(ah0[ks], bf, l20[ct], 0, 0, 0);
        l21[ct] = __builtin_amdgcn_mfma_f32_16x16x32_f16(ah1[ks], bf, l21[ct], 0, 0, 0);
      }
  }
  // q2: L1b -> hidden[64..127] overwrites cols 64..127
  waitv<1>(); rbar();
  stage64(W11p, 32, 0, 0, wbase + 1 * 4096, tid);   // q4: W11 oc0
  {
    const char* wb = wbase + 2 * 4096;
    f4 a0[4], a1[4];
#pragma unroll
    for (int t = 0; t < 4; ++t) { a0[t] = (f4){0.f,0.f,0.f,0.f}; a1[t] = (f4){0.f,0.f,0.f,0.f}; }
#pragma unroll
    for (int t = 0; t < 4; ++t) {
      const int o = t * 16 + lc;
      const int kq = kg ^ ((o >> 1) & 3);
      const h8 bf = *(const h8*)(wb + (o * 4 + kq) * 16);
      a0[t] = __builtin_amdgcn_mfma_f32_16x16x32_f16(axl0, bf, a0[t], 0, 0, 0);
      a1[t] = __builtin_amdgcn_mfma_f32_16x16x32_f16(axl1, bf, a1[t], 0, 0, 0);
    }
#pragma unroll
    for (int t = 0; t < 4; ++t) {
      const int col = t * 16 + lc;
      const float bv = (float)pb[0 * 128 + 64 + col];
#pragma unroll
      for (int r = 0; r < 4; ++r) {
        ast(G0, rb + r, 128 + col * 2, (_Float16)fmaxf(a0[t][r] + bv, 0.f));
        ast(G1, rb + r, 128 + col * 2, (_Float16)fmaxf(a1[t][r] + bv, 0.f));
      }
    }
  }
  // q3: L2b (K-half 1) -> lf20 into cols 39..58
  waitv<1>(); rbar();
  stage64(W11p, 32, 0, 1, wbase + 2 * 4096, tid);   // q5: W11 oc1
  {
    const char* wb = wbase + 0 * 4096;
    h8 ah0[2], ah1[2];
#pragma unroll
    for (int i = 0; i < 2; ++i) {
      ah0[i] = ald8(G0, row0, 128 + i * 64 + kg * 16);
      ah1[i] = ald8(G1, row0, 128 + i * 64 + kg * 16);
    }
#pragma unroll
    for (int ks = 0; ks < 2; ++ks)
#pragma unroll
      for (int ct = 0; ct < 2; ++ct) {
        const int o = ct * 16 + lc;
        const int u = (ks * 4 + kg) ^ (o & 7);
        const h8 bf = *(const h8*)(wb + (o * 8 + u) * 16);
        l20[ct] = __builtin_amdgcn_mfma_f32_16x16x32_f16(ah0[ks], bf, l20[ct], 0, 0, 0);
        l21[ct] = __builtin_amdgcn_mfma_f32_16x16x32_f16(ah1[ks], bf, l21[ct], 0, 0, 0);
      }
#pragma unroll
    for (int ct = 0; ct < 2; ++ct) {
      const int col = ct * 16 + lc;
      if (col < 20) {
        const float bv = (float)pb[1 * 128 + col];
#pragma unroll
        for (int r = 0; r < 4; ++r) {
          ast(G0, rb + r, 78 + col * 2, (_Float16)fmaxf(l20[ct][r] + bv, 0.f));
          ast(G1, rb + r, 78 + col * 2, (_Float16)fmaxf(l21[ct][r] + bv, 0.f));
        }
      }
    }
  }

  Cap rz{};
  // W11 Z-stage (q4,q5): ZT1 = (x.W11^T)^T into G as [feat][node]
  mm32z_old(W11p, G0, G1, wbase, 4, tid,
      [&](int s, char* buf) { stage64(W12p, 128, s, 0, buf, tid); });
  lgkm0(); rbar();
  // GIN1 agg: h1 = relu(M'^T Z1 + b11) -> G normal layout
  agg2_zt(sm.mcol[0], sm.mcol[1], G0, G1, pb, 2, tid);
  lgkm0(); rbar();
  // W12
  mm128_stage<0, false, false>(W12p, G0, G1, pb, 3, rz, wbase, 6, tid,
      [&](int s, char* buf) { stage64(W21p, 128, s, 0, buf, tid); });
  // W21 Z-stage: ZT2 into G
  mm128z_old(W21p, G0, G1, wbase, 14, tid,
      [&](int s, char* buf) { stage64(W22p, 128, s, 0, buf, tid); });
  lgkm0(); rbar();
  // GIN2 agg
  agg2_zt(sm.mcol[0], sm.mcol[1], G0, G1, pb, 4, tid);
  lgkm0(); rbar();
  // W22: t
  mm128_stage<0, false, false>(W22p, G0, G1, pb, 5, rz, wbase, 22, tid,
      [&](int s, char* buf) { stage64(Wat0, 128, s, 0, buf, tid); });
  // ---- transformer layer 0 ----
  mm128_stage<2, false, false>(Wat0, G0, G1, pb, 6, rz, wbase, 30, tid,
      [&](int s, char* buf) { stage64(Wf1_0, 128, s, 0, buf, tid); });
  layer_norm(G0, pb, 12, tid);
  layer_norm(G1, pb, 12, tid);
  Cap c0 = mm128_stage<0, true, false>(Wf1_0, G0, G1, pb, 8, rz, wbase, 38, tid,
      [&](int s, char* buf) { stage64(Wf2_0, 128, s, 0, buf, tid); });
  mm128_stage<3, false, false>(Wf2_0, G0, G1, pb, 9, c0, wbase, 46, tid,
      [&](int s, char* buf) { stage64(Wat1, 128, s, 0, buf, tid); });
  layer_norm(G0, pb, 14, tid);
  layer_norm(G1, pb, 14, tid);
  // ---- transformer layer 1 ----
  mm128_stage<2, false, false>(Wat1, G0, G1, pb, 7, rz, wbase, 54, tid,
      [&](int s, char* buf) { stage64(Wf1_1, 128, s, 0, buf, tid); });
  layer_norm(G0, pb, 16, tid);
  layer_norm(G1, pb, 16, tid);
  Cap c1 = mm128_stage<0, true, false>(Wf1_1, G0, G1, pb, 10, rz, wbase, 62, tid,
      [&](int s, char* buf) { stage64(Wf2_1, 128, s, 0, buf, tid); });
  mm128_stage<3, false, true>(Wf2_1, G0, G1, pb, 11, c1, wbase, 70, tid,
      [&](int, char*) {});
  layer_norm(G0, pb, 18, tid);
  layer_norm(G1, pb, 18, tid);

  // ---- head (wave-local rows) ----
#pragma unroll
  for (int g = 0; g < 2; ++g) {
    const char* Pg = g ? G1 : G0;
    const int n = tid >> 2, q = tid & 3;
    float s = 0.f;
#pragma unroll
    for (int u = 0; u < 4; ++u) {
      const h8 v = ald8(Pg, n, q * 64 + u * 16);
      const float4 w0 = *(const float4*)(Wfc + q * 32 + u * 8);
      const float4 w1 = *(const float4*)(Wfc + q * 32 + u * 8 + 4);
      s = fmaf((float)v[0], w0.x, s); s = fmaf((float)v[1], w0.y, s);
      s = fmaf((float)v[2], w0.z, s); s = fmaf((float)v[3], w0.w, s);
      s = fmaf((float)v[4], w1.x, s); s = fmaf((float)v[5], w1.y, s);
      s = fmaf((float)v[6], w1.z, s); s = fmaf((float)v[7], w1.w, s);
    }
    s += __shfl_xor(s, 1, 64);
    s += __shfl_xor(s, 2, 64);
    if (q == 0) out[((long)b * 2 + g) * NN + n] = s + bfc[0];
  }
}

extern "C" void kernel_launch(void* const* d_in, const int* in_sizes, int n_in,
                              void* d_out, int out_size, void* d_ws, size_t ws_size,
                              hipStream_t stream) {
  const float* data  = (const float*)d_in[0];
  const float* W_l1  = (const float*)d_in[1];
  const float* b_l1  = (const float*)d_in[2];
  const float* W_l2  = (const float*)d_in[3];
  const float* b_l2  = (const float*)d_in[4];
  const float* W11   = (const float*)d_in[5];
  const float* b11   = (const float*)d_in[6];
  const float* W12   = (const float*)d_in[7];
  const float* b12   = (const float*)d_in[8];
  const float* W21   = (const float*)d_in[9];
  const float* b21   = (const float*)d_in[10];
  const float* W22   = (const float*)d_in[11];
  const float* b22   = (const float*)d_in[12];
  const float* Wqkv  = (const float*)d_in[13];
  const float* bqkv  = (const float*)d_in[14];
  const float* Wo    = (const float*)d_in[15];
  const float* bo    = (const float*)d_in[16];
  const float* ln1_g = (const float*)d_in[17];
  const float* ln1_b = (const float*)d_in[18];
  const float* Wf1   = (const float*)d_in[19];
  const float* bf1   = (const float*)d_in[20];
  const float* Wf2   = (const float*)d_in[21];
  const float* bf2   = (const float*)d_in[22];
  const float* ln2_g = (const float*)d_in[23];
  const float* ln2_b = (const float*)d_in[24];
  const float* Wfc   = (const float*)d_in[25];
  const float* bfc   = (const float*)d_in[26];

  _Float16* ws = (_Float16*)d_ws;

  prepA<<<dim3(634), dim3(256), 0, stream>>>(
      W_l1, W_l2, W11, W12, W21, W22, Wf1, Wf2,
      b_l1, b_l2, b11, b12, b21, b22, bf1, bf2,
      ln1_g, ln1_b, ln2_g, ln2_b, ws);
  prepB<<<dim3(129), dim3(256), 0, stream>>>(Wqkv, bqkv, Wo, bo, ws);

  gin_critic_kernel<<<dim3(NB / 2), dim3(256), 0, stream>>>(
      data, Wfc, bfc, ws, (float*)d_out);
}

// Round 14
// 180.859 us; speedup vs baseline: 1.8966x; 1.0690x over previous
//
#include <hip/hip_runtime.h>
#include <math.h>

#define NB 4096
#define NN 64

typedef _Float16 h8 __attribute__((ext_vector_type(8)));
typedef _Float16 h4 __attribute__((ext_vector_type(4)));
typedef float f4 __attribute__((ext_vector_type(4)));
typedef unsigned long long u64;

typedef const __attribute__((address_space(1))) void* gas_t;
typedef __attribute__((address_space(3))) void* las_t;

__device__ __forceinline__ void gload16(const void* g, void* l) {
  __builtin_amdgcn_global_load_lds((gas_t)g, (las_t)l, 16, 0, 0);
}
__device__ __forceinline__ void rbar() {
  asm volatile("" ::: "memory");
  __builtin_amdgcn_s_barrier();
  asm volatile("" ::: "memory");
}
__device__ __forceinline__ void lgkm0() {
  asm volatile("s_waitcnt lgkmcnt(0)" ::: "memory");
}
template<int N> __device__ __forceinline__ void waitv() {
  if constexpr (N == 0) asm volatile("s_waitcnt vmcnt(0)" ::: "memory");
  else                  asm volatile("s_waitcnt vmcnt(1)" ::: "memory");
  __builtin_amdgcn_sched_barrier(0);
}

// activation buffers: 64 rows x 128 f16, 256 B row stride, 4-bit slot XOR
__device__ __forceinline__ int aoff(int row, int colb) {
  return row * 256 + (colb ^ ((row & 15) << 4));
}
__device__ __forceinline__ h8 ald8(const char* a, int row, int colb) {
  return *(const h8*)(a + aoff(row, colb));
}
__device__ __forceinline__ void ast8(char* a, int row, int colb, h8 v) {
  *(h8*)(a + aoff(row, colb)) = v;
}
__device__ __forceinline__ _Float16 ald(const char* a, int row, int colb) {
  return *(const _Float16*)(a + aoff(row, colb));
}
__device__ __forceinline__ void ast(char* a, int row, int colb, _Float16 v) {
  *(_Float16*)(a + aoff(row, colb)) = v;
}
// transposed Z layout in the SAME 16KB buffer: ZT[feature][node], 128 B stride
__device__ __forceinline__ int zoff(int f, int nb) {   // nb = node*2 (bytes)
  return f * 128 + ((((nb >> 4) ^ (f & 7)) << 4) | (nb & 15));
}

// ---------------- weight prep (unchanged from r13) ----------------
__global__ void prepA(
    const float* __restrict__ W_l1, const float* __restrict__ W_l2,
    const float* __restrict__ W11, const float* __restrict__ W12,
    const float* __restrict__ W21, const float* __restrict__ W22,
    const float* __restrict__ Wf1, const float* __restrict__ Wf2,
    const float* __restrict__ b_l1, const float* __restrict__ b_l2,
    const float* __restrict__ b11, const float* __restrict__ b12,
    const float* __restrict__ b21, const float* __restrict__ b22,
    const float* __restrict__ bf1, const float* __restrict__ bf2,
    const float* __restrict__ ln1_g, const float* __restrict__ ln1_b,
    const float* __restrict__ ln2_g, const float* __restrict__ ln2_b,
    _Float16* __restrict__ ws)
{
  const int e = blockIdx.x * 256 + threadIdx.x;
  float v;
  if (e < 4096) { const int o = e >> 5, k = e & 31; v = (k < 20) ? W_l1[o * 20 + k] : 0.f; }
  else if (e < 8192) { const int i = e - 4096; const int o = i >> 7, k = i & 127; v = (o < 20) ? W_l2[o * 128 + k] : 0.f; }
  else if (e < 12288) { const int i = e - 8192; const int o = i >> 5, k = i & 31; v = (k < 27) ? W11[o * 27 + k] : 0.f; }
  else if (e < 28672) v = W12[e - 12288];
  else if (e < 45056) v = W21[e - 28672];
  else if (e < 61440) v = W22[e - 45056];
  else if (e < 94208) return;                      // Wat by prepB
  else if (e < 126976) v = Wf1[e - 94208];
  else if (e < 159744) v = Wf2[e - 126976];
  else {
    const int p = e - 159744;
    if (p >= 2560) return;
    const int idx = p >> 7, col = p & 127;
    switch (idx) {
      case 0: v = b_l1[col]; break;
      case 1: v = (col < 20) ? b_l2[col] : 0.f; break;
      case 2: v = b11[col]; break;
      case 3: v = b12[col]; break;
      case 4: v = b21[col]; break;
      case 5: v = b22[col]; break;
      case 8: v = bf1[col]; break;
      case 9: v = bf2[col]; break;
      case 10: v = bf1[128 + col]; break;
      case 11: v = bf2[128 + col]; break;
      case 12: v = ln1_g[col]; break;
      case 13: v = ln1_b[col]; break;
      case 14: v = ln2_g[col]; break;
      case 15: v = ln2_b[col]; break;
      case 16: v = ln1_g[128 + col]; break;
      case 17: v = ln1_b[128 + col]; break;
      case 18: v = ln2_g[128 + col]; break;
      case 19: v = ln2_b[128 + col]; break;
      default: v = 0.f; break;                      // 6,7 by prepB
    }
  }
  ws[e] = (_Float16)v;
}

__global__ void prepB(
    const float* __restrict__ Wqkv, const float* __restrict__ bqkv,
    const float* __restrict__ Wo, const float* __restrict__ bo,
    _Float16* __restrict__ ws)
{
  if (blockIdx.x < 128) {
    const int e = blockIdx.x * 256 + threadIdx.x;       // 0..32767
    const int l = e >> 14, r = e & 16383, o = r >> 7, k = r & 127;
    const float* wo = Wo + (l * 128 + o) * 128;
    const float* wv = Wqkv + l * 49152 + 32768 + k;
    float acc = 0.f;
#pragma unroll 4
    for (int m = 0; m < 128; ++m) acc += wo[m] * wv[m * 128];
    ws[61440 + e] = (_Float16)acc;
  } else {
    const int t = threadIdx.x;                          // bat[2][128]
    const int l = t >> 7, o = t & 127;
    const float* wo = Wo + (l * 128 + o) * 128;
    const float* bv = bqkv + l * 384 + 256;
    float acc = bo[l * 128 + o];
    for (int m = 0; m < 128; ++m) acc += bv[m] * wo[m];
    ws[159744 + (6 + l) * 128 + o] = (_Float16)acc;
  }
}

// ---------------- chunk staging (4 KB, pre-swizzled source) ----------------
__device__ __forceinline__ void stage64(const _Float16* __restrict__ Wp, int KT,
                                        int kc, int oc, char* buf, int tid) {
  const int o = tid >> 2, kq = tid & 3;
  const int kreal = kq ^ ((o >> 1) & 3);
  gload16(Wp + (oc * 64 + o) * KT + kc * 32 + kreal * 8, buf + tid * 16);
}
__device__ __forceinline__ void stage32(const _Float16* __restrict__ Wp,
                                        int kc, char* buf, int tid) {
  const int o = tid >> 3, u = tid & 7;
  const int ureal = u ^ (o & 7);
  gload16(Wp + o * 128 + kc * 64 + ureal * 8, buf + tid * 16);
}

// residual capture: per t-slot one 4-feature quad per graph
struct Cap { h4 q0[8]; h4 q1[8]; };

// ---------------- 8-chunk matmul stage, swapped roles (A=W, B=act) ----------------
// Q0 = compile-time FIFO phase: all buffer bases constant-fold.
// EPI: 0 bias+relu | 2 bias+residG | 4 bias+residG+LN | 5 bias+residCap+LN
template<int EPI, bool CAP, bool LAST, int Q0, typename PF>
__device__ __forceinline__ Cap mm128_stage(
    const _Float16* __restrict__ Wp, char* g0, char* g1,
    const _Float16* pb, int bidx, int lnidx, Cap rin,
    char* wbase, int tid, PF&& pf)
{
  const int lane = tid & 63, wv = tid >> 6, lc = lane & 15, kg = lane >> 4;
  const int nrow = wv * 16 + lc;

  h8 bf0[4], bf1[4];   // activations hoisted before any in-place write
#pragma unroll
  for (int i = 0; i < 4; ++i) {
    bf0[i] = ald8(g0, nrow, i * 64 + kg * 16);
    bf1[i] = ald8(g1, nrow, i * 64 + kg * 16);
  }
  Cap rout{};

  if constexpr (EPI < 4) {
    // per-half accumulator release (low VGPR)
#pragma unroll
    for (int oc = 0; oc < 2; ++oc) {
      f4 a0[4], a1[4];
#pragma unroll
      for (int t = 0; t < 4; ++t) { a0[t] = (f4){0.f,0.f,0.f,0.f}; a1[t] = (f4){0.f,0.f,0.f,0.f}; }
#pragma unroll
      for (int kc = 0; kc < 4; ++kc) {
        const int ql = oc * 4 + kc;
        if (LAST && ql == 7) waitv<0>(); else waitv<1>();
        rbar();
        const int s = ql + 2;
        char* nbuf = wbase + ((Q0 + s) % 3) * 4096;
        if (s < 8) stage64(Wp, 128, s & 3, s >> 2, nbuf, tid);
        else pf(s - 8, nbuf);
        const char* wb = wbase + ((Q0 + ql) % 3) * 4096;
#pragma unroll
        for (int t = 0; t < 4; ++t) {
          const int o = t * 16 + lc;
          const int kq = kg ^ ((o >> 1) & 3);
          const h8 af = *(const h8*)(wb + (o * 4 + kq) * 16);
          a0[t] = __builtin_amdgcn_mfma_f32_16x16x32_f16(af, bf0[kc], a0[t], 0, 0, 0);
          a1[t] = __builtin_amdgcn_mfma_f32_16x16x32_f16(af, bf1[kc], a1[t], 0, 0, 0);
        }
      }
#pragma unroll
      for (int t = 0; t < 4; ++t) {
        const int slot = oc * 4 + t;
        const int fb = slot * 16 + kg * 4;
        const int cb = fb * 2;
        const h4 bq = *(const h4*)(pb + bidx * 128 + fb);
        h4 r0q{}, r1q{};
        if constexpr (EPI == 2) {
          r0q = *(const h4*)(g0 + aoff(nrow, cb));
          r1q = *(const h4*)(g1 + aoff(nrow, cb));
        }
        if constexpr (CAP) {
          rout.q0[slot] = *(const h4*)(g0 + aoff(nrow, cb));
          rout.q1[slot] = *(const h4*)(g1 + aoff(nrow, cb));
        }
        h4 o0, o1;
#pragma unroll
        for (int r = 0; r < 4; ++r) {
          float v0 = a0[t][r] + (float)bq[r], v1 = a1[t][r] + (float)bq[r];
          if constexpr (EPI == 2) { v0 += (float)r0q[r]; v1 += (float)r1q[r]; }
          if constexpr (EPI == 0) { v0 = fmaxf(v0, 0.f); v1 = fmaxf(v1, 0.f); }
          o0[r] = (_Float16)v0; o1[r] = (_Float16)v1;
        }
        *(h4*)(g0 + aoff(nrow, cb)) = o0;
        *(h4*)(g1 + aoff(nrow, cb)) = o1;
      }
    }
  } else {
    // fused-LN path: full-width acc; 4 kg-lanes of nrow jointly hold 128 feats
    f4 a0[8], a1[8];
#pragma unroll
    for (int t = 0; t < 8; ++t) { a0[t] = (f4){0.f,0.f,0.f,0.f}; a1[t] = (f4){0.f,0.f,0.f,0.f}; }
#pragma unroll
    for (int ql = 0; ql < 8; ++ql) {
      if (LAST && ql == 7) waitv<0>(); else waitv<1>();
      rbar();
      const int s = ql + 2;
      char* nbuf = wbase + ((Q0 + s) % 3) * 4096;
      if (s < 8) stage64(Wp, 128, s & 3, s >> 2, nbuf, tid);
      else pf(s - 8, nbuf);
      const char* wb = wbase + ((Q0 + ql) % 3) * 4096;
      const int oc = ql >> 2, kc = ql & 3;
#pragma unroll
      for (int t = 0; t < 4; ++t) {
        const int o = t * 16 + lc;
        const int kq = kg ^ ((o >> 1) & 3);
        const h8 af = *(const h8*)(wb + (o * 4 + kq) * 16);
        a0[oc * 4 + t] = __builtin_amdgcn_mfma_f32_16x16x32_f16(af, bf0[kc], a0[oc * 4 + t], 0, 0, 0);
        a1[oc * 4 + t] = __builtin_amdgcn_mfma_f32_16x16x32_f16(af, bf1[kc], a1[oc * 4 + t], 0, 0, 0);
      }
    }
    // bias + residual
#pragma unroll
    for (int slot = 0; slot < 8; ++slot) {
      const int fb = slot * 16 + kg * 4;
      const h4 bq = *(const h4*)(pb + bidx * 128 + fb);
      h4 r0q, r1q;
      if constexpr (EPI == 4) {
        r0q = *(const h4*)(g0 + aoff(nrow, fb * 2));
        r1q = *(const h4*)(g1 + aoff(nrow, fb * 2));
      } else {
        r0q = rin.q0[slot]; r1q = rin.q1[slot];
      }
#pragma unroll
      for (int r = 0; r < 4; ++r) {
        a0[slot][r] += (float)bq[r] + (float)r0q[r];
        a1[slot][r] += (float)bq[r] + (float)r1q[r];
      }
    }
    // LN: mean/var over 128 via 8x4 in-reg + shfl_xor 16,32 (kg reduce)
    float s0 = 0.f, s1 = 0.f;
#pragma unroll
    for (int slot = 0; slot < 8; ++slot)
#pragma unroll
      for (int r = 0; r < 4; ++r) { s0 += a0[slot][r]; s1 += a1[slot][r]; }
    s0 += __shfl_xor(s0, 16, 64); s0 += __shfl_xor(s0, 32, 64);
    s1 += __shfl_xor(s1, 16, 64); s1 += __shfl_xor(s1, 32, 64);
    const float m0 = s0 * 0.0078125f, m1 = s1 * 0.0078125f;
    float q0v = 0.f, q1v = 0.f;
#pragma unroll
    for (int slot = 0; slot < 8; ++slot)
#pragma unroll
      for (int r = 0; r < 4; ++r) {
        const float d0 = a0[slot][r] - m0; q0v = fmaf(d0, d0, q0v);
        const float d1 = a1[slot][r] - m1; q1v = fmaf(d1, d1, q1v);
      }
    q0v += __shfl_xor(q0v, 16, 64); q0v += __shfl_xor(q0v, 32, 64);
    q1v += __shfl_xor(q1v, 16, 64); q1v += __shfl_xor(q1v, 32, 64);
    const float rs0 = 1.0f / sqrtf(q0v * 0.0078125f + 1e-5f);
    const float rs1 = 1.0f / sqrtf(q1v * 0.0078125f + 1e-5f);
#pragma unroll
    for (int slot = 0; slot < 8; ++slot) {
      const int fb = slot * 16 + kg * 4;
      const h4 gq = *(const h4*)(pb + lnidx * 128 + fb);
      const h4 b2 = *(const h4*)(pb + (lnidx + 1) * 128 + fb);
      h4 o0, o1;
#pragma unroll
      for (int r = 0; r < 4; ++r) {
        o0[r] = (_Float16)((a0[slot][r] - m0) * rs0 * (float)gq[r] + (float)b2[r]);
        o1[r] = (_Float16)((a1[slot][r] - m1) * rs1 * (float)gq[r] + (float)b2[r]);
      }
      *(h4*)(g0 + aoff(nrow, fb * 2)) = o0;
      *(h4*)(g1 + aoff(nrow, fb * 2)) = o1;
    }
  }
  return rout;
}

// ---- W11 Z-stage, old orientation (A=act,B=W) -> ZT[feature][node] ----
template<int Q0, typename PF>
__device__ __forceinline__ void mm32z_old(
    const _Float16* __restrict__ Wp, char* g0, char* g1,
    char* wbase, int tid, PF&& pf)
{
  const int lane = tid & 63, wv = tid >> 6, lc = lane & 15, kg = lane >> 4;
  const int row0 = wv * 16 + lc, rb = wv * 16 + kg * 4;
  const h8 af0 = ald8(g0, row0, 64 + kg * 16);   // x at logical cols 32..63
  const h8 af1 = ald8(g1, row0, 64 + kg * 16);
#pragma unroll
  for (int oc = 0; oc < 2; ++oc) {
    waitv<1>(); rbar();
    pf(oc, wbase + ((Q0 + oc + 2) % 3) * 4096);
    const char* wb = wbase + ((Q0 + oc) % 3) * 4096;
    f4 a0[4], a1[4];
#pragma unroll
    for (int t = 0; t < 4; ++t) { a0[t] = (f4){0.f,0.f,0.f,0.f}; a1[t] = (f4){0.f,0.f,0.f,0.f}; }
#pragma unroll
    for (int t = 0; t < 4; ++t) {
      const int o = t * 16 + lc;
      const int kq = kg ^ ((o >> 1) & 3);
      const h8 wf = *(const h8*)(wb + (o * 4 + kq) * 16);
      a0[t] = __builtin_amdgcn_mfma_f32_16x16x32_f16(af0, wf, a0[t], 0, 0, 0);
      a1[t] = __builtin_amdgcn_mfma_f32_16x16x32_f16(af1, wf, a1[t], 0, 0, 0);
    }
#pragma unroll
    for (int t = 0; t < 4; ++t) {
      const int o = oc * 64 + t * 16 + lc;
      h4 o0, o1;
#pragma unroll
      for (int r = 0; r < 4; ++r) { o0[r] = (_Float16)a0[t][r]; o1[r] = (_Float16)a1[t][r]; }
      *(h4*)(g0 + zoff(o, rb * 2)) = o0;
      *(h4*)(g1 + zoff(o, rb * 2)) = o1;
    }
  }
}

// ---- W21 Z-stage, old orientation, K=128, 8 chunks, raw -> ZT ----
template<int Q0, typename PF>
__device__ __forceinline__ void mm128z_old(
    const _Float16* __restrict__ Wp, char* g0, char* g1,
    char* wbase, int tid, PF&& pf)
{
  const int lane = tid & 63, wv = tid >> 6, lc = lane & 15, kg = lane >> 4;
  const int row0 = wv * 16 + lc, rb = wv * 16 + kg * 4;
  h8 af0[4], af1[4];
#pragma unroll
  for (int i = 0; i < 4; ++i) {
    af0[i] = ald8(g0, row0, i * 64 + kg * 16);
    af1[i] = ald8(g1, row0, i * 64 + kg * 16);
  }
#pragma unroll
  for (int oc = 0; oc < 2; ++oc) {
    f4 a0[4], a1[4];
#pragma unroll
    for (int t = 0; t < 4; ++t) { a0[t] = (f4){0.f,0.f,0.f,0.f}; a1[t] = (f4){0.f,0.f,0.f,0.f}; }
#pragma unroll
    for (int kc = 0; kc < 4; ++kc) {
      const int ql = oc * 4 + kc;
      waitv<1>();
      rbar();
      const int s = ql + 2;
      char* nbuf = wbase + ((Q0 + s) % 3) * 4096;
      if (s < 8) stage64(Wp, 128, s & 3, s >> 2, nbuf, tid);
      else pf(s - 8, nbuf);
      const char* wb = wbase + ((Q0 + ql) % 3) * 4096;
#pragma unroll
      for (int t = 0; t < 4; ++t) {
        const int o = t * 16 + lc;
        const int kq = kg ^ ((o >> 1) & 3);
        const h8 wf = *(const h8*)(wb + (o * 4 + kq) * 16);
        a0[t] = __builtin_amdgcn_mfma_f32_16x16x32_f16(af0[kc], wf, a0[t], 0, 0, 0);
        a1[t] = __builtin_amdgcn_mfma_f32_16x16x32_f16(af1[kc], wf, a1[t], 0, 0, 0);
      }
    }
#pragma unroll
    for (int t = 0; t < 4; ++t) {
      const int o = oc * 64 + t * 16 + lc;
      h4 o0, o1;
#pragma unroll
      for (int r = 0; r < 4; ++r) { o0[r] = (_Float16)a0[t][r]; o1[r] = (_Float16)a1[t][r]; }
      *(h4*)(g0 + zoff(o, rb * 2)) = o0;
      *(h4*)(g1 + zoff(o, rb * 2)) = o1;
    }
  }
}

// ---- aggregation from ZT (unchanged from r13) ----
__device__ __forceinline__ void agg2_zt(
    const u64* mc0, const u64* mc1, char* g0, char* g1,
    const _Float16* pb, int bidx, int tid)
{
  const int lane = tid & 63, wv = tid >> 6, lc = lane & 15, kg = lane >> 4;
  const int fb = wv * 32;
  h8 a0[2][2], a1[2][2];
#pragma unroll
  for (int mt = 0; mt < 2; ++mt)
#pragma unroll
    for (int ks = 0; ks < 2; ++ks) {
      a0[mt][ks] = *(const h8*)(g0 + zoff(fb + mt * 16 + lc, ks * 64 + kg * 16));
      a1[mt][ks] = *(const h8*)(g1 + zoff(fb + mt * 16 + lc, ks * 64 + kg * 16));
    }
  u64 mr0[4], mr1[4];
#pragma unroll
  for (int nt = 0; nt < 4; ++nt) { mr0[nt] = mc0[nt * 16 + lc]; mr1[nt] = mc1[nt * 16 + lc]; }
  lgkm0(); rbar();
  f4 c0[2][4], c1[2][4];
#pragma unroll
  for (int mt = 0; mt < 2; ++mt)
#pragma unroll
    for (int nt = 0; nt < 4; ++nt) { c0[mt][nt] = (f4){0.f,0.f,0.f,0.f}; c1[mt][nt] = (f4){0.f,0.f,0.f,0.f}; }
#pragma unroll
  for (int ks = 0; ks < 2; ++ks)
#pragma unroll
    for (int nt = 0; nt < 4; ++nt) {
      h8 b0, b1;
#pragma unroll
      for (int e = 0; e < 8; ++e) {
        b0[e] = (_Float16)((mr0[nt] >> (ks * 32 + kg * 8 + e)) & 1ull);
        b1[e] = (_Float16)((mr1[nt] >> (ks * 32 + kg * 8 + e)) & 1ull);
      }
#pragma unroll
      for (int mt = 0; mt < 2; ++mt) {
        c0[mt][nt] = __builtin_amdgcn_mfma_f32_16x16x32_f16(a0[mt][ks], b0, c0[mt][nt], 0, 0, 0);
        c1[mt][nt] = __builtin_amdgcn_mfma_f32_16x16x32_f16(a1[mt][ks], b1, c1[mt][nt], 0, 0, 0);
      }
    }
#pragma unroll
  for (int mt = 0; mt < 2; ++mt) {
    const int f0 = fb + mt * 16 + kg * 4;
    const h4 bq = *(const h4*)(pb + bidx * 128 + f0);
#pragma unroll
    for (int nt = 0; nt < 4; ++nt) {
      const int j = nt * 16 + lc;
      h4 o0, o1;
#pragma unroll
      for (int r = 0; r < 4; ++r) {
        o0[r] = (_Float16)fmaxf(c0[mt][nt][r] + (float)bq[r], 0.f);
        o1[r] = (_Float16)fmaxf(c1[mt][nt][r] + (float)bq[r], 0.f);
      }
      *(h4*)(g0 + aoff(j, f0 * 2)) = o0;
      *(h4*)(g1 + aoff(j, f0 * 2)) = o1;
    }
  }
}

struct SM {
  alignas(16) char G0[16384];
  alignas(16) char G1[16384];
  alignas(16) char WB[12288];
  alignas(16) char PB[5120];       // params [20][128] f16
  u64 mcol[2][64];
};   // 51200 B -> 3 blocks/CU

// (256,2): VGPR cap 256 — a (256,3) cap forced mass spill in rounds 8-10.
__global__ __launch_bounds__(256, 2)
void gin_critic_kernel(
    const float* __restrict__ data,
    const float* __restrict__ Wfc, const float* __restrict__ bfc,
    const _Float16* __restrict__ ws,
    float* __restrict__ out)
{
  __shared__ SM sm;
  const int tid = threadIdx.x;
  const int lane = tid & 63, wv = tid >> 6, lc = lane & 15, kg = lane >> 4;
  const int row0 = wv * 16 + lc, rb = wv * 16 + kg * 4;
  const int b = blockIdx.x;
  const long base = (long)b * 2 * NN * 27;
  char* G0 = sm.G0; char* G1 = sm.G1; char* wbase = sm.WB;
  const _Float16* pb = (const _Float16*)sm.PB;

  const _Float16* Wl1p = ws + 0;
  const _Float16* Wl2p = ws + 4096;
  const _Float16* W11p = ws + 8192;
  const _Float16* W12p = ws + 12288;
  const _Float16* W21p = ws + 28672;
  const _Float16* W22p = ws + 45056;
  const _Float16* Wat0 = ws + 61440;
  const _Float16* Wat1 = ws + 61440 + 16384;
  const _Float16* Wf1_0 = ws + 94208;
  const _Float16* Wf1_1 = ws + 94208 + 16384;
  const _Float16* Wf2_0 = ws + 126976;
  const _Float16* Wf2_1 = ws + 126976 + 16384;

  // ---- input staging: lidar -> cols 0..19, orig7 -> cols 32..38 ----
#pragma unroll
  for (int i = 0; i < 14; ++i) {
    const int idx = tid + i * 256;
    const int cidx = idx < 3456 ? idx : 3455;
    float v = data[base + cidx];
    asm volatile("" : "+v"(v));
    if (idx < 3456) {
      const int gi = idx / 1728;
      const int r = idx - gi * 1728;
      const int n = r / 27, f = r - n * 27;
      char* Gg = gi ? G1 : G0;
      if (f < 7) ast(Gg, n, 64 + f * 2, (_Float16)v);
      else       ast(Gg, n, (f - 7) * 2, (_Float16)v);
    }
  }
  if (tid < 128) {
    const int gi = tid >> 6, n = tid & 63;
    char* Gg = gi ? G1 : G0;
#pragma unroll
    for (int c = 20; c < 32; ++c) ast(Gg, n, c * 2, (_Float16)0.f);
#pragma unroll
    for (int c = 59; c < 64; ++c) ast(Gg, n, c * 2, (_Float16)0.f);
  }
  const float* pp = data + base + (long)(wv >> 1) * 1728 + lane * 27;
  const float px = pp[0], py = pp[1];
  lgkm0(); rbar();   // staged inputs visible

  // ---- adjacency mask (exact double cone + guard-band atan2 fallback) ----
  {
    const int g = wv >> 1;
    const float FOVF = (float)(0.35 * 3.14159265358979323846);
    const double TT = tan(0.35 * 3.14159265358979323846);
    const double T2 = TT * TT;
    for (int jj = 0; jj < 32; ++jj) {
      const int j = (wv & 1) * 32 + jj;
      const float x0j = __shfl(px, j, 64);
      const float x1j = __shfl(py, j, 64);
      const float dxf = px - x0j;
      const float dyf = py - x1j;
      const float dist = sqrtf(dxf * dxf + dyf * dyf);
      bool pred;
      if (lane == j || dist > 10.0f) {
        pred = false;
      } else if (dxf <= 0.0f) {
        pred = (dxf == 0.0f && dyf == 0.0f);
      } else {
        const double qa = (double)dyf * (double)dyf;
        const double qb = (double)dxf * (double)dxf * T2;
        if (qa <= qb * 0.99999) pred = true;
        else if (qa >= qb * 1.00001) pred = false;
        else pred = (fabsf((float)atan2((double)dyf, (double)dxf)) <= FOVF);
      }
      const u64 bal = __ballot(pred);
      if (lane == 0) sm.mcol[g][j] = bal | (1ull << j);
    }
  }

  // ---- FIFO start: params (2 uniform loads) + chunks q0,q1 ----
  gload16(ws + 159744 + (size_t)tid * 8, sm.PB + (size_t)tid * 16);
  gload16(ws + 159744 + 2048 + (size_t)(tid & 63) * 8, sm.PB + 4096 + (size_t)(tid & 63) * 16);
  stage64(Wl1p, 32, 0, 0, wbase + 0 * 4096, tid);   // q0: L1a
  stage32(Wl2p, 0, wbase + 1 * 4096, tid);          // q1: L2a

  // ---- lidar MLP (hand-rolled, chunks q0..q3, hidden time-shared cols 64..127) ----
  h8 axl0, axl1;
  f4 l20[2], l21[2];
  l20[0] = l20[1] = l21[0] = l21[1] = (f4){0.f,0.f,0.f,0.f};
  // q0: L1a -> hidden[0..63] at cols 64..127
  waitv<1>(); rbar();
  stage64(Wl1p, 32, 0, 1, wbase + 2 * 4096, tid);   // q2: L1b
  axl0 = ald8(G0, row0, kg * 16);
  axl1 = ald8(G1, row0, kg * 16);
  {
    const char* wb = wbase + 0 * 4096;
    f4 a0[4], a1[4];
#pragma unroll
    for (int t = 0; t < 4; ++t) { a0[t] = (f4){0.f,0.f,0.f,0.f}; a1[t] = (f4){0.f,0.f,0.f,0.f}; }
#pragma unroll
    for (int t = 0; t < 4; ++t) {
      const int o = t * 16 + lc;
      const int kq = kg ^ ((o >> 1) & 3);
      const h8 bf = *(const h8*)(wb + (o * 4 + kq) * 16);
      a0[t] = __builtin_amdgcn_mfma_f32_16x16x32_f16(axl0, bf, a0[t], 0, 0, 0);
      a1[t] = __builtin_amdgcn_mfma_f32_16x16x32_f16(axl1, bf, a1[t], 0, 0, 0);
    }
#pragma unroll
    for (int t = 0; t < 4; ++t) {
      const int col = t * 16 + lc;
      const float bv = (float)pb[0 * 128 + col];
#pragma unroll
      for (int r = 0; r < 4; ++r) {
        ast(G0, rb + r, 128 + col * 2, (_Float16)fmaxf(a0[t][r] + bv, 0.f));
        ast(G1, rb + r, 128 + col * 2, (_Float16)fmaxf(a1[t][r] + bv, 0.f));
      }
    }
  }
  // q1: L2a (K-half 0)
  waitv<1>(); rbar();
  stage32(Wl2p, 1, wbase + 0 * 4096, tid);          // q3: L2b
  {
    const char* wb = wbase + 1 * 4096;
    h8 ah0[2], ah1[2];
#pragma unroll
    for (int i = 0; i < 2; ++i) {
      ah0[i] = ald8(G0, row0, 128 + i * 64 + kg * 16);
      ah1[i] = ald8(G1, row0, 128 + i * 64 + kg * 16);
    }
#pragma unroll
    for (int ks = 0; ks < 2; ++ks)
#pragma unroll
      for (int ct = 0; ct < 2; ++ct) {
        const int o = ct * 16 + lc;
        const int u = (ks * 4 + kg) ^ (o & 7);
        const h8 bf = *(const h8*)(wb + (o * 8 + u) * 16);
        l20[ct] = __builtin_amdgcn_mfma_f32_16x16x32_f16(ah0[ks], bf, l20[ct], 0, 0, 0);
        l21[ct] = __builtin_amdgcn_mfma_f32_16x16x32_f16(ah1[ks], bf, l21[ct], 0, 0, 0);
      }
  }
  // q2: L1b -> hidden[64..127] overwrites cols 64..127
  waitv<1>(); rbar();
  stage64(W11p, 32, 0, 0, wbase + 1 * 4096, tid);   // q4: W11 oc0
  {
    const char* wb = wbase + 2 * 4096;
    f4 a0[4], a1[4];
#pragma unroll
    for (int t = 0; t < 4; ++t) { a0[t] = (f4){0.f,0.f,0.f,0.f}; a1[t] = (f4){0.f,0.f,0.f,0.f}; }
#pragma unroll
    for (int t = 0; t < 4; ++t) {
      const int o = t * 16 + lc;
      const int kq = kg ^ ((o >> 1) & 3);
      const h8 bf = *(const h8*)(wb + (o * 4 + kq) * 16);
      a0[t] = __builtin_amdgcn_mfma_f32_16x16x32_f16(axl0, bf, a0[t], 0, 0, 0);
      a1[t] = __builtin_amdgcn_mfma_f32_16x16x32_f16(axl1, bf, a1[t], 0, 0, 0);
    }
#pragma unroll
    for (int t = 0; t < 4; ++t) {
      const int col = t * 16 + lc;
      const float bv = (float)pb[0 * 128 + 64 + col];
#pragma unroll
      for (int r = 0; r < 4; ++r) {
        ast(G0, rb + r, 128 + col * 2, (_Float16)fmaxf(a0[t][r] + bv, 0.f));
        ast(G1, rb + r, 128 + col * 2, (_Float16)fmaxf(a1[t][r] + bv, 0.f));
      }
    }
  }
  // q3: L2b (K-half 1) -> lf20 into cols 39..58
  waitv<1>(); rbar();
  stage64(W11p, 32, 0, 1, wbase + 2 * 4096, tid);   // q5: W11 oc1
  {
    const char* wb = wbase + 0 * 4096;
    h8 ah0[2], ah1[2];
#pragma unroll
    for (int i = 0; i < 2; ++i) {
      ah0[i] = ald8(G0, row0, 128 + i * 64 + kg * 16);
      ah1[i] = ald8(G1, row0, 128 + i * 64 + kg * 16);
    }
#pragma unroll
    for (int ks = 0; ks < 2; ++ks)
#pragma unroll
      for (int ct = 0; ct < 2; ++ct) {
        const int o = ct * 16 + lc;
        const int u = (ks * 4 + kg) ^ (o & 7);
        const h8 bf = *(const h8*)(wb + (o * 8 + u) * 16);
        l20[ct] = __builtin_amdgcn_mfma_f32_16x16x32_f16(ah0[ks], bf, l20[ct], 0, 0, 0);
        l21[ct] = __builtin_amdgcn_mfma_f32_16x16x32_f16(ah1[ks], bf, l21[ct], 0, 0, 0);
      }
#pragma unroll
    for (int ct = 0; ct < 2; ++ct) {
      const int col = ct * 16 + lc;
      if (col < 20) {
        const float bv = (float)pb[1 * 128 + col];
#pragma unroll
        for (int r = 0; r < 4; ++r) {
          ast(G0, rb + r, 78 + col * 2, (_Float16)fmaxf(l20[ct][r] + bv, 0.f));
          ast(G1, rb + r, 78 + col * 2, (_Float16)fmaxf(l21[ct][r] + bv, 0.f));
        }
      }
    }
  }

  Cap rz{};
  // W11 Z-stage (q4,q5): ZT1 = (x.W11^T)^T into G as [feat][node]
  mm32z_old<4>(W11p, G0, G1, wbase, tid,
      [&](int s, char* buf) { stage64(W12p, 128, s, 0, buf, tid); });
  lgkm0(); rbar();
  agg2_zt(sm.mcol[0], sm.mcol[1], G0, G1, pb, 2, tid);
  lgkm0(); rbar();
  // W12
  mm128_stage<0, false, false, 6>(W12p, G0, G1, pb, 3, -1, rz, wbase, tid,
      [&](int s, char* buf) { stage64(W21p, 128, s, 0, buf, tid); });
  // W21 Z-stage: ZT2 into G
  mm128z_old<14>(W21p, G0, G1, wbase, tid,
      [&](int s, char* buf) { stage64(W22p, 128, s, 0, buf, tid); });
  lgkm0(); rbar();
  agg2_zt(sm.mcol[0], sm.mcol[1], G0, G1, pb, 4, tid);
  lgkm0(); rbar();
  // W22: t
  mm128_stage<0, false, false, 22>(W22p, G0, G1, pb, 5, -1, rz, wbase, tid,
      [&](int s, char* buf) { stage64(Wat0, 128, s, 0, buf, tid); });
  // ---- transformer layer 0 (LN fused into epilogues) ----
  mm128_stage<4, false, false, 30>(Wat0, G0, G1, pb, 6, 12, rz, wbase, tid,
      [&](int s, char* buf) { stage64(Wf1_0, 128, s, 0, buf, tid); });
  Cap c0 = mm128_stage<0, true, false, 38>(Wf1_0, G0, G1, pb, 8, -1, rz, wbase, tid,
      [&](int s, char* buf) { stage64(Wf2_0, 128, s, 0, buf, tid); });
  mm128_stage<5, false, false, 46>(Wf2_0, G0, G1, pb, 9, 14, c0, wbase, tid,
      [&](int s, char* buf) { stage64(Wat1, 128, s, 0, buf, tid); });
  // ---- transformer layer 1 ----
  mm128_stage<4, false, false, 54>(Wat1, G0, G1, pb, 7, 16, rz, wbase, tid,
      [&](int s, char* buf) { stage64(Wf1_1, 128, s, 0, buf, tid); });
  Cap c1 = mm128_stage<0, true, false, 62>(Wf1_1, G0, G1, pb, 10, -1, rz, wbase, tid,
      [&](int s, char* buf) { stage64(Wf2_1, 128, s, 0, buf, tid); });
  mm128_stage<5, false, true, 70>(Wf2_1, G0, G1, pb, 11, 18, c1, wbase, tid,
      [&](int, char*) {});

  // ---- head (wave-local rows) ----
#pragma unroll
  for (int g = 0; g < 2; ++g) {
    const char* Pg = g ? G1 : G0;
    const int n = tid >> 2, q = tid & 3;
    float s = 0.f;
#pragma unroll
    for (int u = 0; u < 4; ++u) {
      const h8 v = ald8(Pg, n, q * 64 + u * 16);
      const float4 w0 = *(const float4*)(Wfc + q * 32 + u * 8);
      const float4 w1 = *(const float4*)(Wfc + q * 32 + u * 8 + 4);
      s = fmaf((float)v[0], w0.x, s); s = fmaf((float)v[1], w0.y, s);
      s = fmaf((float)v[2], w0.z, s); s = fmaf((float)v[3], w0.w, s);
      s = fmaf((float)v[4], w1.x, s); s = fmaf((float)v[5], w1.y, s);
      s = fmaf((float)v[6], w1.z, s); s = fmaf((float)v[7], w1.w, s);
    }
    s += __shfl_xor(s, 1, 64);
    s += __shfl_xor(s, 2, 64);
    if (q == 0) out[((long)b * 2 + g) * NN + n] = s + bfc[0];
  }
}

extern "C" void kernel_launch(void* const* d_in, const int* in_sizes, int n_in,
                              void* d_out, int out_size, void* d_ws, size_t ws_size,
                              hipStream_t stream) {
  const float* data  = (const float*)d_in[0];
  const float* W_l1  = (const float*)d_in[1];
  const float* b_l1  = (const float*)d_in[2];
  const float* W_l2  = (const float*)d_in[3];
  const float* b_l2  = (const float*)d_in[4];
  const float* W11   = (const float*)d_in[5];
  const float* b11   = (const float*)d_in[6];
  const float* W12   = (const float*)d_in[7];
  const float* b12   = (const float*)d_in[8];
  const float* W21   = (const float*)d_in[9];
  const float* b21   = (const float*)d_in[10];
  const float* W22   = (const float*)d_in[11];
  const float* b22   = (const float*)d_in[12];
  const float* Wqkv  = (const float*)d_in[13];
  const float* bqkv  = (const float*)d_in[14];
  const float* Wo    = (const float*)d_in[15];
  const float* bo    = (const float*)d_in[16];
  const float* ln1_g = (const float*)d_in[17];
  const float* ln1_b = (const float*)d_in[18];
  const float* Wf1   = (const float*)d_in[19];
  const float* bf1   = (const float*)d_in[20];
  const float* Wf2   = (const float*)d_in[21];
  const float* bf2   = (const float*)d_in[22];
  const float* ln2_g = (const float*)d_in[23];
  const float* ln2_b = (const float*)d_in[24];
  const float* Wfc   = (const float*)d_in[25];
  const float* bfc   = (const float*)d_in[26];

  _Float16* ws = (_Float16*)d_ws;

  prepA<<<dim3(634), dim3(256), 0, stream>>>(
      W_l1, W_l2, W11, W12, W21, W22, Wf1, Wf2,
      b_l1, b_l2, b11, b12, b21, b22, bf1, bf2,
      ln1_g, ln1_b, ln2_g, ln2_b, ws);
  prepB<<<dim3(129), dim3(256), 0, stream>>>(Wqkv, bqkv, Wo, bo, ws);

  gin_critic_kernel<<<dim3(NB / 2), dim3(256), 0, stream>>>(
      data, Wfc, bfc, ws, (float*)d_out);
}